// Round 11
// baseline (2946.915 us; speedup 1.0000x reference)
//
#include <hip/hip_runtime.h>
#include <stdint.h>

#define CONF_T 0.05f
#define NMS_T  0.5f
#define WMAX   132           // ceil(8400/64)

// ---- workspace layout (float offsets) ----
#define OFF_T3   0u
#define OFF_T4   1638400u
#define OFF_T5   2048000u
#define OFF_P3   2150400u
#define OFF_P4   3788800u
#define OFF_P5   4198400u
#define OFF_HA3  4300800u
#define OFF_HA4  5939200u
#define OFF_HA5  6348800u
#define OFF_HB3  6451200u
#define OFF_HB4  8089600u
#define OFF_HB5  8499200u
#define OFF_HD3  8601600u
#define OFF_HD4  10240000u
#define OFF_HD5  10649600u
#define OFF_CLS  10752000u
#define OFF_REG  11424000u
#define OFF_CTN  11457600u
// post-processing arrays (T3 region, free after conv stack)
#define POFF_KEYS  (OFF_T3 + 0u)
#define POFF_SCS   (OFF_T3 + 32768u)
#define POFF_CLSS  (OFF_T3 + 49152u)
#define POFF_IDXS  (OFF_T3 + 65536u)
#define POFF_GX1   (OFF_T3 + 81920u)
#define POFF_GY1   (OFF_T3 + 90320u)
#define POFF_GX2   (OFF_T3 + 98720u)
#define POFF_GY2   (OFF_T3 + 107120u)
#define POFF_GAR   (OFF_T3 + 115520u)
#define POFF_GIX   (OFF_T3 + 123920u)
#define POFF_NCNT  (OFF_T3 + 132320u)
#define POFF_NBASE (OFF_T3 + 132400u)
#define POFF_MASK  OFF_HA3

// ---------------- conv 1x1 (+ optional nearest-up2 add) ----------------
__launch_bounds__(256)
__global__ void conv1x1_kernel(const float* __restrict__ in, const float* __restrict__ w,
                               const float* __restrict__ b, float* __restrict__ out,
                               const float* __restrict__ add,
                               int Cin, int Cout, int NPX, int W, int outStride, int outBase)
{
    __shared__ float s_in[16][64];
    __shared__ float s_w[16][64];
    int t = threadIdx.x;
    int pxg = t & 31, cg = t >> 5;
    int px0 = blockIdx.x * 64;
    int co0 = blockIdx.y * 64;
    float acc[8][2];
#pragma unroll
    for (int c = 0; c < 8; ++c) { acc[c][0] = 0.f; acc[c][1] = 0.f; }
    int chunks = Cin >> 4;
    int wco = t >> 2, wpart = t & 3;
    for (int ch = 0; ch < chunks; ++ch) {
        int ci0 = ch << 4;
#pragma unroll
        for (int k = 0; k < 4; ++k) {
            int id = t + k * 256;
            int ci = id >> 6, pp = id & 63;
            int gp = px0 + pp;
            s_in[ci][pp] = (gp < NPX) ? in[(size_t)(ci0 + ci) * NPX + gp] : 0.f;
        }
        {
            int gco = co0 + wco;
            if (gco < Cout) {
                const float* run = w + (size_t)gco * Cin + ci0;
#pragma unroll
                for (int k = 0; k < 4; ++k) {
                    int e = wpart + 4 * k;
                    s_w[e][wco] = run[e];
                }
            } else {
#pragma unroll
                for (int k = 0; k < 4; ++k) s_w[wpart + 4 * k][wco] = 0.f;
            }
        }
        __syncthreads();
#pragma unroll
        for (int ci = 0; ci < 16; ++ci) {
            float i0 = s_in[ci][pxg * 2], i1 = s_in[ci][pxg * 2 + 1];
#pragma unroll
            for (int c = 0; c < 8; ++c) {
                float wv = s_w[ci][cg * 8 + c];
                acc[c][0] += wv * i0;
                acc[c][1] += wv * i1;
            }
        }
        __syncthreads();
    }
    for (int c = 0; c < 8; ++c) {
        int co = co0 + cg * 8 + c;
        if (co >= Cout) break;
        float bb = b[co];
#pragma unroll
        for (int j = 0; j < 2; ++j) {
            int p = px0 + pxg * 2 + j;
            if (p < NPX) {
                float v = acc[c][j] + bb;
                if (add) {
                    int y = p / W, x = p % W;
                    int Sp = W >> 1;
                    v += add[(size_t)co * (Sp * Sp) + (y >> 1) * Sp + (x >> 1)];
                }
                out[(size_t)co * outStride + outBase + p] = v;
            }
        }
    }
}

// ---------------- fused detector 1x1 (9 combos in one dispatch) ----------------
struct Det9 {
    const float* src[9]; const float* w[9]; const float* b[9];
    float*       dst[9];
    int cout[9], npx[9], obase[9], bstart[9], npxb[9];
};

__launch_bounds__(256)
__global__ void det1x1_fused(Det9 d)
{
    int bid = blockIdx.x;
    int q = 0;
#pragma unroll
    for (int i = 1; i < 9; ++i) if (bid >= d.bstart[i]) q = i;
    int local = bid - d.bstart[q];
    int coIdx = local / d.npxb[q];
    int pxIdx = local - coIdx * d.npxb[q];
    const float* in = d.src[q];
    const float* w  = d.w[q];
    const float* b  = d.b[q];
    float* out = d.dst[q];
    int Cout = d.cout[q], NPX = d.npx[q], outBase = d.obase[q];

    __shared__ float s_in[16][64];
    __shared__ float s_w[16][64];
    int t = threadIdx.x;
    int pxg = t & 31, cg = t >> 5;
    int px0 = pxIdx * 64;
    int co0 = coIdx * 64;
    float acc[8][2];
#pragma unroll
    for (int c = 0; c < 8; ++c) { acc[c][0] = 0.f; acc[c][1] = 0.f; }
    int wco = t >> 2, wpart = t & 3;
    for (int ch = 0; ch < 16; ++ch) {
        int ci0 = ch << 4;
#pragma unroll
        for (int k = 0; k < 4; ++k) {
            int id = t + k * 256;
            int ci = id >> 6, pp = id & 63;
            int gp = px0 + pp;
            s_in[ci][pp] = (gp < NPX) ? in[(size_t)(ci0 + ci) * NPX + gp] : 0.f;
        }
        {
            int gco = co0 + wco;
            if (gco < Cout) {
                const float* run = w + (size_t)gco * 256 + ci0;
#pragma unroll
                for (int k = 0; k < 4; ++k) {
                    int e = wpart + 4 * k;
                    s_w[e][wco] = run[e];
                }
            } else {
#pragma unroll
                for (int k = 0; k < 4; ++k) s_w[wpart + 4 * k][wco] = 0.f;
            }
        }
        __syncthreads();
#pragma unroll
        for (int ci = 0; ci < 16; ++ci) {
            float i0 = s_in[ci][pxg * 2], i1 = s_in[ci][pxg * 2 + 1];
#pragma unroll
            for (int c = 0; c < 8; ++c) {
                float wv = s_w[ci][cg * 8 + c];
                acc[c][0] += wv * i0;
                acc[c][1] += wv * i1;
            }
        }
        __syncthreads();
    }
    for (int c = 0; c < 8; ++c) {
        int co = co0 + cg * 8 + c;
        if (co >= Cout) break;
        float bb = b[co];
#pragma unroll
        for (int j = 0; j < 2; ++j) {
            int p = px0 + pxg * 2 + j;
            if (p < NPX) out[(size_t)co * 8400 + outBase + p] = acc[c][j] + bb;
        }
    }
}

// ---------------- conv 3x3 body (shared by smooth + fused heads) ----------------
// Round-9 structure (best measured): TCO=64/COPT=8, double-buffered LDS,
// register-prefetch staging, scalar input reads (INW=TW+3 odd, <=2-way free),
// broadcast float4 weight reads. b128 INPUT reads forbidden (4-way conflict,
// r7/r8). global_load_lds forbidden (4B-wide + vmcnt(0) drain regression, r10).
template<int TW, int TH, int TCO>
__device__ __forceinline__ void conv3x3_body(
    const float* __restrict__ src, const float* __restrict__ w,
    const float* __restrict__ bias, float* __restrict__ dst,
    int H, int W, int act, int bx0, int by0, int co0,
    float* __restrict__ sin0, float* __restrict__ sin1,
    float* __restrict__ sw0, float* __restrict__ sw1)
{
    constexpr int TPX  = TW * TH;
    constexpr int NXQ  = TW / 4;
    constexpr int PXGN = TPX / 4;
    constexpr int COG  = 256 / PXGN;
    constexpr int COPT = TCO / COG;
    constexpr int INW  = TW + 3;
    constexpr int INH  = TH + 2;
    constexpr int SW   = TW + 2;
    constexpr int INSLOTS = 8 * INH * SW;
    constexpr int KSTG = (INSLOTS + 255) / 256;
    constexpr int EPT  = 72 * TCO / 256;      // 18 for TCO=64

    int t = threadIdx.x;
    int pxg = t % PXGN, cg = t / PXGN;
    int xq = pxg % NXQ, yr = pxg / NXQ;
    int x0 = xq * 4;
    int HW = H * W;

    // ch-invariant staging descriptors
    int sl[KSTG], sg[KSTG];
#pragma unroll
    for (int k = 0; k < KSTG; ++k) {
        int id = t + k * 256;
        sl[k] = -1; sg[k] = -1;
        if (id < INSLOTS) {
            int ci = id / (INH * SW);
            int rem = id - ci * (INH * SW);
            int r = rem / SW, cc = rem - r * SW;
            sl[k] = (ci * INH + r) * INW + cc;
            int gy = by0 - 1 + r, gx = bx0 - 1 + cc;
            if (gy >= 0 && gy < H && gx >= 0 && gx < W)
                sg[k] = ci * HW + gy * W + gx;
        }
    }
    int wco = t % TCO;          // staging writes: banks = wco mod 32, 2-way benign
    int wpart = t / TCO;        // 256/TCO parts, EPT consecutive weights each
    const float* wbase = w + (size_t)(co0 + wco) * 2304;

    float acc[COPT][4];
#pragma unroll
    for (int c = 0; c < COPT; ++c)
#pragma unroll
        for (int i = 0; i < 4; ++i) acc[c][i] = 0.f;

    // stage chunk 0 directly
    {
#pragma unroll
        for (int k = 0; k < KSTG; ++k)
            if (sl[k] >= 0) sin0[sl[k]] = (sg[k] >= 0) ? src[sg[k]] : 0.f;
#pragma unroll
        for (int k = 0; k < EPT; ++k) {
            int e = wpart * EPT + k;
            sw0[e * TCO + wco] = wbase[e];
        }
    }
    __syncthreads();

    for (int ch = 0; ch < 32; ++ch) {
        float* cin = (ch & 1) ? sin1 : sin0;
        float* cw  = (ch & 1) ? sw1  : sw0;
        float vin[KSTG]; float vw[EPT];
        bool pf = (ch < 31);
        if (pf) {
            const float* sb = src + (size_t)((ch + 1) * 8) * HW;
            const float* wr = wbase + (ch + 1) * 72;
#pragma unroll
            for (int k = 0; k < KSTG; ++k)
                vin[k] = (sg[k] >= 0) ? sb[sg[k]] : 0.f;
#pragma unroll
            for (int k = 0; k < EPT; ++k)
                vw[k] = wr[wpart * EPT + k];
        }
        // compute chunk ch: scalar input reads, broadcast vector weight reads
        for (int ci = 0; ci < 8; ++ci) {
            float inr[3][6];
#pragma unroll
            for (int ky = 0; ky < 3; ++ky)
#pragma unroll
                for (int j = 0; j < 6; ++j)
                    inr[ky][j] = cin[(ci * INH + yr + ky) * INW + x0 + j];
            const float* wrow = cw + ci * 9 * TCO;
#pragma unroll
            for (int ky = 0; ky < 3; ++ky) {
#pragma unroll
                for (int kx = 0; kx < 3; ++kx) {
                    const float* wp = wrow + (ky * 3 + kx) * TCO + cg * COPT;
                    float wq[COPT];
                    if constexpr (COPT == 8) {
                        float4 w4a = *(const float4*)wp;        // 32B-aligned
                        float4 w4b = *(const float4*)(wp + 4);
                        wq[0] = w4a.x; wq[1] = w4a.y; wq[2] = w4a.z; wq[3] = w4a.w;
                        wq[4] = w4b.x; wq[5] = w4b.y; wq[6] = w4b.z; wq[7] = w4b.w;
                    } else if constexpr (COPT == 4) {
                        float4 w4 = *(const float4*)wp;
                        wq[0] = w4.x; wq[1] = w4.y; wq[2] = w4.z; wq[3] = w4.w;
                    } else if constexpr (COPT == 2) {
                        float2 w2 = *(const float2*)wp;
                        wq[0] = w2.x; wq[1] = w2.y;
                    } else {
                        wq[0] = wp[0];
                    }
#pragma unroll
                    for (int c = 0; c < COPT; ++c) {
#pragma unroll
                        for (int i = 0; i < 4; ++i)
                            acc[c][i] += wq[c] * inr[ky][kx + i];
                    }
                }
            }
        }
        if (pf) {
            float* nin = (ch & 1) ? sin0 : sin1;
            float* nw  = (ch & 1) ? sw0  : sw1;
#pragma unroll
            for (int k = 0; k < KSTG; ++k)
                if (sl[k] >= 0) nin[sl[k]] = vin[k];
#pragma unroll
            for (int k = 0; k < EPT; ++k) {
                int e = wpart * EPT + k;
                nw[e * TCO + wco] = vw[k];
            }
        }
        __syncthreads();
    }

    int y = by0 + yr;
#pragma unroll
    for (int c = 0; c < COPT; ++c) {
        int co = co0 + cg * COPT + c;
        float bb = bias[co];
#pragma unroll
        for (int i = 0; i < 4; ++i) {
            int x = bx0 + x0 + i;
            if (x < W && y < H) {
                float v = acc[c][i] + bb;
                if (act) v = (v >= 0.f) ? v : 0.1f * v;
                dst[(size_t)co * HW + y * W + x] = v;
            }
        }
    }
}

// ---------------- smooth conv wrapper (single level) ----------------
// (256,3): RAISES the VGPR cap to ~170 (grid only needs 2.2 blocks/CU) so the
// compiler can software-pipeline LDS reads across FMAs. NOT round-7's (256,5)
// which FORCED VGPR down to 48 and spilled.
template<int TW, int TH, int TCO>
__launch_bounds__(256, 3)
__global__ void conv3x3_t(const float* __restrict__ src, const float* __restrict__ w,
                          const float* __restrict__ b, float* __restrict__ dst,
                          int H, int W, int act)
{
    constexpr int INW = TW + 3, INH = TH + 2;
    __shared__ __align__(16) float s_in[2][8 * INH * INW];
    __shared__ __align__(16) float s_w[2][72 * TCO];
    int nTx = (W + TW - 1) / TW;
    int tx = blockIdx.x % nTx, ty = blockIdx.x / nTx;
    conv3x3_body<TW, TH, TCO>(src, w, b, dst, H, W, act,
                              tx * TW, ty * TH, blockIdx.y * TCO,
                              s_in[0], s_in[1], s_w[0], s_w[1]);
}

// ---------------- fused 3-level head conv (one layer, both branches) ----------------
struct HeadPtrs {
    const float* src[2][3];
    float*       dst[2][3];
};

__launch_bounds__(256, 3)
__global__ void conv3x3_heads(HeadPtrs hp, const float* __restrict__ wA,
                              const float* __restrict__ wB,
                              const float* __restrict__ bA, const float* __restrict__ bB)
{
    constexpr int TW = 16, TH = 8, TCO = 64;
    constexpr int INW = TW + 3, INH = TH + 2;
    __shared__ __align__(16) float s_in[2][8 * INH * INW];
    __shared__ __align__(16) float s_w[2][72 * TCO];

    int tb = blockIdx.x;                       // 0..70: 50 (L3) + 15 (L4) + 6 (L5)
    int lvl = (tb < 50) ? 0 : (tb < 65) ? 1 : 2;
    int tloc = tb - ((lvl == 0) ? 0 : (lvl == 1) ? 50 : 65);
    int W = (lvl == 0) ? 80 : (lvl == 1) ? 40 : 20;
    int br = blockIdx.z;
    const float* src = hp.src[br][lvl];
    float* dst = hp.dst[br][lvl];
    const float* w    = br ? wB : wA;
    const float* bias = br ? bB : bA;
    int nTx = (W + TW - 1) / TW;
    int tx = tloc % nTx, ty = tloc / nTx;
    conv3x3_body<TW, TH, TCO>(src, w, bias, dst, W, W, 1,
                              tx * TW, ty * TH, blockIdx.y * TCO,
                              s_in[0], s_in[1], s_w[0], s_w[1]);
}

// ---------------- decode: scores, argmax, boxes, sort keys ----------------
__launch_bounds__(256)
__global__ void decode_kernel(const float* __restrict__ cls, const float* __restrict__ reg,
                              const float* __restrict__ ctn, float* __restrict__ out,
                              unsigned long long* __restrict__ keys)
{
    int p = blockIdx.x * 256 + threadIdx.x;
    if (p >= 16384) return;
    if (p >= 8400) { keys[p] = ~0ull; return; }
    int base, hs; float s;
    if (p < 6400)      { base = 0;    hs = 80; s = 8.f;  }
    else if (p < 8000) { base = 6400; hs = 40; s = 16.f; }
    else               { base = 8000; hs = 20; s = 32.f; }
    int local = p - base;
    float gx = (float)(local % hs), gy = (float)(local / hs);
    float ct = ctn[p];
    float sct = 1.f / (1.f + expf(-ct));
    float best = -1.f; int arg = 0;
    for (int c = 0; c < 80; ++c) {
        float v = cls[(size_t)c * 8400 + p];
        float sv = 1.f / (1.f + expf(-v));
        float sc = sqrtf(sv * sct);
        if (sc > best) { best = sc; arg = c; }
    }
    float r0 = reg[0 * 8400 + p], r1 = reg[1 * 8400 + p];
    float r2 = reg[2 * 8400 + p], r3 = reg[3 * 8400 + p];
    float x1 = (gx - expf(r0)) * s / 640.f;
    float y1 = (gy - expf(r1)) * s / 640.f;
    float x2 = (gx + expf(r2)) * s / 640.f;
    float y2 = (gy + expf(r3)) * s / 640.f;
    x1 = fminf(fmaxf(x1, 0.f), 1.f);
    y1 = fminf(fmaxf(y1, 0.f), 1.f);
    x2 = fminf(fmaxf(x2, 0.f), 1.f);
    y2 = fminf(fmaxf(y2, 0.f), 1.f);
    out[p * 4 + 0] = x1; out[p * 4 + 1] = y1;
    out[p * 4 + 2] = x2; out[p * 4 + 3] = y2;
    out[33600 + p] = best;
    out[42000 + p] = (float)arg;
    out[50400 + p] = 0.f;
    unsigned int ub = __float_as_uint(best);
    keys[p] = ((unsigned long long)(~ub) << 32) | (unsigned int)p;
}

// ---------------- hybrid bitonic sort of 16384 u64 keys ----------------
__launch_bounds__(256)
__global__ void bitonic_local(unsigned long long* __restrict__ keys, unsigned kmerge)
{
    __shared__ unsigned long long sk[2048];
    int t = threadIdx.x;
    unsigned base = blockIdx.x * 2048u;
#pragma unroll
    for (int m = 0; m < 8; ++m) sk[t + m * 256] = keys[base + t + m * 256];
    __syncthreads();
    if (kmerge == 0u) {
        for (unsigned k = 2; k <= 2048u; k <<= 1) {
            for (unsigned j = k >> 1; j > 0; j >>= 1) {
#pragma unroll
                for (int pp = 0; pp < 4; ++pp) {
                    unsigned p = (unsigned)t + pp * 256u;
                    unsigned li = ((p & ~(j - 1)) << 1) | (p & (j - 1));
                    unsigned gi = base + li;
                    bool up = ((gi & k) == 0);
                    unsigned long long a = sk[li], b = sk[li + j];
                    if ((a > b) == up) { sk[li] = b; sk[li + j] = a; }
                }
                __syncthreads();
            }
        }
    } else {
        unsigned k = kmerge;
        for (unsigned j = 1024; j > 0; j >>= 1) {
#pragma unroll
            for (int pp = 0; pp < 4; ++pp) {
                unsigned p = (unsigned)t + pp * 256u;
                unsigned li = ((p & ~(j - 1)) << 1) | (p & (j - 1));
                unsigned gi = base + li;
                bool up = ((gi & k) == 0);
                unsigned long long a = sk[li], b = sk[li + j];
                if ((a > b) == up) { sk[li] = b; sk[li + j] = a; }
            }
            __syncthreads();
        }
    }
#pragma unroll
    for (int m = 0; m < 8; ++m) keys[base + t + m * 256] = sk[t + m * 256];
}

__launch_bounds__(256)
__global__ void bitonic_global(unsigned long long* __restrict__ keys, unsigned k, unsigned j)
{
    unsigned p = blockIdx.x * 256u + threadIdx.x;
    unsigned i = ((p & ~(j - 1)) << 1) | (p & (j - 1));
    bool up = ((i & k) == 0);
    unsigned long long a = keys[i], b = keys[i + j];
    if ((a > b) == up) { keys[i] = b; keys[i + j] = a; }
}

// ---------------- expand sorted keys into SoA arrays ----------------
__launch_bounds__(256)
__global__ void sorted_aux(const unsigned long long* __restrict__ keys,
                           const float* __restrict__ out,
                           float* __restrict__ scs, int* __restrict__ clss,
                           int* __restrict__ idxs)
{
    int i = blockIdx.x * 256 + threadIdx.x;
    if (i >= 16384) return;
    unsigned long long key = keys[i];
    unsigned ub = ~(unsigned)(key >> 32);
    float sc = __uint_as_float(ub);
    unsigned idx = (unsigned)(key & 0xffffffffu);
    int cl = -1;
    if (idx < 8400u) cl = (int)out[42000 + idx];
    else sc = 0.f;
    scs[i] = sc; clss[i] = cl; idxs[i] = (int)idx;
}

// ---------------- NMS stage 1: per-class stable compaction ----------------
__launch_bounds__(256)
__global__ void compact_cls(const float* __restrict__ scs, const int* __restrict__ clss,
                            const int* __restrict__ idxs, const float* __restrict__ outbuf,
                            float* __restrict__ GX1, float* __restrict__ GY1,
                            float* __restrict__ GX2, float* __restrict__ GY2,
                            float* __restrict__ GAR, int* __restrict__ GIX,
                            int* __restrict__ NCOUNT, int* __restrict__ NBASE)
{
    int c = blockIdx.x, t = threadIdx.x;
    __shared__ int s_red[2];
    __shared__ int s_wtot[4];
    int cb = 0, co = 0;
    for (int i = t; i < 16384; i += 256) {
        float sc = scs[i]; int cl = clss[i];
        if (sc >= CONF_T && cl >= 0) { cb += (cl < c); co += (cl == c); }
    }
    if (t == 0) { s_red[0] = 0; s_red[1] = 0; }
    __syncthreads();
    atomicAdd(&s_red[0], cb);
    atomicAdd(&s_red[1], co);
    __syncthreads();
    int base = s_red[0], n = s_red[1];
    if (t == 0) { NCOUNT[c] = n; NBASE[c] = base; }

    int rank = 0;
    for (int st = 0; st < 16384; st += 256) {
        int i = st + t;
        float sc = scs[i]; int cl = clss[i];
        bool flag = (sc >= CONF_T && cl == c);
        unsigned long long m = __ballot(flag);
        int lane = t & 63, wv = t >> 6;
        if (lane == 0) s_wtot[wv] = __popcll(m);
        __syncthreads();
        int off = rank;
        for (int w = 0; w < wv; ++w) off += s_wtot[w];
        int tot = s_wtot[0] + s_wtot[1] + s_wtot[2] + s_wtot[3];
        if (flag) {
            int pos = off + __popcll(m & ((1ull << lane) - 1ull));
            int idx = idxs[i];
            float x1 = outbuf[idx * 4 + 0], y1 = outbuf[idx * 4 + 1];
            float x2 = outbuf[idx * 4 + 2], y2 = outbuf[idx * 4 + 3];
            GX1[base + pos] = x1; GY1[base + pos] = y1;
            GX2[base + pos] = x2; GY2[base + pos] = y2;
            GAR[base + pos] = (x2 - x1) * (y2 - y1);
            GIX[base + pos] = idx;
        }
        rank += tot;
        __syncthreads();
    }
}

// ---------------- NMS stage 2: suppression bit-matrix (parallel) ----------------
__launch_bounds__(256)
__global__ void nms_mask(const float* __restrict__ GX1, const float* __restrict__ GY1,
                         const float* __restrict__ GX2, const float* __restrict__ GY2,
                         const float* __restrict__ GAR,
                         const int* __restrict__ NCOUNT, const int* __restrict__ NBASE,
                         unsigned long long* __restrict__ MASK)
{
    int c = blockIdx.y;
    int n = NCOUNT[c];
    if ((int)(blockIdx.x * 256) >= n) return;
    int base = NBASE[c];
    int t = threadIdx.x;
    int r = blockIdx.x * 256 + t;
    bool hav = (r < n);
    float rx1 = 0.f, ry1 = 0.f, rx2 = 0.f, ry2 = 0.f, rar = 0.f;
    if (hav) {
        rx1 = GX1[base + r]; ry1 = GY1[base + r];
        rx2 = GX2[base + r]; ry2 = GY2[base + r];
        rar = GAR[base + r];
    }
    __shared__ float tx1[2048], ty1[2048], tx2[2048], ty2[2048], tar[2048];
    for (int jt = 0; jt < n; jt += 2048) {
        int cnt = min(2048, n - jt);
        __syncthreads();
        for (int k = t; k < cnt; k += 256) {
            tx1[k] = GX1[base + jt + k]; ty1[k] = GY1[base + jt + k];
            tx2[k] = GX2[base + jt + k]; ty2[k] = GY2[base + jt + k];
            tar[k] = GAR[base + jt + k];
        }
        __syncthreads();
        if (hav) {
            int w0 = jt >> 6;
            int nw = (cnt + 63) >> 6;
            for (int w = 0; w < nw; ++w) {
                int jb = jt + w * 64;
                unsigned long long bits = 0ull;
                if (jb + 63 > r) {
                    int kmax = min(64, n - jb);
                    for (int kk = 0; kk < kmax; ++kk) {
                        int j = jb + kk;
                        if (j > r) {
                            int k2 = j - jt;
                            float xx1 = fmaxf(rx1, tx1[k2]);
                            float yy1 = fmaxf(ry1, ty1[k2]);
                            float xx2 = fminf(rx2, tx2[k2]);
                            float yy2 = fminf(ry2, ty2[k2]);
                            float ww = fmaxf(1e-28f, xx2 - xx1);
                            float hh = fmaxf(1e-28f, yy2 - yy1);
                            float inter = ww * hh;
                            float ovr = inter / (rar + tar[k2] - inter);
                            if (ovr > NMS_T) bits |= (1ull << kk);
                        }
                    }
                }
                MASK[(size_t)(base + r) * WMAX + w0 + w] = bits;
            }
        }
    }
}

// ---------------- NMS stage 3: chunked bitmask scan (80 blocks) ----------------
__launch_bounds__(256)
__global__ void nms_scan(const unsigned long long* __restrict__ MASK,
                         const int* __restrict__ GIX,
                         const int* __restrict__ NCOUNT, const int* __restrict__ NBASE,
                         float* __restrict__ keep)
{
    int c = blockIdx.x, t = threadIdx.x;
    int n = NCOUNT[c];
    if (n == 0) return;
    int base = NBASE[c];
    int Wc = (n + 63) >> 6;
    __shared__ unsigned long long remv[WMAX];
    __shared__ unsigned long long sld[32][WMAX];
    __shared__ unsigned int s_alive;
    for (int w = t; w < Wc; w += 256) remv[w] = 0ull;
    __syncthreads();
    for (int i0 = 0; i0 < n; i0 += 32) {
        int rows = min(32, n - i0);
        int tot = rows * Wc;
        for (int k = t; k < tot; k += 256) {
            int rr = k / Wc, w = k - rr * Wc;
            sld[rr][w] = MASK[(size_t)(base + i0 + rr) * WMAX + w];
        }
        __syncthreads();
        if (t == 0) {
            int wq = i0 >> 6, b0 = i0 & 63;
            unsigned long long lw = remv[wq];
            unsigned am = 0;
            for (int rr = 0; rr < rows; ++rr) {
                if (!((lw >> (b0 + rr)) & 1ull)) {
                    am |= (1u << rr);
                    lw |= sld[rr][wq];
                }
            }
            s_alive = am;
        }
        __syncthreads();
        unsigned am = s_alive;
        for (int w = t; w < Wc; w += 256) {
            unsigned long long acc = remv[w];
            unsigned m = am;
            while (m) { int rr = __ffs(m) - 1; m &= m - 1; acc |= sld[rr][w]; }
            remv[w] = acc;
        }
        if (t < rows && ((am >> t) & 1u)) keep[GIX[base + i0 + t]] = 1.0f;
        __syncthreads();
    }
}

// ---------------- host orchestration ----------------
extern "C" void kernel_launch(void* const* d_in, const int* in_sizes, int n_in,
                              void* d_out, int out_size, void* d_ws, size_t ws_size,
                              hipStream_t stream)
{
    const float* c3      = (const float*)d_in[0];
    const float* c4      = (const float*)d_in[1];
    const float* c5      = (const float*)d_in[2];
    const float* lat1_w  = (const float*)d_in[3];
    const float* lat1_b  = (const float*)d_in[4];
    const float* lat2_w  = (const float*)d_in[5];
    const float* lat2_b  = (const float*)d_in[6];
    const float* lat3_w  = (const float*)d_in[7];
    const float* lat3_b  = (const float*)d_in[8];
    const float* sm1_w   = (const float*)d_in[9];
    const float* sm1_b   = (const float*)d_in[10];
    const float* sm2_w   = (const float*)d_in[11];
    const float* sm2_b   = (const float*)d_in[12];
    const float* sm3_w   = (const float*)d_in[13];
    const float* sm3_b   = (const float*)d_in[14];
    const float* clsh_w  = (const float*)d_in[15];
    const float* clsh_b  = (const float*)d_in[16];
    const float* regh_w  = (const float*)d_in[17];
    const float* regh_b  = (const float*)d_in[18];
    const float* clsd_w  = (const float*)d_in[19];
    const float* clsd_b  = (const float*)d_in[20];
    const float* regd_w  = (const float*)d_in[21];
    const float* regd_b  = (const float*)d_in[22];
    const float* ctnd_w  = (const float*)d_in[23];
    const float* ctnd_b  = (const float*)d_in[24];

    float* ws = (float*)d_ws;
    float* T3 = ws + OFF_T3;  float* T4 = ws + OFF_T4;  float* T5 = ws + OFF_T5;
    float* P3 = ws + OFF_P3;  float* P4 = ws + OFF_P4;  float* P5 = ws + OFF_P5;
    float* HA3 = ws + OFF_HA3; float* HA4 = ws + OFF_HA4; float* HA5 = ws + OFF_HA5;
    float* HB3 = ws + OFF_HB3; float* HB4 = ws + OFF_HB4; float* HB5 = ws + OFF_HB5;
    float* HD3 = ws + OFF_HD3; float* HD4 = ws + OFF_HD4; float* HD5 = ws + OFF_HD5;
    float* CLS = ws + OFF_CLS; float* REG = ws + OFF_REG; float* CTN = ws + OFF_CTN;
    unsigned long long* KEYS = (unsigned long long*)(ws + POFF_KEYS);
    float* SCS = ws + POFF_SCS;
    int* CLSS = (int*)(ws + POFF_CLSS);
    int* IDXS = (int*)(ws + POFF_IDXS);
    float* GX1 = ws + POFF_GX1; float* GY1 = ws + POFF_GY1;
    float* GX2 = ws + POFF_GX2; float* GY2 = ws + POFF_GY2;
    float* GAR = ws + POFF_GAR;
    int* GIX = (int*)(ws + POFF_GIX);
    int* NCOUNT = (int*)(ws + POFF_NCNT);
    int* NBASE  = (int*)(ws + POFF_NBASE);
    unsigned long long* MASK = (unsigned long long*)(ws + POFF_MASK);

    float* out = (float*)d_out;
    dim3 blk(256);
    const size_t WSTEP = 256u * 256u * 9u;

    // ---- FPN ----
    conv1x1_kernel<<<dim3(7, 4), blk, 0, stream>>>(c5, lat3_w, lat3_b, T5, nullptr,
                                                   512, 256, 400, 20, 400, 0);
    conv3x3_t<8, 4, 64><<<dim3(15, 4), blk, 0, stream>>>(T5, sm3_w, sm3_b, P5, 20, 20, 0);
    conv1x1_kernel<<<dim3(25, 4), blk, 0, stream>>>(c4, lat2_w, lat2_b, T4, T5,
                                                    256, 256, 1600, 40, 1600, 0);
    conv3x3_t<16, 4, 64><<<dim3(30, 4), blk, 0, stream>>>(T4, sm2_w, sm2_b, P4, 40, 40, 0);
    conv1x1_kernel<<<dim3(100, 4), blk, 0, stream>>>(c3, lat1_w, lat1_b, T3, T4,
                                                     128, 256, 6400, 80, 6400, 0);
    conv3x3_t<16, 8, 64><<<dim3(50, 4), blk, 0, stream>>>(T3, sm1_w, sm1_b, P3, 80, 80, 0);

    // ---- heads: 4 fused layers, 3 levels + both branches per dispatch ----
    {
        float* clsS[3][5] = { {P3, HA3, HB3, HA3, HB3},
                              {P4, HA4, HB4, HA4, HB4},
                              {P5, HA5, HB5, HA5, HB5} };
        float* regS[3][5] = { {P3, T3,  HD3, T3,  HD3},
                              {P4, T4,  HD4, T4,  HD4},
                              {P5, T5,  HD5, T5,  HD5} };
        for (int i = 0; i < 4; ++i) {
            HeadPtrs hp;
            for (int l = 0; l < 3; ++l) {
                hp.src[0][l] = clsS[l][i];     hp.dst[0][l] = clsS[l][i + 1];
                hp.src[1][l] = regS[l][i];     hp.dst[1][l] = regS[l][i + 1];
            }
            conv3x3_heads<<<dim3(71, 4, 2), blk, 0, stream>>>(
                hp, clsh_w + (size_t)i * WSTEP, regh_w + (size_t)i * WSTEP,
                clsh_b + i * 256, regh_b + i * 256);
        }
    }

    // ---- detectors: all 9 (level x {cls,reg,ctn}) in one dispatch ----
    {
        Det9 d;
        const float* feats[3][2] = { {HB3, HD3}, {HB4, HD4}, {HB5, HD5} };
        int   npx[3]   = {6400, 1600, 400};
        int   obase[3] = {0, 6400, 8000};
        int q = 0, bacc = 0;
        for (int l = 0; l < 3; ++l) {
            d.src[q] = feats[l][0]; d.w[q] = clsd_w; d.b[q] = clsd_b; d.dst[q] = CLS;
            d.cout[q] = 80; d.npx[q] = npx[l]; d.obase[q] = obase[l];
            d.bstart[q] = bacc; d.npxb[q] = (npx[l] + 63) / 64;
            bacc += d.npxb[q] * 2; ++q;
            d.src[q] = feats[l][1]; d.w[q] = regd_w; d.b[q] = regd_b; d.dst[q] = REG;
            d.cout[q] = 4; d.npx[q] = npx[l]; d.obase[q] = obase[l];
            d.bstart[q] = bacc; d.npxb[q] = (npx[l] + 63) / 64;
            bacc += d.npxb[q]; ++q;
            d.src[q] = feats[l][1]; d.w[q] = ctnd_w; d.b[q] = ctnd_b; d.dst[q] = CTN;
            d.cout[q] = 1; d.npx[q] = npx[l]; d.obase[q] = obase[l];
            d.bstart[q] = bacc; d.npxb[q] = (npx[l] + 63) / 64;
            bacc += d.npxb[q]; ++q;
        }
        det1x1_fused<<<dim3(bacc), blk, 0, stream>>>(d);
    }

    // ---- decode ----
    decode_kernel<<<dim3(64), blk, 0, stream>>>(CLS, REG, CTN, out, KEYS);

    // ---- hybrid bitonic sort ----
    bitonic_local<<<dim3(8), blk, 0, stream>>>(KEYS, 0u);
    bitonic_global<<<dim3(32), blk, 0, stream>>>(KEYS, 4096u, 2048u);
    bitonic_local<<<dim3(8), blk, 0, stream>>>(KEYS, 4096u);
    bitonic_global<<<dim3(32), blk, 0, stream>>>(KEYS, 8192u, 4096u);
    bitonic_global<<<dim3(32), blk, 0, stream>>>(KEYS, 8192u, 2048u);
    bitonic_local<<<dim3(8), blk, 0, stream>>>(KEYS, 8192u);
    bitonic_global<<<dim3(32), blk, 0, stream>>>(KEYS, 16384u, 8192u);
    bitonic_global<<<dim3(32), blk, 0, stream>>>(KEYS, 16384u, 4096u);
    bitonic_global<<<dim3(32), blk, 0, stream>>>(KEYS, 16384u, 2048u);
    bitonic_local<<<dim3(8), blk, 0, stream>>>(KEYS, 16384u);

    // ---- NMS pipeline ----
    sorted_aux<<<dim3(64), blk, 0, stream>>>(KEYS, out, SCS, CLSS, IDXS);
    compact_cls<<<dim3(80), blk, 0, stream>>>(SCS, CLSS, IDXS, out,
                                              GX1, GY1, GX2, GY2, GAR, GIX, NCOUNT, NBASE);
    nms_mask<<<dim3(33, 80), blk, 0, stream>>>(GX1, GY1, GX2, GY2, GAR, NCOUNT, NBASE, MASK);
    nms_scan<<<dim3(80), blk, 0, stream>>>(MASK, GIX, NCOUNT, NBASE, out + 50400);
}

// Round 12
// 2262.803 us; speedup vs baseline: 1.3023x; 1.3023x over previous
//
#include <hip/hip_runtime.h>
#include <stdint.h>

#define CONF_T 0.05f
#define NMS_T  0.5f
#define WMAX   132           // ceil(8400/64)

// ---- workspace layout (float offsets) ----
#define OFF_T3   0u
#define OFF_T4   1638400u
#define OFF_T5   2048000u
#define OFF_P3   2150400u
#define OFF_P4   3788800u
#define OFF_P5   4198400u
#define OFF_HA3  4300800u
#define OFF_HA4  5939200u
#define OFF_HA5  6348800u
#define OFF_HB3  6451200u
#define OFF_HB4  8089600u
#define OFF_HB5  8499200u
#define OFF_HD3  8601600u
#define OFF_HD4  10240000u
#define OFF_HD5  10649600u
#define OFF_CLS  10752000u
#define OFF_REG  11424000u
#define OFF_CTN  11457600u
// post-processing arrays (T3 region, free after conv stack)
#define POFF_KEYS  (OFF_T3 + 0u)
#define POFF_SCS   (OFF_T3 + 32768u)
#define POFF_CLSS  (OFF_T3 + 49152u)
#define POFF_IDXS  (OFF_T3 + 65536u)
#define POFF_GX1   (OFF_T3 + 81920u)
#define POFF_GY1   (OFF_T3 + 90320u)
#define POFF_GX2   (OFF_T3 + 98720u)
#define POFF_GY2   (OFF_T3 + 107120u)
#define POFF_GAR   (OFF_T3 + 115520u)
#define POFF_GIX   (OFF_T3 + 123920u)
#define POFF_NCNT  (OFF_T3 + 132320u)
#define POFF_NBASE (OFF_T3 + 132400u)
#define POFF_MASK  OFF_HA3

// ---------------- conv 1x1 (+ optional nearest-up2 add) ----------------
__launch_bounds__(256)
__global__ void conv1x1_kernel(const float* __restrict__ in, const float* __restrict__ w,
                               const float* __restrict__ b, float* __restrict__ out,
                               const float* __restrict__ add,
                               int Cin, int Cout, int NPX, int W, int outStride, int outBase)
{
    __shared__ float s_in[16][64];
    __shared__ float s_w[16][64];
    int t = threadIdx.x;
    int pxg = t & 31, cg = t >> 5;
    int px0 = blockIdx.x * 64;
    int co0 = blockIdx.y * 64;
    float acc[8][2];
#pragma unroll
    for (int c = 0; c < 8; ++c) { acc[c][0] = 0.f; acc[c][1] = 0.f; }
    int chunks = Cin >> 4;
    int wco = t >> 2, wpart = t & 3;
    for (int ch = 0; ch < chunks; ++ch) {
        int ci0 = ch << 4;
#pragma unroll
        for (int k = 0; k < 4; ++k) {
            int id = t + k * 256;
            int ci = id >> 6, pp = id & 63;
            int gp = px0 + pp;
            s_in[ci][pp] = (gp < NPX) ? in[(size_t)(ci0 + ci) * NPX + gp] : 0.f;
        }
        {
            int gco = co0 + wco;
            if (gco < Cout) {
                const float* run = w + (size_t)gco * Cin + ci0;
#pragma unroll
                for (int k = 0; k < 4; ++k) {
                    int e = wpart + 4 * k;
                    s_w[e][wco] = run[e];
                }
            } else {
#pragma unroll
                for (int k = 0; k < 4; ++k) s_w[wpart + 4 * k][wco] = 0.f;
            }
        }
        __syncthreads();
#pragma unroll
        for (int ci = 0; ci < 16; ++ci) {
            float i0 = s_in[ci][pxg * 2], i1 = s_in[ci][pxg * 2 + 1];
#pragma unroll
            for (int c = 0; c < 8; ++c) {
                float wv = s_w[ci][cg * 8 + c];
                acc[c][0] += wv * i0;
                acc[c][1] += wv * i1;
            }
        }
        __syncthreads();
    }
    for (int c = 0; c < 8; ++c) {
        int co = co0 + cg * 8 + c;
        if (co >= Cout) break;
        float bb = b[co];
#pragma unroll
        for (int j = 0; j < 2; ++j) {
            int p = px0 + pxg * 2 + j;
            if (p < NPX) {
                float v = acc[c][j] + bb;
                if (add) {
                    int y = p / W, x = p % W;
                    int Sp = W >> 1;
                    v += add[(size_t)co * (Sp * Sp) + (y >> 1) * Sp + (x >> 1)];
                }
                out[(size_t)co * outStride + outBase + p] = v;
            }
        }
    }
}

// ---------------- fused detector 1x1 (9 combos in one dispatch) ----------------
struct Det9 {
    const float* src[9]; const float* w[9]; const float* b[9];
    float*       dst[9];
    int cout[9], npx[9], obase[9], bstart[9], npxb[9];
};

__launch_bounds__(256)
__global__ void det1x1_fused(Det9 d)
{
    int bid = blockIdx.x;
    int q = 0;
#pragma unroll
    for (int i = 1; i < 9; ++i) if (bid >= d.bstart[i]) q = i;
    int local = bid - d.bstart[q];
    int coIdx = local / d.npxb[q];
    int pxIdx = local - coIdx * d.npxb[q];
    const float* in = d.src[q];
    const float* w  = d.w[q];
    const float* b  = d.b[q];
    float* out = d.dst[q];
    int Cout = d.cout[q], NPX = d.npx[q], outBase = d.obase[q];

    __shared__ float s_in[16][64];
    __shared__ float s_w[16][64];
    int t = threadIdx.x;
    int pxg = t & 31, cg = t >> 5;
    int px0 = pxIdx * 64;
    int co0 = coIdx * 64;
    float acc[8][2];
#pragma unroll
    for (int c = 0; c < 8; ++c) { acc[c][0] = 0.f; acc[c][1] = 0.f; }
    int wco = t >> 2, wpart = t & 3;
    for (int ch = 0; ch < 16; ++ch) {
        int ci0 = ch << 4;
#pragma unroll
        for (int k = 0; k < 4; ++k) {
            int id = t + k * 256;
            int ci = id >> 6, pp = id & 63;
            int gp = px0 + pp;
            s_in[ci][pp] = (gp < NPX) ? in[(size_t)(ci0 + ci) * NPX + gp] : 0.f;
        }
        {
            int gco = co0 + wco;
            if (gco < Cout) {
                const float* run = w + (size_t)gco * 256 + ci0;
#pragma unroll
                for (int k = 0; k < 4; ++k) {
                    int e = wpart + 4 * k;
                    s_w[e][wco] = run[e];
                }
            } else {
#pragma unroll
                for (int k = 0; k < 4; ++k) s_w[wpart + 4 * k][wco] = 0.f;
            }
        }
        __syncthreads();
#pragma unroll
        for (int ci = 0; ci < 16; ++ci) {
            float i0 = s_in[ci][pxg * 2], i1 = s_in[ci][pxg * 2 + 1];
#pragma unroll
            for (int c = 0; c < 8; ++c) {
                float wv = s_w[ci][cg * 8 + c];
                acc[c][0] += wv * i0;
                acc[c][1] += wv * i1;
            }
        }
        __syncthreads();
    }
    for (int c = 0; c < 8; ++c) {
        int co = co0 + cg * 8 + c;
        if (co >= Cout) break;
        float bb = b[co];
#pragma unroll
        for (int j = 0; j < 2; ++j) {
            int p = px0 + pxg * 2 + j;
            if (p < NPX) out[(size_t)co * 8400 + outBase + p] = acc[c][j] + bb;
        }
    }
}

// ---------------- conv 3x3 body (shared by smooth + fused heads) ----------------
// Round-9 structure + TCO=32: double-buffered LDS, register-prefetch staging,
// scalar input reads (INW=TW+3 odd, <=2-way free), broadcast float4 weight
// reads. TCO=32 halves LDS to 30.6KB and doubles the grid -> 4.4 blocks/CU
// (r9's TCO=64 left only 2.2 blocks/CU: grid-bound, FMA-issue capped at 33%).
// Forbidden (measured): b128 input reads (r7/r8 4-way conflict), global_load_lds
// (r10 vmcnt-drain regression), ANY min-waves launch bound (r7/r11 spill).
template<int TW, int TH, int TCO>
__device__ __forceinline__ void conv3x3_body(
    const float* __restrict__ src, const float* __restrict__ w,
    const float* __restrict__ bias, float* __restrict__ dst,
    int H, int W, int act, int bx0, int by0, int co0,
    float* __restrict__ sin0, float* __restrict__ sin1,
    float* __restrict__ sw0, float* __restrict__ sw1)
{
    constexpr int TPX  = TW * TH;
    constexpr int NXQ  = TW / 4;
    constexpr int PXGN = TPX / 4;
    constexpr int COG  = 256 / PXGN;
    constexpr int COPT = TCO / COG;
    constexpr int INW  = TW + 3;
    constexpr int INH  = TH + 2;
    constexpr int SW   = TW + 2;
    constexpr int INSLOTS = 8 * INH * SW;
    constexpr int KSTG = (INSLOTS + 255) / 256;
    constexpr int EPT  = 72 * TCO / 256;      // 9 for TCO=32

    int t = threadIdx.x;
    int pxg = t % PXGN, cg = t / PXGN;
    int xq = pxg % NXQ, yr = pxg / NXQ;
    int x0 = xq * 4;
    int HW = H * W;

    // ch-invariant staging descriptors
    int sl[KSTG], sg[KSTG];
#pragma unroll
    for (int k = 0; k < KSTG; ++k) {
        int id = t + k * 256;
        sl[k] = -1; sg[k] = -1;
        if (id < INSLOTS) {
            int ci = id / (INH * SW);
            int rem = id - ci * (INH * SW);
            int r = rem / SW, cc = rem - r * SW;
            sl[k] = (ci * INH + r) * INW + cc;
            int gy = by0 - 1 + r, gx = bx0 - 1 + cc;
            if (gy >= 0 && gy < H && gx >= 0 && gx < W)
                sg[k] = ci * HW + gy * W + gx;
        }
    }
    int wco = t % TCO;          // staging writes: banks distinct per half-wave
    int wpart = t / TCO;        // 256/TCO parts, EPT consecutive weights each
    const float* wbase = w + (size_t)(co0 + wco) * 2304;

    float acc[COPT][4];
#pragma unroll
    for (int c = 0; c < COPT; ++c)
#pragma unroll
        for (int i = 0; i < 4; ++i) acc[c][i] = 0.f;

    // stage chunk 0 directly
    {
#pragma unroll
        for (int k = 0; k < KSTG; ++k)
            if (sl[k] >= 0) sin0[sl[k]] = (sg[k] >= 0) ? src[sg[k]] : 0.f;
#pragma unroll
        for (int k = 0; k < EPT; ++k) {
            int e = wpart * EPT + k;
            sw0[e * TCO + wco] = wbase[e];
        }
    }
    __syncthreads();

    for (int ch = 0; ch < 32; ++ch) {
        float* cin = (ch & 1) ? sin1 : sin0;
        float* cw  = (ch & 1) ? sw1  : sw0;
        float vin[KSTG]; float vw[EPT];
        bool pf = (ch < 31);
        if (pf) {
            const float* sb = src + (size_t)((ch + 1) * 8) * HW;
            const float* wr = wbase + (ch + 1) * 72;
#pragma unroll
            for (int k = 0; k < KSTG; ++k)
                vin[k] = (sg[k] >= 0) ? sb[sg[k]] : 0.f;
#pragma unroll
            for (int k = 0; k < EPT; ++k)
                vw[k] = wr[wpart * EPT + k];
        }
        // compute chunk ch: scalar input reads, broadcast vector weight reads
        for (int ci = 0; ci < 8; ++ci) {
            float inr[3][6];
#pragma unroll
            for (int ky = 0; ky < 3; ++ky)
#pragma unroll
                for (int j = 0; j < 6; ++j)
                    inr[ky][j] = cin[(ci * INH + yr + ky) * INW + x0 + j];
            const float* wrow = cw + ci * 9 * TCO;
#pragma unroll
            for (int ky = 0; ky < 3; ++ky) {
#pragma unroll
                for (int kx = 0; kx < 3; ++kx) {
                    const float* wp = wrow + (ky * 3 + kx) * TCO + cg * COPT;
                    float wq[COPT];
                    if constexpr (COPT == 8) {
                        float4 w4a = *(const float4*)wp;
                        float4 w4b = *(const float4*)(wp + 4);
                        wq[0] = w4a.x; wq[1] = w4a.y; wq[2] = w4a.z; wq[3] = w4a.w;
                        wq[4] = w4b.x; wq[5] = w4b.y; wq[6] = w4b.z; wq[7] = w4b.w;
                    } else if constexpr (COPT == 4) {
                        float4 w4 = *(const float4*)wp;
                        wq[0] = w4.x; wq[1] = w4.y; wq[2] = w4.z; wq[3] = w4.w;
                    } else if constexpr (COPT == 2) {
                        float2 w2 = *(const float2*)wp;
                        wq[0] = w2.x; wq[1] = w2.y;
                    } else {
                        wq[0] = wp[0];
                    }
#pragma unroll
                    for (int c = 0; c < COPT; ++c) {
#pragma unroll
                        for (int i = 0; i < 4; ++i)
                            acc[c][i] += wq[c] * inr[ky][kx + i];
                    }
                }
            }
        }
        if (pf) {
            float* nin = (ch & 1) ? sin0 : sin1;
            float* nw  = (ch & 1) ? sw0  : sw1;
#pragma unroll
            for (int k = 0; k < KSTG; ++k)
                if (sl[k] >= 0) nin[sl[k]] = vin[k];
#pragma unroll
            for (int k = 0; k < EPT; ++k) {
                int e = wpart * EPT + k;
                nw[e * TCO + wco] = vw[k];
            }
        }
        __syncthreads();
    }

    int y = by0 + yr;
#pragma unroll
    for (int c = 0; c < COPT; ++c) {
        int co = co0 + cg * COPT + c;
        float bb = bias[co];
#pragma unroll
        for (int i = 0; i < 4; ++i) {
            int x = bx0 + x0 + i;
            if (x < W && y < H) {
                float v = acc[c][i] + bb;
                if (act) v = (v >= 0.f) ? v : 0.1f * v;
                dst[(size_t)co * HW + y * W + x] = v;
            }
        }
    }
}

// ---------------- smooth conv wrapper (single level) ----------------
template<int TW, int TH, int TCO>
__launch_bounds__(256)
__global__ void conv3x3_t(const float* __restrict__ src, const float* __restrict__ w,
                          const float* __restrict__ b, float* __restrict__ dst,
                          int H, int W, int act)
{
    constexpr int INW = TW + 3, INH = TH + 2;
    __shared__ __align__(16) float s_in[2][8 * INH * INW];
    __shared__ __align__(16) float s_w[2][72 * TCO];
    int nTx = (W + TW - 1) / TW;
    int tx = blockIdx.x % nTx, ty = blockIdx.x / nTx;
    conv3x3_body<TW, TH, TCO>(src, w, b, dst, H, W, act,
                              tx * TW, ty * TH, blockIdx.y * TCO,
                              s_in[0], s_in[1], s_w[0], s_w[1]);
}

// ---------------- fused 3-level head conv (one layer, both branches) ----------------
struct HeadPtrs {
    const float* src[2][3];
    float*       dst[2][3];
};

__launch_bounds__(256)
__global__ void conv3x3_heads(HeadPtrs hp, const float* __restrict__ wA,
                              const float* __restrict__ wB,
                              const float* __restrict__ bA, const float* __restrict__ bB)
{
    constexpr int TW = 16, TH = 8, TCO = 32;
    constexpr int INW = TW + 3, INH = TH + 2;
    __shared__ __align__(16) float s_in[2][8 * INH * INW];
    __shared__ __align__(16) float s_w[2][72 * TCO];

    int tb = blockIdx.x;                       // 0..70: 50 (L3) + 15 (L4) + 6 (L5)
    int lvl = (tb < 50) ? 0 : (tb < 65) ? 1 : 2;
    int tloc = tb - ((lvl == 0) ? 0 : (lvl == 1) ? 50 : 65);
    int W = (lvl == 0) ? 80 : (lvl == 1) ? 40 : 20;
    int br = blockIdx.z;
    const float* src = hp.src[br][lvl];
    float* dst = hp.dst[br][lvl];
    const float* w    = br ? wB : wA;
    const float* bias = br ? bB : bA;
    int nTx = (W + TW - 1) / TW;
    int tx = tloc % nTx, ty = tloc / nTx;
    conv3x3_body<TW, TH, TCO>(src, w, bias, dst, W, W, 1,
                              tx * TW, ty * TH, blockIdx.y * TCO,
                              s_in[0], s_in[1], s_w[0], s_w[1]);
}

// ---------------- decode: scores, argmax, boxes, sort keys ----------------
__launch_bounds__(256)
__global__ void decode_kernel(const float* __restrict__ cls, const float* __restrict__ reg,
                              const float* __restrict__ ctn, float* __restrict__ out,
                              unsigned long long* __restrict__ keys)
{
    int p = blockIdx.x * 256 + threadIdx.x;
    if (p >= 16384) return;
    if (p >= 8400) { keys[p] = ~0ull; return; }
    int base, hs; float s;
    if (p < 6400)      { base = 0;    hs = 80; s = 8.f;  }
    else if (p < 8000) { base = 6400; hs = 40; s = 16.f; }
    else               { base = 8000; hs = 20; s = 32.f; }
    int local = p - base;
    float gx = (float)(local % hs), gy = (float)(local / hs);
    float ct = ctn[p];
    float sct = 1.f / (1.f + expf(-ct));
    float best = -1.f; int arg = 0;
    for (int c = 0; c < 80; ++c) {
        float v = cls[(size_t)c * 8400 + p];
        float sv = 1.f / (1.f + expf(-v));
        float sc = sqrtf(sv * sct);
        if (sc > best) { best = sc; arg = c; }
    }
    float r0 = reg[0 * 8400 + p], r1 = reg[1 * 8400 + p];
    float r2 = reg[2 * 8400 + p], r3 = reg[3 * 8400 + p];
    float x1 = (gx - expf(r0)) * s / 640.f;
    float y1 = (gy - expf(r1)) * s / 640.f;
    float x2 = (gx + expf(r2)) * s / 640.f;
    float y2 = (gy + expf(r3)) * s / 640.f;
    x1 = fminf(fmaxf(x1, 0.f), 1.f);
    y1 = fminf(fmaxf(y1, 0.f), 1.f);
    x2 = fminf(fmaxf(x2, 0.f), 1.f);
    y2 = fminf(fmaxf(y2, 0.f), 1.f);
    out[p * 4 + 0] = x1; out[p * 4 + 1] = y1;
    out[p * 4 + 2] = x2; out[p * 4 + 3] = y2;
    out[33600 + p] = best;
    out[42000 + p] = (float)arg;
    out[50400 + p] = 0.f;
    unsigned int ub = __float_as_uint(best);
    keys[p] = ((unsigned long long)(~ub) << 32) | (unsigned int)p;
}

// ---------------- hybrid bitonic sort of 16384 u64 keys ----------------
__launch_bounds__(256)
__global__ void bitonic_local(unsigned long long* __restrict__ keys, unsigned kmerge)
{
    __shared__ unsigned long long sk[2048];
    int t = threadIdx.x;
    unsigned base = blockIdx.x * 2048u;
#pragma unroll
    for (int m = 0; m < 8; ++m) sk[t + m * 256] = keys[base + t + m * 256];
    __syncthreads();
    if (kmerge == 0u) {
        for (unsigned k = 2; k <= 2048u; k <<= 1) {
            for (unsigned j = k >> 1; j > 0; j >>= 1) {
#pragma unroll
                for (int pp = 0; pp < 4; ++pp) {
                    unsigned p = (unsigned)t + pp * 256u;
                    unsigned li = ((p & ~(j - 1)) << 1) | (p & (j - 1));
                    unsigned gi = base + li;
                    bool up = ((gi & k) == 0);
                    unsigned long long a = sk[li], b = sk[li + j];
                    if ((a > b) == up) { sk[li] = b; sk[li + j] = a; }
                }
                __syncthreads();
            }
        }
    } else {
        unsigned k = kmerge;
        for (unsigned j = 1024; j > 0; j >>= 1) {
#pragma unroll
            for (int pp = 0; pp < 4; ++pp) {
                unsigned p = (unsigned)t + pp * 256u;
                unsigned li = ((p & ~(j - 1)) << 1) | (p & (j - 1));
                unsigned gi = base + li;
                bool up = ((gi & k) == 0);
                unsigned long long a = sk[li], b = sk[li + j];
                if ((a > b) == up) { sk[li] = b; sk[li + j] = a; }
            }
            __syncthreads();
        }
    }
#pragma unroll
    for (int m = 0; m < 8; ++m) keys[base + t + m * 256] = sk[t + m * 256];
}

__launch_bounds__(256)
__global__ void bitonic_global(unsigned long long* __restrict__ keys, unsigned k, unsigned j)
{
    unsigned p = blockIdx.x * 256u + threadIdx.x;
    unsigned i = ((p & ~(j - 1)) << 1) | (p & (j - 1));
    bool up = ((i & k) == 0);
    unsigned long long a = keys[i], b = keys[i + j];
    if ((a > b) == up) { keys[i] = b; keys[i + j] = a; }
}

// ---------------- expand sorted keys into SoA arrays ----------------
__launch_bounds__(256)
__global__ void sorted_aux(const unsigned long long* __restrict__ keys,
                           const float* __restrict__ out,
                           float* __restrict__ scs, int* __restrict__ clss,
                           int* __restrict__ idxs)
{
    int i = blockIdx.x * 256 + threadIdx.x;
    if (i >= 16384) return;
    unsigned long long key = keys[i];
    unsigned ub = ~(unsigned)(key >> 32);
    float sc = __uint_as_float(ub);
    unsigned idx = (unsigned)(key & 0xffffffffu);
    int cl = -1;
    if (idx < 8400u) cl = (int)out[42000 + idx];
    else sc = 0.f;
    scs[i] = sc; clss[i] = cl; idxs[i] = (int)idx;
}

// ---------------- NMS stage 1: per-class stable compaction ----------------
__launch_bounds__(256)
__global__ void compact_cls(const float* __restrict__ scs, const int* __restrict__ clss,
                            const int* __restrict__ idxs, const float* __restrict__ outbuf,
                            float* __restrict__ GX1, float* __restrict__ GY1,
                            float* __restrict__ GX2, float* __restrict__ GY2,
                            float* __restrict__ GAR, int* __restrict__ GIX,
                            int* __restrict__ NCOUNT, int* __restrict__ NBASE)
{
    int c = blockIdx.x, t = threadIdx.x;
    __shared__ int s_red[2];
    __shared__ int s_wtot[4];
    int cb = 0, co = 0;
    for (int i = t; i < 16384; i += 256) {
        float sc = scs[i]; int cl = clss[i];
        if (sc >= CONF_T && cl >= 0) { cb += (cl < c); co += (cl == c); }
    }
    if (t == 0) { s_red[0] = 0; s_red[1] = 0; }
    __syncthreads();
    atomicAdd(&s_red[0], cb);
    atomicAdd(&s_red[1], co);
    __syncthreads();
    int base = s_red[0], n = s_red[1];
    if (t == 0) { NCOUNT[c] = n; NBASE[c] = base; }

    int rank = 0;
    for (int st = 0; st < 16384; st += 256) {
        int i = st + t;
        float sc = scs[i]; int cl = clss[i];
        bool flag = (sc >= CONF_T && cl == c);
        unsigned long long m = __ballot(flag);
        int lane = t & 63, wv = t >> 6;
        if (lane == 0) s_wtot[wv] = __popcll(m);
        __syncthreads();
        int off = rank;
        for (int w = 0; w < wv; ++w) off += s_wtot[w];
        int tot = s_wtot[0] + s_wtot[1] + s_wtot[2] + s_wtot[3];
        if (flag) {
            int pos = off + __popcll(m & ((1ull << lane) - 1ull));
            int idx = idxs[i];
            float x1 = outbuf[idx * 4 + 0], y1 = outbuf[idx * 4 + 1];
            float x2 = outbuf[idx * 4 + 2], y2 = outbuf[idx * 4 + 3];
            GX1[base + pos] = x1; GY1[base + pos] = y1;
            GX2[base + pos] = x2; GY2[base + pos] = y2;
            GAR[base + pos] = (x2 - x1) * (y2 - y1);
            GIX[base + pos] = idx;
        }
        rank += tot;
        __syncthreads();
    }
}

// ---------------- NMS stage 2: suppression bit-matrix (parallel) ----------------
__launch_bounds__(256)
__global__ void nms_mask(const float* __restrict__ GX1, const float* __restrict__ GY1,
                         const float* __restrict__ GX2, const float* __restrict__ GY2,
                         const float* __restrict__ GAR,
                         const int* __restrict__ NCOUNT, const int* __restrict__ NBASE,
                         unsigned long long* __restrict__ MASK)
{
    int c = blockIdx.y;
    int n = NCOUNT[c];
    if ((int)(blockIdx.x * 256) >= n) return;
    int base = NBASE[c];
    int t = threadIdx.x;
    int r = blockIdx.x * 256 + t;
    bool hav = (r < n);
    float rx1 = 0.f, ry1 = 0.f, rx2 = 0.f, ry2 = 0.f, rar = 0.f;
    if (hav) {
        rx1 = GX1[base + r]; ry1 = GY1[base + r];
        rx2 = GX2[base + r]; ry2 = GY2[base + r];
        rar = GAR[base + r];
    }
    __shared__ float tx1[2048], ty1[2048], tx2[2048], ty2[2048], tar[2048];
    for (int jt = 0; jt < n; jt += 2048) {
        int cnt = min(2048, n - jt);
        __syncthreads();
        for (int k = t; k < cnt; k += 256) {
            tx1[k] = GX1[base + jt + k]; ty1[k] = GY1[base + jt + k];
            tx2[k] = GX2[base + jt + k]; ty2[k] = GY2[base + jt + k];
            tar[k] = GAR[base + jt + k];
        }
        __syncthreads();
        if (hav) {
            int w0 = jt >> 6;
            int nw = (cnt + 63) >> 6;
            for (int w = 0; w < nw; ++w) {
                int jb = jt + w * 64;
                unsigned long long bits = 0ull;
                if (jb + 63 > r) {
                    int kmax = min(64, n - jb);
                    for (int kk = 0; kk < kmax; ++kk) {
                        int j = jb + kk;
                        if (j > r) {
                            int k2 = j - jt;
                            float xx1 = fmaxf(rx1, tx1[k2]);
                            float yy1 = fmaxf(ry1, ty1[k2]);
                            float xx2 = fminf(rx2, tx2[k2]);
                            float yy2 = fminf(ry2, ty2[k2]);
                            float ww = fmaxf(1e-28f, xx2 - xx1);
                            float hh = fmaxf(1e-28f, yy2 - yy1);
                            float inter = ww * hh;
                            float ovr = inter / (rar + tar[k2] - inter);
                            if (ovr > NMS_T) bits |= (1ull << kk);
                        }
                    }
                }
                MASK[(size_t)(base + r) * WMAX + w0 + w] = bits;
            }
        }
    }
}

// ---------------- NMS stage 3: chunked bitmask scan (80 blocks) ----------------
__launch_bounds__(256)
__global__ void nms_scan(const unsigned long long* __restrict__ MASK,
                         const int* __restrict__ GIX,
                         const int* __restrict__ NCOUNT, const int* __restrict__ NBASE,
                         float* __restrict__ keep)
{
    int c = blockIdx.x, t = threadIdx.x;
    int n = NCOUNT[c];
    if (n == 0) return;
    int base = NBASE[c];
    int Wc = (n + 63) >> 6;
    __shared__ unsigned long long remv[WMAX];
    __shared__ unsigned long long sld[32][WMAX];
    __shared__ unsigned int s_alive;
    for (int w = t; w < Wc; w += 256) remv[w] = 0ull;
    __syncthreads();
    for (int i0 = 0; i0 < n; i0 += 32) {
        int rows = min(32, n - i0);
        int tot = rows * Wc;
        for (int k = t; k < tot; k += 256) {
            int rr = k / Wc, w = k - rr * Wc;
            sld[rr][w] = MASK[(size_t)(base + i0 + rr) * WMAX + w];
        }
        __syncthreads();
        if (t == 0) {
            int wq = i0 >> 6, b0 = i0 & 63;
            unsigned long long lw = remv[wq];
            unsigned am = 0;
            for (int rr = 0; rr < rows; ++rr) {
                if (!((lw >> (b0 + rr)) & 1ull)) {
                    am |= (1u << rr);
                    lw |= sld[rr][wq];
                }
            }
            s_alive = am;
        }
        __syncthreads();
        unsigned am = s_alive;
        for (int w = t; w < Wc; w += 256) {
            unsigned long long acc = remv[w];
            unsigned m = am;
            while (m) { int rr = __ffs(m) - 1; m &= m - 1; acc |= sld[rr][w]; }
            remv[w] = acc;
        }
        if (t < rows && ((am >> t) & 1u)) keep[GIX[base + i0 + t]] = 1.0f;
        __syncthreads();
    }
}

// ---------------- host orchestration ----------------
extern "C" void kernel_launch(void* const* d_in, const int* in_sizes, int n_in,
                              void* d_out, int out_size, void* d_ws, size_t ws_size,
                              hipStream_t stream)
{
    const float* c3      = (const float*)d_in[0];
    const float* c4      = (const float*)d_in[1];
    const float* c5      = (const float*)d_in[2];
    const float* lat1_w  = (const float*)d_in[3];
    const float* lat1_b  = (const float*)d_in[4];
    const float* lat2_w  = (const float*)d_in[5];
    const float* lat2_b  = (const float*)d_in[6];
    const float* lat3_w  = (const float*)d_in[7];
    const float* lat3_b  = (const float*)d_in[8];
    const float* sm1_w   = (const float*)d_in[9];
    const float* sm1_b   = (const float*)d_in[10];
    const float* sm2_w   = (const float*)d_in[11];
    const float* sm2_b   = (const float*)d_in[12];
    const float* sm3_w   = (const float*)d_in[13];
    const float* sm3_b   = (const float*)d_in[14];
    const float* clsh_w  = (const float*)d_in[15];
    const float* clsh_b  = (const float*)d_in[16];
    const float* regh_w  = (const float*)d_in[17];
    const float* regh_b  = (const float*)d_in[18];
    const float* clsd_w  = (const float*)d_in[19];
    const float* clsd_b  = (const float*)d_in[20];
    const float* regd_w  = (const float*)d_in[21];
    const float* regd_b  = (const float*)d_in[22];
    const float* ctnd_w  = (const float*)d_in[23];
    const float* ctnd_b  = (const float*)d_in[24];

    float* ws = (float*)d_ws;
    float* T3 = ws + OFF_T3;  float* T4 = ws + OFF_T4;  float* T5 = ws + OFF_T5;
    float* P3 = ws + OFF_P3;  float* P4 = ws + OFF_P4;  float* P5 = ws + OFF_P5;
    float* HA3 = ws + OFF_HA3; float* HA4 = ws + OFF_HA4; float* HA5 = ws + OFF_HA5;
    float* HB3 = ws + OFF_HB3; float* HB4 = ws + OFF_HB4; float* HB5 = ws + OFF_HB5;
    float* HD3 = ws + OFF_HD3; float* HD4 = ws + OFF_HD4; float* HD5 = ws + OFF_HD5;
    float* CLS = ws + OFF_CLS; float* REG = ws + OFF_REG; float* CTN = ws + OFF_CTN;
    unsigned long long* KEYS = (unsigned long long*)(ws + POFF_KEYS);
    float* SCS = ws + POFF_SCS;
    int* CLSS = (int*)(ws + POFF_CLSS);
    int* IDXS = (int*)(ws + POFF_IDXS);
    float* GX1 = ws + POFF_GX1; float* GY1 = ws + POFF_GY1;
    float* GX2 = ws + POFF_GX2; float* GY2 = ws + POFF_GY2;
    float* GAR = ws + POFF_GAR;
    int* GIX = (int*)(ws + POFF_GIX);
    int* NCOUNT = (int*)(ws + POFF_NCNT);
    int* NBASE  = (int*)(ws + POFF_NBASE);
    unsigned long long* MASK = (unsigned long long*)(ws + POFF_MASK);

    float* out = (float*)d_out;
    dim3 blk(256);
    const size_t WSTEP = 256u * 256u * 9u;

    // ---- FPN ----
    conv1x1_kernel<<<dim3(7, 4), blk, 0, stream>>>(c5, lat3_w, lat3_b, T5, nullptr,
                                                   512, 256, 400, 20, 400, 0);
    conv3x3_t<8, 4, 32><<<dim3(15, 8), blk, 0, stream>>>(T5, sm3_w, sm3_b, P5, 20, 20, 0);
    conv1x1_kernel<<<dim3(25, 4), blk, 0, stream>>>(c4, lat2_w, lat2_b, T4, T5,
                                                    256, 256, 1600, 40, 1600, 0);
    conv3x3_t<16, 4, 32><<<dim3(30, 8), blk, 0, stream>>>(T4, sm2_w, sm2_b, P4, 40, 40, 0);
    conv1x1_kernel<<<dim3(100, 4), blk, 0, stream>>>(c3, lat1_w, lat1_b, T3, T4,
                                                     128, 256, 6400, 80, 6400, 0);
    conv3x3_t<16, 8, 32><<<dim3(50, 8), blk, 0, stream>>>(T3, sm1_w, sm1_b, P3, 80, 80, 0);

    // ---- heads: 4 fused layers, 3 levels + both branches per dispatch ----
    {
        float* clsS[3][5] = { {P3, HA3, HB3, HA3, HB3},
                              {P4, HA4, HB4, HA4, HB4},
                              {P5, HA5, HB5, HA5, HB5} };
        float* regS[3][5] = { {P3, T3,  HD3, T3,  HD3},
                              {P4, T4,  HD4, T4,  HD4},
                              {P5, T5,  HD5, T5,  HD5} };
        for (int i = 0; i < 4; ++i) {
            HeadPtrs hp;
            for (int l = 0; l < 3; ++l) {
                hp.src[0][l] = clsS[l][i];     hp.dst[0][l] = clsS[l][i + 1];
                hp.src[1][l] = regS[l][i];     hp.dst[1][l] = regS[l][i + 1];
            }
            conv3x3_heads<<<dim3(71, 8, 2), blk, 0, stream>>>(
                hp, clsh_w + (size_t)i * WSTEP, regh_w + (size_t)i * WSTEP,
                clsh_b + i * 256, regh_b + i * 256);
        }
    }

    // ---- detectors: all 9 (level x {cls,reg,ctn}) in one dispatch ----
    {
        Det9 d;
        const float* feats[3][2] = { {HB3, HD3}, {HB4, HD4}, {HB5, HD5} };
        int   npx[3]   = {6400, 1600, 400};
        int   obase[3] = {0, 6400, 8000};
        int q = 0, bacc = 0;
        for (int l = 0; l < 3; ++l) {
            d.src[q] = feats[l][0]; d.w[q] = clsd_w; d.b[q] = clsd_b; d.dst[q] = CLS;
            d.cout[q] = 80; d.npx[q] = npx[l]; d.obase[q] = obase[l];
            d.bstart[q] = bacc; d.npxb[q] = (npx[l] + 63) / 64;
            bacc += d.npxb[q] * 2; ++q;
            d.src[q] = feats[l][1]; d.w[q] = regd_w; d.b[q] = regd_b; d.dst[q] = REG;
            d.cout[q] = 4; d.npx[q] = npx[l]; d.obase[q] = obase[l];
            d.bstart[q] = bacc; d.npxb[q] = (npx[l] + 63) / 64;
            bacc += d.npxb[q]; ++q;
            d.src[q] = feats[l][1]; d.w[q] = ctnd_w; d.b[q] = ctnd_b; d.dst[q] = CTN;
            d.cout[q] = 1; d.npx[q] = npx[l]; d.obase[q] = obase[l];
            d.bstart[q] = bacc; d.npxb[q] = (npx[l] + 63) / 64;
            bacc += d.npxb[q]; ++q;
        }
        det1x1_fused<<<dim3(bacc), blk, 0, stream>>>(d);
    }

    // ---- decode ----
    decode_kernel<<<dim3(64), blk, 0, stream>>>(CLS, REG, CTN, out, KEYS);

    // ---- hybrid bitonic sort ----
    bitonic_local<<<dim3(8), blk, 0, stream>>>(KEYS, 0u);
    bitonic_global<<<dim3(32), blk, 0, stream>>>(KEYS, 4096u, 2048u);
    bitonic_local<<<dim3(8), blk, 0, stream>>>(KEYS, 4096u);
    bitonic_global<<<dim3(32), blk, 0, stream>>>(KEYS, 8192u, 4096u);
    bitonic_global<<<dim3(32), blk, 0, stream>>>(KEYS, 8192u, 2048u);
    bitonic_local<<<dim3(8), blk, 0, stream>>>(KEYS, 8192u);
    bitonic_global<<<dim3(32), blk, 0, stream>>>(KEYS, 16384u, 8192u);
    bitonic_global<<<dim3(32), blk, 0, stream>>>(KEYS, 16384u, 4096u);
    bitonic_global<<<dim3(32), blk, 0, stream>>>(KEYS, 16384u, 2048u);
    bitonic_local<<<dim3(8), blk, 0, stream>>>(KEYS, 16384u);

    // ---- NMS pipeline ----
    sorted_aux<<<dim3(64), blk, 0, stream>>>(KEYS, out, SCS, CLSS, IDXS);
    compact_cls<<<dim3(80), blk, 0, stream>>>(SCS, CLSS, IDXS, out,
                                              GX1, GY1, GX2, GY2, GAR, GIX, NCOUNT, NBASE);
    nms_mask<<<dim3(33, 80), blk, 0, stream>>>(GX1, GY1, GX2, GY2, GAR, NCOUNT, NBASE, MASK);
    nms_scan<<<dim3(80), blk, 0, stream>>>(MASK, GIX, NCOUNT, NBASE, out + 50400);
}

// Round 13
// 1640.633 us; speedup vs baseline: 1.7962x; 1.3792x over previous
//
#include <hip/hip_runtime.h>
#include <stdint.h>

#define CONF_T 0.05f
#define NMS_T  0.5f
#define WMAX   132           // ceil(8400/64)
#define WSTEP9 589824        // 256*256*9

typedef _Float16 f16x8 __attribute__((ext_vector_type(8)));
typedef _Float16 f16x2 __attribute__((ext_vector_type(2)));
typedef float    f32x4 __attribute__((ext_vector_type(4)));
#define MFMA16 __builtin_amdgcn_mfma_f32_16x16x32_f16

// ---- workspace layout (float offsets) ----
#define OFF_T3   0u
#define OFF_T4   1638400u
#define OFF_T5   2048000u
#define OFF_P3   2150400u
#define OFF_P4   3788800u
#define OFF_P5   4198400u
#define OFF_HA3  4300800u
#define OFF_HA4  5939200u
#define OFF_HA5  6348800u
#define OFF_HB3  6451200u
#define OFF_HB4  8089600u
#define OFF_HB5  8499200u
#define OFF_HD3  8601600u
#define OFF_HD4  10240000u
#define OFF_HD5  10649600u
#define OFF_CLS  10752000u
#define OFF_REG  11424000u
#define OFF_CTN  11457600u
#define OFF_W2H  11466000u                 // 11 matrices x 589824 f16 (hi)
#define OFF_W2L  14710032u                 // (lo)
#define WS_NEED  17954064u                 // floats required for MFMA path
// post-processing arrays (T3 region, free after conv stack)
#define POFF_KEYS  (OFF_T3 + 0u)
#define POFF_SCS   (OFF_T3 + 32768u)
#define POFF_CLSS  (OFF_T3 + 49152u)
#define POFF_IDXS  (OFF_T3 + 65536u)
#define POFF_GX1   (OFF_T3 + 81920u)
#define POFF_GY1   (OFF_T3 + 90320u)
#define POFF_GX2   (OFF_T3 + 98720u)
#define POFF_GY2   (OFF_T3 + 107120u)
#define POFF_GAR   (OFF_T3 + 115520u)
#define POFF_GIX   (OFF_T3 + 123920u)
#define POFF_NCNT  (OFF_T3 + 132320u)
#define POFF_NBASE (OFF_T3 + 132400u)
#define POFF_MASK  OFF_HA3

// ---------------- conv 1x1 (+ optional nearest-up2 add) ----------------
__launch_bounds__(256)
__global__ void conv1x1_kernel(const float* __restrict__ in, const float* __restrict__ w,
                               const float* __restrict__ b, float* __restrict__ out,
                               const float* __restrict__ add,
                               int Cin, int Cout, int NPX, int W, int outStride, int outBase)
{
    __shared__ float s_in[16][64];
    __shared__ float s_w[16][64];
    int t = threadIdx.x;
    int pxg = t & 31, cg = t >> 5;
    int px0 = blockIdx.x * 64;
    int co0 = blockIdx.y * 64;
    float acc[8][2];
#pragma unroll
    for (int c = 0; c < 8; ++c) { acc[c][0] = 0.f; acc[c][1] = 0.f; }
    int chunks = Cin >> 4;
    int wco = t >> 2, wpart = t & 3;
    for (int ch = 0; ch < chunks; ++ch) {
        int ci0 = ch << 4;
#pragma unroll
        for (int k = 0; k < 4; ++k) {
            int id = t + k * 256;
            int ci = id >> 6, pp = id & 63;
            int gp = px0 + pp;
            s_in[ci][pp] = (gp < NPX) ? in[(size_t)(ci0 + ci) * NPX + gp] : 0.f;
        }
        {
            int gco = co0 + wco;
            if (gco < Cout) {
                const float* run = w + (size_t)gco * Cin + ci0;
#pragma unroll
                for (int k = 0; k < 4; ++k) {
                    int e = wpart + 4 * k;
                    s_w[e][wco] = run[e];
                }
            } else {
#pragma unroll
                for (int k = 0; k < 4; ++k) s_w[wpart + 4 * k][wco] = 0.f;
            }
        }
        __syncthreads();
#pragma unroll
        for (int ci = 0; ci < 16; ++ci) {
            float i0 = s_in[ci][pxg * 2], i1 = s_in[ci][pxg * 2 + 1];
#pragma unroll
            for (int c = 0; c < 8; ++c) {
                float wv = s_w[ci][cg * 8 + c];
                acc[c][0] += wv * i0;
                acc[c][1] += wv * i1;
            }
        }
        __syncthreads();
    }
    for (int c = 0; c < 8; ++c) {
        int co = co0 + cg * 8 + c;
        if (co >= Cout) break;
        float bb = b[co];
#pragma unroll
        for (int j = 0; j < 2; ++j) {
            int p = px0 + pxg * 2 + j;
            if (p < NPX) {
                float v = acc[c][j] + bb;
                if (add) {
                    int y = p / W, x = p % W;
                    int Sp = W >> 1;
                    v += add[(size_t)co * (Sp * Sp) + (y >> 1) * Sp + (x >> 1)];
                }
                out[(size_t)co * outStride + outBase + p] = v;
            }
        }
    }
}

// ---------------- fused detector 1x1 (9 combos in one dispatch) ----------------
struct Det9 {
    const float* src[9]; const float* w[9]; const float* b[9];
    float*       dst[9];
    int cout[9], npx[9], obase[9], bstart[9], npxb[9];
};

__launch_bounds__(256)
__global__ void det1x1_fused(Det9 d)
{
    int bid = blockIdx.x;
    int q = 0;
#pragma unroll
    for (int i = 1; i < 9; ++i) if (bid >= d.bstart[i]) q = i;
    int local = bid - d.bstart[q];
    int coIdx = local / d.npxb[q];
    int pxIdx = local - coIdx * d.npxb[q];
    const float* in = d.src[q];
    const float* w  = d.w[q];
    const float* b  = d.b[q];
    float* out = d.dst[q];
    int Cout = d.cout[q], NPX = d.npx[q], outBase = d.obase[q];

    __shared__ float s_in[16][64];
    __shared__ float s_w[16][64];
    int t = threadIdx.x;
    int pxg = t & 31, cg = t >> 5;
    int px0 = pxIdx * 64;
    int co0 = coIdx * 64;
    float acc[8][2];
#pragma unroll
    for (int c = 0; c < 8; ++c) { acc[c][0] = 0.f; acc[c][1] = 0.f; }
    int wco = t >> 2, wpart = t & 3;
    for (int ch = 0; ch < 16; ++ch) {
        int ci0 = ch << 4;
#pragma unroll
        for (int k = 0; k < 4; ++k) {
            int id = t + k * 256;
            int ci = id >> 6, pp = id & 63;
            int gp = px0 + pp;
            s_in[ci][pp] = (gp < NPX) ? in[(size_t)(ci0 + ci) * NPX + gp] : 0.f;
        }
        {
            int gco = co0 + wco;
            if (gco < Cout) {
                const float* run = w + (size_t)gco * 256 + ci0;
#pragma unroll
                for (int k = 0; k < 4; ++k) {
                    int e = wpart + 4 * k;
                    s_w[e][wco] = run[e];
                }
            } else {
#pragma unroll
                for (int k = 0; k < 4; ++k) s_w[wpart + 4 * k][wco] = 0.f;
            }
        }
        __syncthreads();
#pragma unroll
        for (int ci = 0; ci < 16; ++ci) {
            float i0 = s_in[ci][pxg * 2], i1 = s_in[ci][pxg * 2 + 1];
#pragma unroll
            for (int c = 0; c < 8; ++c) {
                float wv = s_w[ci][cg * 8 + c];
                acc[c][0] += wv * i0;
                acc[c][1] += wv * i1;
            }
        }
        __syncthreads();
    }
    for (int c = 0; c < 8; ++c) {
        int co = co0 + cg * 8 + c;
        if (co >= Cout) break;
        float bb = b[co];
#pragma unroll
        for (int j = 0; j < 2; ++j) {
            int p = px0 + pxg * 2 + j;
            if (p < NPX) out[(size_t)co * 8400 + outBase + p] = acc[c][j] + bb;
        }
    }
}

// ---------------- fp32 conv3x3 (fallback path, r12 config) ----------------
template<int TW, int TH, int TCO>
__device__ __forceinline__ void conv3x3_body(
    const float* __restrict__ src, const float* __restrict__ w,
    const float* __restrict__ bias, float* __restrict__ dst,
    int H, int W, int act, int bx0, int by0, int co0,
    float* __restrict__ sin0, float* __restrict__ sin1,
    float* __restrict__ sw0, float* __restrict__ sw1)
{
    constexpr int TPX  = TW * TH;
    constexpr int NXQ  = TW / 4;
    constexpr int PXGN = TPX / 4;
    constexpr int COG  = 256 / PXGN;
    constexpr int COPT = TCO / COG;
    constexpr int INW  = TW + 3;
    constexpr int INH  = TH + 2;
    constexpr int SW   = TW + 2;
    constexpr int INSLOTS = 8 * INH * SW;
    constexpr int KSTG = (INSLOTS + 255) / 256;
    constexpr int EPT  = 72 * TCO / 256;

    int t = threadIdx.x;
    int pxg = t % PXGN, cg = t / PXGN;
    int xq = pxg % NXQ, yr = pxg / NXQ;
    int x0 = xq * 4;
    int HW = H * W;

    int sl[KSTG], sg[KSTG];
#pragma unroll
    for (int k = 0; k < KSTG; ++k) {
        int id = t + k * 256;
        sl[k] = -1; sg[k] = -1;
        if (id < INSLOTS) {
            int ci = id / (INH * SW);
            int rem = id - ci * (INH * SW);
            int r = rem / SW, cc = rem - r * SW;
            sl[k] = (ci * INH + r) * INW + cc;
            int gy = by0 - 1 + r, gx = bx0 - 1 + cc;
            if (gy >= 0 && gy < H && gx >= 0 && gx < W)
                sg[k] = ci * HW + gy * W + gx;
        }
    }
    int wco = t % TCO;
    int wpart = t / TCO;
    const float* wbase = w + (size_t)(co0 + wco) * 2304;

    float acc[COPT][4];
#pragma unroll
    for (int c = 0; c < COPT; ++c)
#pragma unroll
        for (int i = 0; i < 4; ++i) acc[c][i] = 0.f;

    {
#pragma unroll
        for (int k = 0; k < KSTG; ++k)
            if (sl[k] >= 0) sin0[sl[k]] = (sg[k] >= 0) ? src[sg[k]] : 0.f;
#pragma unroll
        for (int k = 0; k < EPT; ++k) {
            int e = wpart * EPT + k;
            sw0[e * TCO + wco] = wbase[e];
        }
    }
    __syncthreads();

    for (int ch = 0; ch < 32; ++ch) {
        float* cin = (ch & 1) ? sin1 : sin0;
        float* cw  = (ch & 1) ? sw1  : sw0;
        float vin[KSTG]; float vw[EPT];
        bool pf = (ch < 31);
        if (pf) {
            const float* sb = src + (size_t)((ch + 1) * 8) * HW;
            const float* wr = wbase + (ch + 1) * 72;
#pragma unroll
            for (int k = 0; k < KSTG; ++k)
                vin[k] = (sg[k] >= 0) ? sb[sg[k]] : 0.f;
#pragma unroll
            for (int k = 0; k < EPT; ++k)
                vw[k] = wr[wpart * EPT + k];
        }
        for (int ci = 0; ci < 8; ++ci) {
            float inr[3][6];
#pragma unroll
            for (int ky = 0; ky < 3; ++ky)
#pragma unroll
                for (int j = 0; j < 6; ++j)
                    inr[ky][j] = cin[(ci * INH + yr + ky) * INW + x0 + j];
            const float* wrow = cw + ci * 9 * TCO;
#pragma unroll
            for (int ky = 0; ky < 3; ++ky) {
#pragma unroll
                for (int kx = 0; kx < 3; ++kx) {
                    const float* wp = wrow + (ky * 3 + kx) * TCO + cg * COPT;
                    float wq[COPT];
                    if constexpr (COPT == 4) {
                        float4 w4 = *(const float4*)wp;
                        wq[0] = w4.x; wq[1] = w4.y; wq[2] = w4.z; wq[3] = w4.w;
                    } else if constexpr (COPT == 2) {
                        float2 w2 = *(const float2*)wp;
                        wq[0] = w2.x; wq[1] = w2.y;
                    } else {
                        wq[0] = wp[0];
                    }
#pragma unroll
                    for (int c = 0; c < COPT; ++c) {
#pragma unroll
                        for (int i = 0; i < 4; ++i)
                            acc[c][i] += wq[c] * inr[ky][kx + i];
                    }
                }
            }
        }
        if (pf) {
            float* nin = (ch & 1) ? sin0 : sin1;
            float* nw  = (ch & 1) ? sw0  : sw1;
#pragma unroll
            for (int k = 0; k < KSTG; ++k)
                if (sl[k] >= 0) nin[sl[k]] = vin[k];
#pragma unroll
            for (int k = 0; k < EPT; ++k) {
                int e = wpart * EPT + k;
                nw[e * TCO + wco] = vw[k];
            }
        }
        __syncthreads();
    }

    int y = by0 + yr;
#pragma unroll
    for (int c = 0; c < COPT; ++c) {
        int co = co0 + cg * COPT + c;
        float bb = bias[co];
#pragma unroll
        for (int i = 0; i < 4; ++i) {
            int x = bx0 + x0 + i;
            if (x < W && y < H) {
                float v = acc[c][i] + bb;
                if (act) v = (v >= 0.f) ? v : 0.1f * v;
                dst[(size_t)co * HW + y * W + x] = v;
            }
        }
    }
}

template<int TW, int TH, int TCO>
__launch_bounds__(256)
__global__ void conv3x3_t(const float* __restrict__ src, const float* __restrict__ w,
                          const float* __restrict__ b, float* __restrict__ dst,
                          int H, int W, int act)
{
    constexpr int INW = TW + 3, INH = TH + 2;
    __shared__ __align__(16) float s_in[2][8 * INH * INW];
    __shared__ __align__(16) float s_w[2][72 * TCO];
    int nTx = (W + TW - 1) / TW;
    int tx = blockIdx.x % nTx, ty = blockIdx.x / nTx;
    conv3x3_body<TW, TH, TCO>(src, w, b, dst, H, W, act,
                              tx * TW, ty * TH, blockIdx.y * TCO,
                              s_in[0], s_in[1], s_w[0], s_w[1]);
}

struct HeadPtrs {
    const float* src[2][3];
    float*       dst[2][3];
};

__launch_bounds__(256)
__global__ void conv3x3_heads(HeadPtrs hp, const float* __restrict__ wA,
                              const float* __restrict__ wB,
                              const float* __restrict__ bA, const float* __restrict__ bB)
{
    constexpr int TW = 16, TH = 8, TCO = 32;
    constexpr int INW = TW + 3, INH = TH + 2;
    __shared__ __align__(16) float s_in[2][8 * INH * INW];
    __shared__ __align__(16) float s_w[2][72 * TCO];

    int tb = blockIdx.x;
    int lvl = (tb < 50) ? 0 : (tb < 65) ? 1 : 2;
    int tloc = tb - ((lvl == 0) ? 0 : (lvl == 1) ? 50 : 65);
    int W = (lvl == 0) ? 80 : (lvl == 1) ? 40 : 20;
    int br = blockIdx.z;
    const float* src = hp.src[br][lvl];
    float* dst = hp.dst[br][lvl];
    const float* w    = br ? wB : wA;
    const float* bias = br ? bB : bA;
    int nTx = (W + TW - 1) / TW;
    int tx = tloc % nTx, ty = tloc / nTx;
    conv3x3_body<TW, TH, TCO>(src, w, bias, dst, W, W, 1,
                              tx * TW, ty * TH, blockIdx.y * TCO,
                              s_in[0], s_in[1], s_w[0], s_w[1]);
}

// ---------------- MFMA path: weight f16 hi/lo prep ----------------
// 11 matrices: 0-3 cls layers, 4-7 reg layers, 8-10 smooth sm1/sm2/sm3.
// dst layout [m][tap][cout][ci] f16 (natural ci order; A/B consistency makes
// the hw k-interleave irrelevant).
__launch_bounds__(256)
__global__ void w2prep(const float* __restrict__ clsh_w, const float* __restrict__ regh_w,
                       const float* __restrict__ sm1_w, const float* __restrict__ sm2_w,
                       const float* __restrict__ sm3_w,
                       _Float16* __restrict__ WH, _Float16* __restrict__ WL)
{
    int idx = blockIdx.x * 256 + threadIdx.x;
    if (idx >= 11 * WSTEP9) return;
    int m = idx / WSTEP9, e = idx - m * WSTEP9;
    int co = e / 2304, r2 = e - co * 2304;
    int ci = r2 / 9, tap = r2 - ci * 9;
    const float* srcb;
    if (m < 4)       srcb = clsh_w + (size_t)m * WSTEP9;
    else if (m < 8)  srcb = regh_w + (size_t)(m - 4) * WSTEP9;
    else if (m == 8) srcb = sm1_w;
    else if (m == 9) srcb = sm2_w;
    else             srcb = sm3_w;
    float f = srcb[(size_t)co * 2304 + ci * 9 + tap];
    _Float16 h = (_Float16)f;
    _Float16 l = (_Float16)(f - (float)h);
    size_t d = (size_t)m * WSTEP9 + ((size_t)(tap * 256 + co)) * 256 + ci;
    WH[d] = h; WL[d] = l;
}

// ---------------- MFMA conv3x3 (fp16 3-term split) ----------------
// Block: 64px (16x4) x 64cout; 4 waves: cw=wid&1 (32co), pw=wid>>1 (2 px rows).
// Input LDS: 6x18 halo cells x 32 ci, CPAD=40 f16 (16B-aligned b128 frags,
// col stride 20 dwords -> <=2-way). Weights read from prepped global (L2-hot).
// D[m=cout][n=px]; C/D map: col=lane&15, row=(lane>>4)*4+reg (HW-verified).
struct MC {
    const float*    src[2][3];
    float*          dst[2][3];
    const _Float16* wh[2][3];
    const _Float16* wl[2][3];
    const float*    bias[2][3];
    int act;
};

__launch_bounds__(256)
__global__ void mconv3x3(MC p)
{
    __shared__ __align__(16) _Float16 SH[2][108 * 40];
    __shared__ __align__(16) _Float16 SL[2][108 * 40];
    int t = threadIdx.x;
    int tb = blockIdx.x;                      // 0..139: 100 L3, 30 L4, 10 L5
    int lvl = (tb < 100) ? 0 : (tb < 130) ? 1 : 2;
    int tloc = tb - ((lvl == 0) ? 0 : (lvl == 1) ? 100 : 130);
    int W = (lvl == 0) ? 80 : (lvl == 1) ? 40 : 20;
    int nTx = (lvl == 0) ? 5 : (lvl == 1) ? 3 : 2;
    int HW = W * W;
    int bx0 = (tloc % nTx) * 16, by0 = (tloc / nTx) * 4;
    int br = blockIdx.z;
    int co0 = blockIdx.y * 64;
    const float* src = p.src[br][lvl];
    float* dst = p.dst[br][lvl];
    const _Float16* wh = p.wh[br][lvl];
    const _Float16* wl = p.wl[br][lvl];
    const float* bias = p.bias[br][lvl];

    int lane = t & 63, wid = t >> 6;
    int cw = wid & 1, pw = wid >> 1;
    int colc = lane & 15, g = lane >> 4;

    // staging descriptors: 1728 ci-pair slots (108 cells x 16 pairs)
    int sgo[7], sla[7];
#pragma unroll
    for (int k = 0; k < 7; ++k) {
        int s2 = t + k * 256;
        sgo[k] = -1; sla[k] = 0;
        if (s2 < 1728) {
            int ci2 = s2 / 108, cell = s2 - ci2 * 108;
            int r = cell / 18, c = cell - r * 18;
            sla[k] = cell * 40 + ci2 * 2;
            int gy = by0 - 1 + r, gx = bx0 - 1 + c;
            if (gy >= 0 && gy < W && gx >= 0 && gx < W)
                sgo[k] = (ci2 * 2) * HW + gy * W + gx;
        }
    }

    f32x4 acc[2][2];
#pragma unroll
    for (int mi = 0; mi < 2; ++mi)
#pragma unroll
        for (int ny = 0; ny < 2; ++ny) acc[mi][ny] = (f32x4)0.f;

    // stage chunk 0
#pragma unroll
    for (int k = 0; k < 7; ++k) {
        if (t + k * 256 < 1728) {
            float v0 = 0.f, v1 = 0.f;
            if (sgo[k] >= 0) { v0 = src[sgo[k]]; v1 = src[sgo[k] + HW]; }
            _Float16 h0 = (_Float16)v0, h1 = (_Float16)v1;
            _Float16 l0 = (_Float16)(v0 - (float)h0), l1 = (_Float16)(v1 - (float)h1);
            f16x2 ph = {h0, h1}, pl = {l0, l1};
            *(f16x2*)&SH[0][sla[k]] = ph;
            *(f16x2*)&SL[0][sla[k]] = pl;
        }
    }
    __syncthreads();

    int coA = co0 + cw * 32 + colc;
    for (int ck = 0; ck < 8; ++ck) {
        const _Float16* sh  = SH[ck & 1];
        const _Float16* sl_ = SL[ck & 1];
        float pv[14];
        bool pf = (ck < 7);
        if (pf) {
            const float* sb = src + (size_t)(ck + 1) * 32 * HW;
#pragma unroll
            for (int k = 0; k < 7; ++k) {
                pv[2 * k] = 0.f; pv[2 * k + 1] = 0.f;
                if (t + k * 256 < 1728 && sgo[k] >= 0) {
                    pv[2 * k] = sb[sgo[k]]; pv[2 * k + 1] = sb[sgo[k] + HW];
                }
            }
        }
#pragma unroll
        for (int tap = 0; tap < 9; ++tap) {
            int ky = tap / 3, kx = tap - ky * 3;
            size_t a0 = ((size_t)(tap * 256 + coA)) * 256 + ck * 32 + g * 8;
            f16x8 a0h = *(const f16x8*)(wh + a0);
            f16x8 a0l = *(const f16x8*)(wl + a0);
            f16x8 a1h = *(const f16x8*)(wh + a0 + 4096);
            f16x8 a1l = *(const f16x8*)(wl + a0 + 4096);
#pragma unroll
            for (int ny = 0; ny < 2; ++ny) {
                int cell = (pw * 2 + ny + ky) * 18 + colc + kx;
                f16x8 bh = *(const f16x8*)(sh  + cell * 40 + g * 8);
                f16x8 bl = *(const f16x8*)(sl_ + cell * 40 + g * 8);
                acc[0][ny] = MFMA16(a0h, bh, acc[0][ny], 0, 0, 0);
                acc[0][ny] = MFMA16(a0h, bl, acc[0][ny], 0, 0, 0);
                acc[0][ny] = MFMA16(a0l, bh, acc[0][ny], 0, 0, 0);
                acc[1][ny] = MFMA16(a1h, bh, acc[1][ny], 0, 0, 0);
                acc[1][ny] = MFMA16(a1h, bl, acc[1][ny], 0, 0, 0);
                acc[1][ny] = MFMA16(a1l, bh, acc[1][ny], 0, 0, 0);
            }
        }
        if (pf) {
            _Float16* nh = SH[(ck + 1) & 1];
            _Float16* nl = SL[(ck + 1) & 1];
#pragma unroll
            for (int k = 0; k < 7; ++k) {
                if (t + k * 256 < 1728) {
                    float v0 = pv[2 * k], v1 = pv[2 * k + 1];
                    _Float16 h0 = (_Float16)v0, h1 = (_Float16)v1;
                    _Float16 l0 = (_Float16)(v0 - (float)h0), l1 = (_Float16)(v1 - (float)h1);
                    f16x2 ph = {h0, h1}, pl = {l0, l1};
                    *(f16x2*)&nh[sla[k]] = ph;
                    *(f16x2*)&nl[sla[k]] = pl;
                }
            }
        }
        __syncthreads();
    }

    int x = bx0 + colc;
    if (x < W) {
#pragma unroll
        for (int mi = 0; mi < 2; ++mi) {
            int cob = co0 + cw * 32 + mi * 16 + g * 4;
#pragma unroll
            for (int ny = 0; ny < 2; ++ny) {
                int y = by0 + pw * 2 + ny;
#pragma unroll
                for (int i = 0; i < 4; ++i) {
                    int co = cob + i;
                    float v = acc[mi][ny][i] + bias[co];
                    if (p.act) v = (v >= 0.f) ? v : 0.1f * v;
                    dst[(size_t)co * HW + y * W + x] = v;
                }
            }
        }
    }
}

// ---------------- decode: scores, argmax, boxes, sort keys ----------------
__launch_bounds__(256)
__global__ void decode_kernel(const float* __restrict__ cls, const float* __restrict__ reg,
                              const float* __restrict__ ctn, float* __restrict__ out,
                              unsigned long long* __restrict__ keys)
{
    int p = blockIdx.x * 256 + threadIdx.x;
    if (p >= 16384) return;
    if (p >= 8400) { keys[p] = ~0ull; return; }
    int base, hs; float s;
    if (p < 6400)      { base = 0;    hs = 80; s = 8.f;  }
    else if (p < 8000) { base = 6400; hs = 40; s = 16.f; }
    else               { base = 8000; hs = 20; s = 32.f; }
    int local = p - base;
    float gx = (float)(local % hs), gy = (float)(local / hs);
    float ct = ctn[p];
    float sct = 1.f / (1.f + expf(-ct));
    float best = -1.f; int arg = 0;
    for (int c = 0; c < 80; ++c) {
        float v = cls[(size_t)c * 8400 + p];
        float sv = 1.f / (1.f + expf(-v));
        float sc = sqrtf(sv * sct);
        if (sc > best) { best = sc; arg = c; }
    }
    float r0 = reg[0 * 8400 + p], r1 = reg[1 * 8400 + p];
    float r2 = reg[2 * 8400 + p], r3 = reg[3 * 8400 + p];
    float x1 = (gx - expf(r0)) * s / 640.f;
    float y1 = (gy - expf(r1)) * s / 640.f;
    float x2 = (gx + expf(r2)) * s / 640.f;
    float y2 = (gy + expf(r3)) * s / 640.f;
    x1 = fminf(fmaxf(x1, 0.f), 1.f);
    y1 = fminf(fmaxf(y1, 0.f), 1.f);
    x2 = fminf(fmaxf(x2, 0.f), 1.f);
    y2 = fminf(fmaxf(y2, 0.f), 1.f);
    out[p * 4 + 0] = x1; out[p * 4 + 1] = y1;
    out[p * 4 + 2] = x2; out[p * 4 + 3] = y2;
    out[33600 + p] = best;
    out[42000 + p] = (float)arg;
    out[50400 + p] = 0.f;
    unsigned int ub = __float_as_uint(best);
    keys[p] = ((unsigned long long)(~ub) << 32) | (unsigned int)p;
}

// ---------------- hybrid bitonic sort of 16384 u64 keys ----------------
__launch_bounds__(256)
__global__ void bitonic_local(unsigned long long* __restrict__ keys, unsigned kmerge)
{
    __shared__ unsigned long long sk[2048];
    int t = threadIdx.x;
    unsigned base = blockIdx.x * 2048u;
#pragma unroll
    for (int m = 0; m < 8; ++m) sk[t + m * 256] = keys[base + t + m * 256];
    __syncthreads();
    if (kmerge == 0u) {
        for (unsigned k = 2; k <= 2048u; k <<= 1) {
            for (unsigned j = k >> 1; j > 0; j >>= 1) {
#pragma unroll
                for (int pp = 0; pp < 4; ++pp) {
                    unsigned p = (unsigned)t + pp * 256u;
                    unsigned li = ((p & ~(j - 1)) << 1) | (p & (j - 1));
                    unsigned gi = base + li;
                    bool up = ((gi & k) == 0);
                    unsigned long long a = sk[li], b = sk[li + j];
                    if ((a > b) == up) { sk[li] = b; sk[li + j] = a; }
                }
                __syncthreads();
            }
        }
    } else {
        unsigned k = kmerge;
        for (unsigned j = 1024; j > 0; j >>= 1) {
#pragma unroll
            for (int pp = 0; pp < 4; ++pp) {
                unsigned p = (unsigned)t + pp * 256u;
                unsigned li = ((p & ~(j - 1)) << 1) | (p & (j - 1));
                unsigned gi = base + li;
                bool up = ((gi & k) == 0);
                unsigned long long a = sk[li], b = sk[li + j];
                if ((a > b) == up) { sk[li] = b; sk[li + j] = a; }
            }
            __syncthreads();
        }
    }
#pragma unroll
    for (int m = 0; m < 8; ++m) keys[base + t + m * 256] = sk[t + m * 256];
}

__launch_bounds__(256)
__global__ void bitonic_global(unsigned long long* __restrict__ keys, unsigned k, unsigned j)
{
    unsigned p = blockIdx.x * 256u + threadIdx.x;
    unsigned i = ((p & ~(j - 1)) << 1) | (p & (j - 1));
    bool up = ((i & k) == 0);
    unsigned long long a = keys[i], b = keys[i + j];
    if ((a > b) == up) { keys[i] = b; keys[i + j] = a; }
}

// ---------------- expand sorted keys into SoA arrays ----------------
__launch_bounds__(256)
__global__ void sorted_aux(const unsigned long long* __restrict__ keys,
                           const float* __restrict__ out,
                           float* __restrict__ scs, int* __restrict__ clss,
                           int* __restrict__ idxs)
{
    int i = blockIdx.x * 256 + threadIdx.x;
    if (i >= 16384) return;
    unsigned long long key = keys[i];
    unsigned ub = ~(unsigned)(key >> 32);
    float sc = __uint_as_float(ub);
    unsigned idx = (unsigned)(key & 0xffffffffu);
    int cl = -1;
    if (idx < 8400u) cl = (int)out[42000 + idx];
    else sc = 0.f;
    scs[i] = sc; clss[i] = cl; idxs[i] = (int)idx;
}

// ---------------- NMS stage 1: per-class stable compaction ----------------
__launch_bounds__(256)
__global__ void compact_cls(const float* __restrict__ scs, const int* __restrict__ clss,
                            const int* __restrict__ idxs, const float* __restrict__ outbuf,
                            float* __restrict__ GX1, float* __restrict__ GY1,
                            float* __restrict__ GX2, float* __restrict__ GY2,
                            float* __restrict__ GAR, int* __restrict__ GIX,
                            int* __restrict__ NCOUNT, int* __restrict__ NBASE)
{
    int c = blockIdx.x, t = threadIdx.x;
    __shared__ int s_red[2];
    __shared__ int s_wtot[4];
    int cb = 0, co = 0;
    for (int i = t; i < 16384; i += 256) {
        float sc = scs[i]; int cl = clss[i];
        if (sc >= CONF_T && cl >= 0) { cb += (cl < c); co += (cl == c); }
    }
    if (t == 0) { s_red[0] = 0; s_red[1] = 0; }
    __syncthreads();
    atomicAdd(&s_red[0], cb);
    atomicAdd(&s_red[1], co);
    __syncthreads();
    int base = s_red[0], n = s_red[1];
    if (t == 0) { NCOUNT[c] = n; NBASE[c] = base; }

    int rank = 0;
    for (int st = 0; st < 16384; st += 256) {
        int i = st + t;
        float sc = scs[i]; int cl = clss[i];
        bool flag = (sc >= CONF_T && cl == c);
        unsigned long long m = __ballot(flag);
        int lane = t & 63, wv = t >> 6;
        if (lane == 0) s_wtot[wv] = __popcll(m);
        __syncthreads();
        int off = rank;
        for (int w = 0; w < wv; ++w) off += s_wtot[w];
        int tot = s_wtot[0] + s_wtot[1] + s_wtot[2] + s_wtot[3];
        if (flag) {
            int pos = off + __popcll(m & ((1ull << lane) - 1ull));
            int idx = idxs[i];
            float x1 = outbuf[idx * 4 + 0], y1 = outbuf[idx * 4 + 1];
            float x2 = outbuf[idx * 4 + 2], y2 = outbuf[idx * 4 + 3];
            GX1[base + pos] = x1; GY1[base + pos] = y1;
            GX2[base + pos] = x2; GY2[base + pos] = y2;
            GAR[base + pos] = (x2 - x1) * (y2 - y1);
            GIX[base + pos] = idx;
        }
        rank += tot;
        __syncthreads();
    }
}

// ---------------- NMS stage 2: suppression bit-matrix (parallel) ----------------
__launch_bounds__(256)
__global__ void nms_mask(const float* __restrict__ GX1, const float* __restrict__ GY1,
                         const float* __restrict__ GX2, const float* __restrict__ GY2,
                         const float* __restrict__ GAR,
                         const int* __restrict__ NCOUNT, const int* __restrict__ NBASE,
                         unsigned long long* __restrict__ MASK)
{
    int c = blockIdx.y;
    int n = NCOUNT[c];
    if ((int)(blockIdx.x * 256) >= n) return;
    int base = NBASE[c];
    int t = threadIdx.x;
    int r = blockIdx.x * 256 + t;
    bool hav = (r < n);
    float rx1 = 0.f, ry1 = 0.f, rx2 = 0.f, ry2 = 0.f, rar = 0.f;
    if (hav) {
        rx1 = GX1[base + r]; ry1 = GY1[base + r];
        rx2 = GX2[base + r]; ry2 = GY2[base + r];
        rar = GAR[base + r];
    }
    __shared__ float tx1[2048], ty1[2048], tx2[2048], ty2[2048], tar[2048];
    for (int jt = 0; jt < n; jt += 2048) {
        int cnt = min(2048, n - jt);
        __syncthreads();
        for (int k = t; k < cnt; k += 256) {
            tx1[k] = GX1[base + jt + k]; ty1[k] = GY1[base + jt + k];
            tx2[k] = GX2[base + jt + k]; ty2[k] = GY2[base + jt + k];
            tar[k] = GAR[base + jt + k];
        }
        __syncthreads();
        if (hav) {
            int w0 = jt >> 6;
            int nw = (cnt + 63) >> 6;
            for (int w = 0; w < nw; ++w) {
                int jb = jt + w * 64;
                unsigned long long bits = 0ull;
                if (jb + 63 > r) {
                    int kmax = min(64, n - jb);
                    for (int kk = 0; kk < kmax; ++kk) {
                        int j = jb + kk;
                        if (j > r) {
                            int k2 = j - jt;
                            float xx1 = fmaxf(rx1, tx1[k2]);
                            float yy1 = fmaxf(ry1, ty1[k2]);
                            float xx2 = fminf(rx2, tx2[k2]);
                            float yy2 = fminf(ry2, ty2[k2]);
                            float ww = fmaxf(1e-28f, xx2 - xx1);
                            float hh = fmaxf(1e-28f, yy2 - yy1);
                            float inter = ww * hh;
                            float ovr = inter / (rar + tar[k2] - inter);
                            if (ovr > NMS_T) bits |= (1ull << kk);
                        }
                    }
                }
                MASK[(size_t)(base + r) * WMAX + w0 + w] = bits;
            }
        }
    }
}

// ---------------- NMS stage 3: chunked bitmask scan (80 blocks) ----------------
__launch_bounds__(256)
__global__ void nms_scan(const unsigned long long* __restrict__ MASK,
                         const int* __restrict__ GIX,
                         const int* __restrict__ NCOUNT, const int* __restrict__ NBASE,
                         float* __restrict__ keep)
{
    int c = blockIdx.x, t = threadIdx.x;
    int n = NCOUNT[c];
    if (n == 0) return;
    int base = NBASE[c];
    int Wc = (n + 63) >> 6;
    __shared__ unsigned long long remv[WMAX];
    __shared__ unsigned long long sld[32][WMAX];
    __shared__ unsigned int s_alive;
    for (int w = t; w < Wc; w += 256) remv[w] = 0ull;
    __syncthreads();
    for (int i0 = 0; i0 < n; i0 += 32) {
        int rows = min(32, n - i0);
        int tot = rows * Wc;
        for (int k = t; k < tot; k += 256) {
            int rr = k / Wc, w = k - rr * Wc;
            sld[rr][w] = MASK[(size_t)(base + i0 + rr) * WMAX + w];
        }
        __syncthreads();
        if (t == 0) {
            int wq = i0 >> 6, b0 = i0 & 63;
            unsigned long long lw = remv[wq];
            unsigned am = 0;
            for (int rr = 0; rr < rows; ++rr) {
                if (!((lw >> (b0 + rr)) & 1ull)) {
                    am |= (1u << rr);
                    lw |= sld[rr][wq];
                }
            }
            s_alive = am;
        }
        __syncthreads();
        unsigned am = s_alive;
        for (int w = t; w < Wc; w += 256) {
            unsigned long long acc = remv[w];
            unsigned m = am;
            while (m) { int rr = __ffs(m) - 1; m &= m - 1; acc |= sld[rr][w]; }
            remv[w] = acc;
        }
        if (t < rows && ((am >> t) & 1u)) keep[GIX[base + i0 + t]] = 1.0f;
        __syncthreads();
    }
}

// ---------------- host orchestration ----------------
extern "C" void kernel_launch(void* const* d_in, const int* in_sizes, int n_in,
                              void* d_out, int out_size, void* d_ws, size_t ws_size,
                              hipStream_t stream)
{
    const float* c3      = (const float*)d_in[0];
    const float* c4      = (const float*)d_in[1];
    const float* c5      = (const float*)d_in[2];
    const float* lat1_w  = (const float*)d_in[3];
    const float* lat1_b  = (const float*)d_in[4];
    const float* lat2_w  = (const float*)d_in[5];
    const float* lat2_b  = (const float*)d_in[6];
    const float* lat3_w  = (const float*)d_in[7];
    const float* lat3_b  = (const float*)d_in[8];
    const float* sm1_w   = (const float*)d_in[9];
    const float* sm1_b   = (const float*)d_in[10];
    const float* sm2_w   = (const float*)d_in[11];
    const float* sm2_b   = (const float*)d_in[12];
    const float* sm3_w   = (const float*)d_in[13];
    const float* sm3_b   = (const float*)d_in[14];
    const float* clsh_w  = (const float*)d_in[15];
    const float* clsh_b  = (const float*)d_in[16];
    const float* regh_w  = (const float*)d_in[17];
    const float* regh_b  = (const float*)d_in[18];
    const float* clsd_w  = (const float*)d_in[19];
    const float* clsd_b  = (const float*)d_in[20];
    const float* regd_w  = (const float*)d_in[21];
    const float* regd_b  = (const float*)d_in[22];
    const float* ctnd_w  = (const float*)d_in[23];
    const float* ctnd_b  = (const float*)d_in[24];

    float* ws = (float*)d_ws;
    float* T3 = ws + OFF_T3;  float* T4 = ws + OFF_T4;  float* T5 = ws + OFF_T5;
    float* P3 = ws + OFF_P3;  float* P4 = ws + OFF_P4;  float* P5 = ws + OFF_P5;
    float* HA3 = ws + OFF_HA3; float* HA4 = ws + OFF_HA4; float* HA5 = ws + OFF_HA5;
    float* HB3 = ws + OFF_HB3; float* HB4 = ws + OFF_HB4; float* HB5 = ws + OFF_HB5;
    float* HD3 = ws + OFF_HD3; float* HD4 = ws + OFF_HD4; float* HD5 = ws + OFF_HD5;
    float* CLS = ws + OFF_CLS; float* REG = ws + OFF_REG; float* CTN = ws + OFF_CTN;
    _Float16* WH = (_Float16*)(ws + OFF_W2H);
    _Float16* WL = (_Float16*)(ws + OFF_W2L);
    unsigned long long* KEYS = (unsigned long long*)(ws + POFF_KEYS);
    float* SCS = ws + POFF_SCS;
    int* CLSS = (int*)(ws + POFF_CLSS);
    int* IDXS = (int*)(ws + POFF_IDXS);
    float* GX1 = ws + POFF_GX1; float* GY1 = ws + POFF_GY1;
    float* GX2 = ws + POFF_GX2; float* GY2 = ws + POFF_GY2;
    float* GAR = ws + POFF_GAR;
    int* GIX = (int*)(ws + POFF_GIX);
    int* NCOUNT = (int*)(ws + POFF_NCNT);
    int* NBASE  = (int*)(ws + POFF_NBASE);
    unsigned long long* MASK = (unsigned long long*)(ws + POFF_MASK);

    float* out = (float*)d_out;
    dim3 blk(256);
    const size_t WSTEP = 256u * 256u * 9u;
    bool use_mfma = (ws_size >= (size_t)WS_NEED * sizeof(float));

    if (use_mfma) {
        // weight f16 hi/lo prep (11 matrices)
        w2prep<<<dim3((11 * WSTEP9 + 255) / 256), blk, 0, stream>>>(
            clsh_w, regh_w, sm1_w, sm2_w, sm3_w, WH, WL);

        // FPN laterals first (dependency chain), then all smooths fused
        conv1x1_kernel<<<dim3(7, 4), blk, 0, stream>>>(c5, lat3_w, lat3_b, T5, nullptr,
                                                       512, 256, 400, 20, 400, 0);
        conv1x1_kernel<<<dim3(25, 4), blk, 0, stream>>>(c4, lat2_w, lat2_b, T4, T5,
                                                        256, 256, 1600, 40, 1600, 0);
        conv1x1_kernel<<<dim3(100, 4), blk, 0, stream>>>(c3, lat1_w, lat1_b, T3, T4,
                                                         128, 256, 6400, 80, 6400, 0);
        {
            MC mc{};
            float* sT[3] = {T3, T4, T5};
            float* sP[3] = {P3, P4, P5};
            const float* sB[3] = {sm1_b, sm2_b, sm3_b};
            for (int l = 0; l < 3; ++l) {
                mc.src[0][l] = sT[l]; mc.dst[0][l] = sP[l];
                mc.wh[0][l] = WH + (size_t)(8 + l) * WSTEP9;
                mc.wl[0][l] = WL + (size_t)(8 + l) * WSTEP9;
                mc.bias[0][l] = sB[l];
            }
            mc.act = 0;
            mconv3x3<<<dim3(140, 4, 1), blk, 0, stream>>>(mc);
        }
        // heads: 4 MFMA layers
        {
            float* clsS[3][5] = { {P3, HA3, HB3, HA3, HB3},
                                  {P4, HA4, HB4, HA4, HB4},
                                  {P5, HA5, HB5, HA5, HB5} };
            float* regS[3][5] = { {P3, T3,  HD3, T3,  HD3},
                                  {P4, T4,  HD4, T4,  HD4},
                                  {P5, T5,  HD5, T5,  HD5} };
            for (int i = 0; i < 4; ++i) {
                MC mc{};
                for (int l = 0; l < 3; ++l) {
                    mc.src[0][l] = clsS[l][i]; mc.dst[0][l] = clsS[l][i + 1];
                    mc.src[1][l] = regS[l][i]; mc.dst[1][l] = regS[l][i + 1];
                    mc.wh[0][l] = WH + (size_t)i * WSTEP9;
                    mc.wl[0][l] = WL + (size_t)i * WSTEP9;
                    mc.wh[1][l] = WH + (size_t)(4 + i) * WSTEP9;
                    mc.wl[1][l] = WL + (size_t)(4 + i) * WSTEP9;
                    mc.bias[0][l] = clsh_b + i * 256;
                    mc.bias[1][l] = regh_b + i * 256;
                }
                mc.act = 1;
                mconv3x3<<<dim3(140, 4, 2), blk, 0, stream>>>(mc);
            }
        }
    } else {
        // fallback: r12 fp32 path
        conv1x1_kernel<<<dim3(7, 4), blk, 0, stream>>>(c5, lat3_w, lat3_b, T5, nullptr,
                                                       512, 256, 400, 20, 400, 0);
        conv3x3_t<8, 4, 32><<<dim3(15, 8), blk, 0, stream>>>(T5, sm3_w, sm3_b, P5, 20, 20, 0);
        conv1x1_kernel<<<dim3(25, 4), blk, 0, stream>>>(c4, lat2_w, lat2_b, T4, T5,
                                                        256, 256, 1600, 40, 1600, 0);
        conv3x3_t<16, 4, 32><<<dim3(30, 8), blk, 0, stream>>>(T4, sm2_w, sm2_b, P4, 40, 40, 0);
        conv1x1_kernel<<<dim3(100, 4), blk, 0, stream>>>(c3, lat1_w, lat1_b, T3, T4,
                                                         128, 256, 6400, 80, 6400, 0);
        conv3x3_t<16, 8, 32><<<dim3(50, 8), blk, 0, stream>>>(T3, sm1_w, sm1_b, P3, 80, 80, 0);
        float* clsS[3][5] = { {P3, HA3, HB3, HA3, HB3},
                              {P4, HA4, HB4, HA4, HB4},
                              {P5, HA5, HB5, HA5, HB5} };
        float* regS[3][5] = { {P3, T3,  HD3, T3,  HD3},
                              {P4, T4,  HD4, T4,  HD4},
                              {P5, T5,  HD5, T5,  HD5} };
        for (int i = 0; i < 4; ++i) {
            HeadPtrs hp;
            for (int l = 0; l < 3; ++l) {
                hp.src[0][l] = clsS[l][i];     hp.dst[0][l] = clsS[l][i + 1];
                hp.src[1][l] = regS[l][i];     hp.dst[1][l] = regS[l][i + 1];
            }
            conv3x3_heads<<<dim3(71, 8, 2), blk, 0, stream>>>(
                hp, clsh_w + (size_t)i * WSTEP, regh_w + (size_t)i * WSTEP,
                clsh_b + i * 256, regh_b + i * 256);
        }
    }

    // ---- detectors: all 9 (level x {cls,reg,ctn}) in one dispatch ----
    {
        Det9 d;
        const float* feats[3][2] = { {HB3, HD3}, {HB4, HD4}, {HB5, HD5} };
        int   npx[3]   = {6400, 1600, 400};
        int   obase[3] = {0, 6400, 8000};
        int q = 0, bacc = 0;
        for (int l = 0; l < 3; ++l) {
            d.src[q] = feats[l][0]; d.w[q] = clsd_w; d.b[q] = clsd_b; d.dst[q] = CLS;
            d.cout[q] = 80; d.npx[q] = npx[l]; d.obase[q] = obase[l];
            d.bstart[q] = bacc; d.npxb[q] = (npx[l] + 63) / 64;
            bacc += d.npxb[q] * 2; ++q;
            d.src[q] = feats[l][1]; d.w[q] = regd_w; d.b[q] = regd_b; d.dst[q] = REG;
            d.cout[q] = 4; d.npx[q] = npx[l]; d.obase[q] = obase[l];
            d.bstart[q] = bacc; d.npxb[q] = (npx[l] + 63) / 64;
            bacc += d.npxb[q]; ++q;
            d.src[q] = feats[l][1]; d.w[q] = ctnd_w; d.b[q] = ctnd_b; d.dst[q] = CTN;
            d.cout[q] = 1; d.npx[q] = npx[l]; d.obase[q] = obase[l];
            d.bstart[q] = bacc; d.npxb[q] = (npx[l] + 63) / 64;
            bacc += d.npxb[q]; ++q;
        }
        det1x1_fused<<<dim3(bacc), blk, 0, stream>>>(d);
    }

    // ---- decode ----
    decode_kernel<<<dim3(64), blk, 0, stream>>>(CLS, REG, CTN, out, KEYS);

    // ---- hybrid bitonic sort ----
    bitonic_local<<<dim3(8), blk, 0, stream>>>(KEYS, 0u);
    bitonic_global<<<dim3(32), blk, 0, stream>>>(KEYS, 4096u, 2048u);
    bitonic_local<<<dim3(8), blk, 0, stream>>>(KEYS, 4096u);
    bitonic_global<<<dim3(32), blk, 0, stream>>>(KEYS, 8192u, 4096u);
    bitonic_global<<<dim3(32), blk, 0, stream>>>(KEYS, 8192u, 2048u);
    bitonic_local<<<dim3(8), blk, 0, stream>>>(KEYS, 8192u);
    bitonic_global<<<dim3(32), blk, 0, stream>>>(KEYS, 16384u, 8192u);
    bitonic_global<<<dim3(32), blk, 0, stream>>>(KEYS, 16384u, 4096u);
    bitonic_global<<<dim3(32), blk, 0, stream>>>(KEYS, 16384u, 2048u);
    bitonic_local<<<dim3(8), blk, 0, stream>>>(KEYS, 16384u);

    // ---- NMS pipeline ----
    sorted_aux<<<dim3(64), blk, 0, stream>>>(KEYS, out, SCS, CLSS, IDXS);
    compact_cls<<<dim3(80), blk, 0, stream>>>(SCS, CLSS, IDXS, out,
                                              GX1, GY1, GX2, GY2, GAR, GIX, NCOUNT, NBASE);
    nms_mask<<<dim3(33, 80), blk, 0, stream>>>(GX1, GY1, GX2, GY2, GAR, NCOUNT, NBASE, MASK);
    nms_scan<<<dim3(80), blk, 0, stream>>>(MASK, GIX, NCOUNT, NBASE, out + 50400);
}

// Round 14
// 1533.832 us; speedup vs baseline: 1.9213x; 1.0696x over previous
//
#include <hip/hip_runtime.h>
#include <stdint.h>

#define CONF_T 0.05f
#define NMS_T  0.5f
#define WMAX   132           // ceil(8400/64)
#define WSTEP9 589824        // 256*256*9

typedef _Float16 f16x8 __attribute__((ext_vector_type(8)));
typedef _Float16 f16x2 __attribute__((ext_vector_type(2)));
typedef float    f32x4 __attribute__((ext_vector_type(4)));
#define MFMA16 __builtin_amdgcn_mfma_f32_16x16x32_f16

// ---- workspace layout (float offsets) ----
#define OFF_T3   0u
#define OFF_T4   1638400u
#define OFF_T5   2048000u
#define OFF_P3   2150400u
#define OFF_P4   3788800u
#define OFF_P5   4198400u
#define OFF_HA3  4300800u
#define OFF_HA4  5939200u
#define OFF_HA5  6348800u
#define OFF_HB3  6451200u
#define OFF_HB4  8089600u
#define OFF_HB5  8499200u
#define OFF_HD3  8601600u
#define OFF_HD4  10240000u
#define OFF_HD5  10649600u
#define OFF_CLS  10752000u
#define OFF_REG  11424000u
#define OFF_CTN  11457600u
#define OFF_W2H  11466000u                 // 11 matrices x 589824 f16 (hi)
#define OFF_W2L  14710032u                 // (lo)
#define WS_NEED  17954064u                 // floats required for MFMA path
// post-processing arrays (T3 region, free after conv stack)
#define POFF_KEYS  (OFF_T3 + 0u)
#define POFF_SCS   (OFF_T3 + 32768u)
#define POFF_CLSS  (OFF_T3 + 49152u)
#define POFF_IDXS  (OFF_T3 + 65536u)
#define POFF_GX1   (OFF_T3 + 81920u)
#define POFF_GY1   (OFF_T3 + 90320u)
#define POFF_GX2   (OFF_T3 + 98720u)
#define POFF_GY2   (OFF_T3 + 107120u)
#define POFF_GAR   (OFF_T3 + 115520u)
#define POFF_GIX   (OFF_T3 + 123920u)
#define POFF_NCNT  (OFF_T3 + 132320u)
#define POFF_NBASE (OFF_T3 + 132400u)
#define POFF_MASK  OFF_HA3

// ---------------- conv 1x1 (+ optional nearest-up2 add) ----------------
__launch_bounds__(256)
__global__ void conv1x1_kernel(const float* __restrict__ in, const float* __restrict__ w,
                               const float* __restrict__ b, float* __restrict__ out,
                               const float* __restrict__ add,
                               int Cin, int Cout, int NPX, int W, int outStride, int outBase)
{
    __shared__ float s_in[16][64];
    __shared__ float s_w[16][64];
    int t = threadIdx.x;
    int pxg = t & 31, cg = t >> 5;
    int px0 = blockIdx.x * 64;
    int co0 = blockIdx.y * 64;
    float acc[8][2];
#pragma unroll
    for (int c = 0; c < 8; ++c) { acc[c][0] = 0.f; acc[c][1] = 0.f; }
    int chunks = Cin >> 4;
    int wco = t >> 2, wpart = t & 3;
    for (int ch = 0; ch < chunks; ++ch) {
        int ci0 = ch << 4;
#pragma unroll
        for (int k = 0; k < 4; ++k) {
            int id = t + k * 256;
            int ci = id >> 6, pp = id & 63;
            int gp = px0 + pp;
            s_in[ci][pp] = (gp < NPX) ? in[(size_t)(ci0 + ci) * NPX + gp] : 0.f;
        }
        {
            int gco = co0 + wco;
            if (gco < Cout) {
                const float* run = w + (size_t)gco * Cin + ci0;
#pragma unroll
                for (int k = 0; k < 4; ++k) {
                    int e = wpart + 4 * k;
                    s_w[e][wco] = run[e];
                }
            } else {
#pragma unroll
                for (int k = 0; k < 4; ++k) s_w[wpart + 4 * k][wco] = 0.f;
            }
        }
        __syncthreads();
#pragma unroll
        for (int ci = 0; ci < 16; ++ci) {
            float i0 = s_in[ci][pxg * 2], i1 = s_in[ci][pxg * 2 + 1];
#pragma unroll
            for (int c = 0; c < 8; ++c) {
                float wv = s_w[ci][cg * 8 + c];
                acc[c][0] += wv * i0;
                acc[c][1] += wv * i1;
            }
        }
        __syncthreads();
    }
    for (int c = 0; c < 8; ++c) {
        int co = co0 + cg * 8 + c;
        if (co >= Cout) break;
        float bb = b[co];
#pragma unroll
        for (int j = 0; j < 2; ++j) {
            int p = px0 + pxg * 2 + j;
            if (p < NPX) {
                float v = acc[c][j] + bb;
                if (add) {
                    int y = p / W, x = p % W;
                    int Sp = W >> 1;
                    v += add[(size_t)co * (Sp * Sp) + (y >> 1) * Sp + (x >> 1)];
                }
                out[(size_t)co * outStride + outBase + p] = v;
            }
        }
    }
}

// ---------------- fused detector 1x1 (9 combos in one dispatch) ----------------
struct Det9 {
    const float* src[9]; const float* w[9]; const float* b[9];
    float*       dst[9];
    int cout[9], npx[9], obase[9], bstart[9], npxb[9];
};

__launch_bounds__(256)
__global__ void det1x1_fused(Det9 d)
{
    int bid = blockIdx.x;
    int q = 0;
#pragma unroll
    for (int i = 1; i < 9; ++i) if (bid >= d.bstart[i]) q = i;
    int local = bid - d.bstart[q];
    int coIdx = local / d.npxb[q];
    int pxIdx = local - coIdx * d.npxb[q];
    const float* in = d.src[q];
    const float* w  = d.w[q];
    const float* b  = d.b[q];
    float* out = d.dst[q];
    int Cout = d.cout[q], NPX = d.npx[q], outBase = d.obase[q];

    __shared__ float s_in[16][64];
    __shared__ float s_w[16][64];
    int t = threadIdx.x;
    int pxg = t & 31, cg = t >> 5;
    int px0 = pxIdx * 64;
    int co0 = coIdx * 64;
    float acc[8][2];
#pragma unroll
    for (int c = 0; c < 8; ++c) { acc[c][0] = 0.f; acc[c][1] = 0.f; }
    int wco = t >> 2, wpart = t & 3;
    for (int ch = 0; ch < 16; ++ch) {
        int ci0 = ch << 4;
#pragma unroll
        for (int k = 0; k < 4; ++k) {
            int id = t + k * 256;
            int ci = id >> 6, pp = id & 63;
            int gp = px0 + pp;
            s_in[ci][pp] = (gp < NPX) ? in[(size_t)(ci0 + ci) * NPX + gp] : 0.f;
        }
        {
            int gco = co0 + wco;
            if (gco < Cout) {
                const float* run = w + (size_t)gco * 256 + ci0;
#pragma unroll
                for (int k = 0; k < 4; ++k) {
                    int e = wpart + 4 * k;
                    s_w[e][wco] = run[e];
                }
            } else {
#pragma unroll
                for (int k = 0; k < 4; ++k) s_w[wpart + 4 * k][wco] = 0.f;
            }
        }
        __syncthreads();
#pragma unroll
        for (int ci = 0; ci < 16; ++ci) {
            float i0 = s_in[ci][pxg * 2], i1 = s_in[ci][pxg * 2 + 1];
#pragma unroll
            for (int c = 0; c < 8; ++c) {
                float wv = s_w[ci][cg * 8 + c];
                acc[c][0] += wv * i0;
                acc[c][1] += wv * i1;
            }
        }
        __syncthreads();
    }
    for (int c = 0; c < 8; ++c) {
        int co = co0 + cg * 8 + c;
        if (co >= Cout) break;
        float bb = b[co];
#pragma unroll
        for (int j = 0; j < 2; ++j) {
            int p = px0 + pxg * 2 + j;
            if (p < NPX) out[(size_t)co * 8400 + outBase + p] = acc[c][j] + bb;
        }
    }
}

// ---------------- MFMA path: weight f16 hi/lo prep ----------------
__launch_bounds__(256)
__global__ void w2prep(const float* __restrict__ clsh_w, const float* __restrict__ regh_w,
                       const float* __restrict__ sm1_w, const float* __restrict__ sm2_w,
                       const float* __restrict__ sm3_w,
                       _Float16* __restrict__ WH, _Float16* __restrict__ WL)
{
    int idx = blockIdx.x * 256 + threadIdx.x;
    if (idx >= 11 * WSTEP9) return;
    int m = idx / WSTEP9, e = idx - m * WSTEP9;
    int co = e / 2304, r2 = e - co * 2304;
    int ci = r2 / 9, tap = r2 - ci * 9;
    const float* srcb;
    if (m < 4)       srcb = clsh_w + (size_t)m * WSTEP9;
    else if (m < 8)  srcb = regh_w + (size_t)(m - 4) * WSTEP9;
    else if (m == 8) srcb = sm1_w;
    else if (m == 9) srcb = sm2_w;
    else             srcb = sm3_w;
    float f = srcb[(size_t)co * 2304 + ci * 9 + tap];
    _Float16 h = (_Float16)f;
    _Float16 l = (_Float16)(f - (float)h);
    size_t d = (size_t)m * WSTEP9 + ((size_t)(tap * 256 + co)) * 256 + ci;
    WH[d] = h; WL[d] = l;
}

// ---------------- MFMA conv3x3 (fp16 3-term split) ----------------
// 1D grid with XCD-slice swizzle: slice = bid % (4*nbr) selects (co0, branch);
// with round-robin bid->XCD all 140 spatial tiles of a slice share one XCD's
// L2 (2.36 MB weight slice < 4 MB) -> A-loads become L2 hits instead of the
// r13 HBM misses (FETCH 110 MB/dispatch, ~10x weight re-fetch).
// A-frags software-pipelined one tap ahead (global loads, cross ck barrier).
struct MC {
    const float*    src[2][3];
    float*          dst[2][3];
    const _Float16* wh[2][3];
    const _Float16* wl[2][3];
    const float*    bias[2][3];
    int act;
    int nbr;
};

__launch_bounds__(256)
__global__ void mconv3x3(MC p)
{
    __shared__ __align__(16) _Float16 SH[2][108 * 40];
    __shared__ __align__(16) _Float16 SL[2][108 * 40];
    int t = threadIdx.x;
    int NS = 4 * p.nbr;
    int bid = blockIdx.x;
    int slice = bid % NS;
    int sp = bid / NS;                        // 0..139: 100 L3, 30 L4, 10 L5
    int br = slice % p.nbr;
    int co0 = (slice / p.nbr) * 64;
    int lvl = (sp < 100) ? 0 : (sp < 130) ? 1 : 2;
    int tloc = sp - ((lvl == 0) ? 0 : (lvl == 1) ? 100 : 130);
    int W = (lvl == 0) ? 80 : (lvl == 1) ? 40 : 20;
    int nTx = (lvl == 0) ? 5 : (lvl == 1) ? 3 : 2;
    int HW = W * W;
    int bx0 = (tloc % nTx) * 16, by0 = (tloc / nTx) * 4;
    const float* src = p.src[br][lvl];
    float* dst = p.dst[br][lvl];
    const _Float16* wh = p.wh[br][lvl];
    const _Float16* wl = p.wl[br][lvl];
    const float* bias = p.bias[br][lvl];

    int lane = t & 63, wid = t >> 6;
    int cw = wid & 1, pw = wid >> 1;
    int colc = lane & 15, g = lane >> 4;

    // staging descriptors: 1728 ci-pair slots (108 cells x 16 pairs)
    int sgo[7], sla[7];
#pragma unroll
    for (int k = 0; k < 7; ++k) {
        int s2 = t + k * 256;
        sgo[k] = -1; sla[k] = 0;
        if (s2 < 1728) {
            int ci2 = s2 / 108, cell = s2 - ci2 * 108;
            int r = cell / 18, c = cell - r * 18;
            sla[k] = cell * 40 + ci2 * 2;
            int gy = by0 - 1 + r, gx = bx0 - 1 + c;
            if (gy >= 0 && gy < W && gx >= 0 && gx < W)
                sgo[k] = (ci2 * 2) * HW + gy * W + gx;
        }
    }

    f32x4 acc[2][2];
#pragma unroll
    for (int mi = 0; mi < 2; ++mi)
#pragma unroll
        for (int ny = 0; ny < 2; ++ny) acc[mi][ny] = (f32x4)0.f;

    // stage chunk 0
#pragma unroll
    for (int k = 0; k < 7; ++k) {
        if (t + k * 256 < 1728) {
            float v0 = 0.f, v1 = 0.f;
            if (sgo[k] >= 0) { v0 = src[sgo[k]]; v1 = src[sgo[k] + HW]; }
            _Float16 h0 = (_Float16)v0, h1 = (_Float16)v1;
            _Float16 l0 = (_Float16)(v0 - (float)h0), l1 = (_Float16)(v1 - (float)h1);
            f16x2 ph = {h0, h1}, pl = {l0, l1};
            *(f16x2*)&SH[0][sla[k]] = ph;
            *(f16x2*)&SL[0][sla[k]] = pl;
        }
    }
    __syncthreads();

    int coA = co0 + cw * 32 + colc;
    // A-frag software pipeline (global; unaffected by LDS barriers)
    auto aoff = [&](int ckk, int tap) -> size_t {
        return ((size_t)(tap * 256 + coA)) * 256 + ckk * 32 + g * 8;
    };
    f16x8 a0h, a0l, a1h, a1l;
    {
        size_t a0 = aoff(0, 0);
        a0h = *(const f16x8*)(wh + a0);       a0l = *(const f16x8*)(wl + a0);
        a1h = *(const f16x8*)(wh + a0 + 4096); a1l = *(const f16x8*)(wl + a0 + 4096);
    }
    for (int ck = 0; ck < 8; ++ck) {
        const _Float16* sh  = SH[ck & 1];
        const _Float16* sl_ = SL[ck & 1];
        float pv[14];
        bool pf = (ck < 7);
        if (pf) {
            const float* sb = src + (size_t)(ck + 1) * 32 * HW;
#pragma unroll
            for (int k = 0; k < 7; ++k) {
                pv[2 * k] = 0.f; pv[2 * k + 1] = 0.f;
                if (t + k * 256 < 1728 && sgo[k] >= 0) {
                    pv[2 * k] = sb[sgo[k]]; pv[2 * k + 1] = sb[sgo[k] + HW];
                }
            }
        }
#pragma unroll
        for (int tap = 0; tap < 9; ++tap) {
            int ky = tap / 3, kx = tap - ky * 3;
            // prefetch next (tap, ck) A-frags
            int nck = (tap < 8) ? ck : (pf ? ck + 1 : ck);
            int ntap = (tap < 8) ? tap + 1 : (pf ? 0 : 8);
            size_t an = aoff(nck, ntap);
            f16x8 n0h = *(const f16x8*)(wh + an);
            f16x8 n0l = *(const f16x8*)(wl + an);
            f16x8 n1h = *(const f16x8*)(wh + an + 4096);
            f16x8 n1l = *(const f16x8*)(wl + an + 4096);
#pragma unroll
            for (int ny = 0; ny < 2; ++ny) {
                int cell = (pw * 2 + ny + ky) * 18 + colc + kx;
                f16x8 bh = *(const f16x8*)(sh  + cell * 40 + g * 8);
                f16x8 bl = *(const f16x8*)(sl_ + cell * 40 + g * 8);
                acc[0][ny] = MFMA16(a0h, bh, acc[0][ny], 0, 0, 0);
                acc[1][ny] = MFMA16(a1h, bh, acc[1][ny], 0, 0, 0);
                acc[0][ny] = MFMA16(a0h, bl, acc[0][ny], 0, 0, 0);
                acc[1][ny] = MFMA16(a1h, bl, acc[1][ny], 0, 0, 0);
                acc[0][ny] = MFMA16(a0l, bh, acc[0][ny], 0, 0, 0);
                acc[1][ny] = MFMA16(a1l, bh, acc[1][ny], 0, 0, 0);
            }
            a0h = n0h; a0l = n0l; a1h = n1h; a1l = n1l;
        }
        if (pf) {
            _Float16* nh = SH[(ck + 1) & 1];
            _Float16* nl = SL[(ck + 1) & 1];
#pragma unroll
            for (int k = 0; k < 7; ++k) {
                if (t + k * 256 < 1728) {
                    float v0 = pv[2 * k], v1 = pv[2 * k + 1];
                    _Float16 h0 = (_Float16)v0, h1 = (_Float16)v1;
                    _Float16 l0 = (_Float16)(v0 - (float)h0), l1 = (_Float16)(v1 - (float)h1);
                    f16x2 ph = {h0, h1}, pl = {l0, l1};
                    *(f16x2*)&nh[sla[k]] = ph;
                    *(f16x2*)&nl[sla[k]] = pl;
                }
            }
        }
        __syncthreads();
    }

    int x = bx0 + colc;
    if (x < W) {
#pragma unroll
        for (int mi = 0; mi < 2; ++mi) {
            int cob = co0 + cw * 32 + mi * 16 + g * 4;
#pragma unroll
            for (int ny = 0; ny < 2; ++ny) {
                int y = by0 + pw * 2 + ny;
#pragma unroll
                for (int i = 0; i < 4; ++i) {
                    int co = cob + i;
                    float v = acc[mi][ny][i] + bias[co];
                    if (p.act) v = (v >= 0.f) ? v : 0.1f * v;
                    dst[(size_t)co * HW + y * W + x] = v;
                }
            }
        }
    }
}

// ---------------- decode: scores, argmax, boxes, sort keys ----------------
__launch_bounds__(256)
__global__ void decode_kernel(const float* __restrict__ cls, const float* __restrict__ reg,
                              const float* __restrict__ ctn, float* __restrict__ out,
                              unsigned long long* __restrict__ keys)
{
    int p = blockIdx.x * 256 + threadIdx.x;
    if (p >= 16384) return;
    if (p >= 8400) { keys[p] = ~0ull; return; }
    int base, hs; float s;
    if (p < 6400)      { base = 0;    hs = 80; s = 8.f;  }
    else if (p < 8000) { base = 6400; hs = 40; s = 16.f; }
    else               { base = 8000; hs = 20; s = 32.f; }
    int local = p - base;
    float gx = (float)(local % hs), gy = (float)(local / hs);
    float ct = ctn[p];
    float sct = 1.f / (1.f + expf(-ct));
    float best = -1.f; int arg = 0;
    for (int c = 0; c < 80; ++c) {
        float v = cls[(size_t)c * 8400 + p];
        float sv = 1.f / (1.f + expf(-v));
        float sc = sqrtf(sv * sct);
        if (sc > best) { best = sc; arg = c; }
    }
    float r0 = reg[0 * 8400 + p], r1 = reg[1 * 8400 + p];
    float r2 = reg[2 * 8400 + p], r3 = reg[3 * 8400 + p];
    float x1 = (gx - expf(r0)) * s / 640.f;
    float y1 = (gy - expf(r1)) * s / 640.f;
    float x2 = (gx + expf(r2)) * s / 640.f;
    float y2 = (gy + expf(r3)) * s / 640.f;
    x1 = fminf(fmaxf(x1, 0.f), 1.f);
    y1 = fminf(fmaxf(y1, 0.f), 1.f);
    x2 = fminf(fmaxf(x2, 0.f), 1.f);
    y2 = fminf(fmaxf(y2, 0.f), 1.f);
    out[p * 4 + 0] = x1; out[p * 4 + 1] = y1;
    out[p * 4 + 2] = x2; out[p * 4 + 3] = y2;
    out[33600 + p] = best;
    out[42000 + p] = (float)arg;
    out[50400 + p] = 0.f;
    unsigned int ub = __float_as_uint(best);
    keys[p] = ((unsigned long long)(~ub) << 32) | (unsigned int)p;
}

// ---------------- hybrid bitonic sort of 16384 u64 keys ----------------
__launch_bounds__(256)
__global__ void bitonic_local(unsigned long long* __restrict__ keys, unsigned kmerge)
{
    __shared__ unsigned long long sk[2048];
    int t = threadIdx.x;
    unsigned base = blockIdx.x * 2048u;
#pragma unroll
    for (int m = 0; m < 8; ++m) sk[t + m * 256] = keys[base + t + m * 256];
    __syncthreads();
    if (kmerge == 0u) {
        for (unsigned k = 2; k <= 2048u; k <<= 1) {
            for (unsigned j = k >> 1; j > 0; j >>= 1) {
#pragma unroll
                for (int pp = 0; pp < 4; ++pp) {
                    unsigned p = (unsigned)t + pp * 256u;
                    unsigned li = ((p & ~(j - 1)) << 1) | (p & (j - 1));
                    unsigned gi = base + li;
                    bool up = ((gi & k) == 0);
                    unsigned long long a = sk[li], b = sk[li + j];
                    if ((a > b) == up) { sk[li] = b; sk[li + j] = a; }
                }
                __syncthreads();
            }
        }
    } else {
        unsigned k = kmerge;
        for (unsigned j = 1024; j > 0; j >>= 1) {
#pragma unroll
            for (int pp = 0; pp < 4; ++pp) {
                unsigned p = (unsigned)t + pp * 256u;
                unsigned li = ((p & ~(j - 1)) << 1) | (p & (j - 1));
                unsigned gi = base + li;
                bool up = ((gi & k) == 0);
                unsigned long long a = sk[li], b = sk[li + j];
                if ((a > b) == up) { sk[li] = b; sk[li + j] = a; }
            }
            __syncthreads();
        }
    }
#pragma unroll
    for (int m = 0; m < 8; ++m) keys[base + t + m * 256] = sk[t + m * 256];
}

__launch_bounds__(256)
__global__ void bitonic_global(unsigned long long* __restrict__ keys, unsigned k, unsigned j)
{
    unsigned p = blockIdx.x * 256u + threadIdx.x;
    unsigned i = ((p & ~(j - 1)) << 1) | (p & (j - 1));
    bool up = ((i & k) == 0);
    unsigned long long a = keys[i], b = keys[i + j];
    if ((a > b) == up) { keys[i] = b; keys[i + j] = a; }
}

// ---------------- expand sorted keys into SoA arrays ----------------
__launch_bounds__(256)
__global__ void sorted_aux(const unsigned long long* __restrict__ keys,
                           const float* __restrict__ out,
                           float* __restrict__ scs, int* __restrict__ clss,
                           int* __restrict__ idxs)
{
    int i = blockIdx.x * 256 + threadIdx.x;
    if (i >= 16384) return;
    unsigned long long key = keys[i];
    unsigned ub = ~(unsigned)(key >> 32);
    float sc = __uint_as_float(ub);
    unsigned idx = (unsigned)(key & 0xffffffffu);
    int cl = -1;
    if (idx < 8400u) cl = (int)out[42000 + idx];
    else sc = 0.f;
    scs[i] = sc; clss[i] = cl; idxs[i] = (int)idx;
}

// ---------------- NMS stage 1: per-class stable compaction ----------------
__launch_bounds__(256)
__global__ void compact_cls(const float* __restrict__ scs, const int* __restrict__ clss,
                            const int* __restrict__ idxs, const float* __restrict__ outbuf,
                            float* __restrict__ GX1, float* __restrict__ GY1,
                            float* __restrict__ GX2, float* __restrict__ GY2,
                            float* __restrict__ GAR, int* __restrict__ GIX,
                            int* __restrict__ NCOUNT, int* __restrict__ NBASE)
{
    int c = blockIdx.x, t = threadIdx.x;
    __shared__ int s_red[2];
    __shared__ int s_wtot[4];
    int cb = 0, co = 0;
    for (int i = t; i < 16384; i += 256) {
        float sc = scs[i]; int cl = clss[i];
        if (sc >= CONF_T && cl >= 0) { cb += (cl < c); co += (cl == c); }
    }
    if (t == 0) { s_red[0] = 0; s_red[1] = 0; }
    __syncthreads();
    atomicAdd(&s_red[0], cb);
    atomicAdd(&s_red[1], co);
    __syncthreads();
    int base = s_red[0], n = s_red[1];
    if (t == 0) { NCOUNT[c] = n; NBASE[c] = base; }

    int rank = 0;
    for (int st = 0; st < 16384; st += 256) {
        int i = st + t;
        float sc = scs[i]; int cl = clss[i];
        bool flag = (sc >= CONF_T && cl == c);
        unsigned long long m = __ballot(flag);
        int lane = t & 63, wv = t >> 6;
        if (lane == 0) s_wtot[wv] = __popcll(m);
        __syncthreads();
        int off = rank;
        for (int w = 0; w < wv; ++w) off += s_wtot[w];
        int tot = s_wtot[0] + s_wtot[1] + s_wtot[2] + s_wtot[3];
        if (flag) {
            int pos = off + __popcll(m & ((1ull << lane) - 1ull));
            int idx = idxs[i];
            float x1 = outbuf[idx * 4 + 0], y1 = outbuf[idx * 4 + 1];
            float x2 = outbuf[idx * 4 + 2], y2 = outbuf[idx * 4 + 3];
            GX1[base + pos] = x1; GY1[base + pos] = y1;
            GX2[base + pos] = x2; GY2[base + pos] = y2;
            GAR[base + pos] = (x2 - x1) * (y2 - y1);
            GIX[base + pos] = idx;
        }
        rank += tot;
        __syncthreads();
    }
}

// ---------------- NMS stage 2: suppression bit-matrix (parallel) ----------------
__launch_bounds__(256)
__global__ void nms_mask(const float* __restrict__ GX1, const float* __restrict__ GY1,
                         const float* __restrict__ GX2, const float* __restrict__ GY2,
                         const float* __restrict__ GAR,
                         const int* __restrict__ NCOUNT, const int* __restrict__ NBASE,
                         unsigned long long* __restrict__ MASK)
{
    int c = blockIdx.y;
    int n = NCOUNT[c];
    if ((int)(blockIdx.x * 256) >= n) return;
    int base = NBASE[c];
    int t = threadIdx.x;
    int r = blockIdx.x * 256 + t;
    bool hav = (r < n);
    float rx1 = 0.f, ry1 = 0.f, rx2 = 0.f, ry2 = 0.f, rar = 0.f;
    if (hav) {
        rx1 = GX1[base + r]; ry1 = GY1[base + r];
        rx2 = GX2[base + r]; ry2 = GY2[base + r];
        rar = GAR[base + r];
    }
    __shared__ float tx1[2048], ty1[2048], tx2[2048], ty2[2048], tar[2048];
    for (int jt = 0; jt < n; jt += 2048) {
        int cnt = min(2048, n - jt);
        __syncthreads();
        for (int k = t; k < cnt; k += 256) {
            tx1[k] = GX1[base + jt + k]; ty1[k] = GY1[base + jt + k];
            tx2[k] = GX2[base + jt + k]; ty2[k] = GY2[base + jt + k];
            tar[k] = GAR[base + jt + k];
        }
        __syncthreads();
        if (hav) {
            int w0 = jt >> 6;
            int nw = (cnt + 63) >> 6;
            for (int w = 0; w < nw; ++w) {
                int jb = jt + w * 64;
                unsigned long long bits = 0ull;
                if (jb + 63 > r) {
                    int kmax = min(64, n - jb);
                    for (int kk = 0; kk < kmax; ++kk) {
                        int j = jb + kk;
                        if (j > r) {
                            int k2 = j - jt;
                            float xx1 = fmaxf(rx1, tx1[k2]);
                            float yy1 = fmaxf(ry1, ty1[k2]);
                            float xx2 = fminf(rx2, tx2[k2]);
                            float yy2 = fminf(ry2, ty2[k2]);
                            float ww = fmaxf(1e-28f, xx2 - xx1);
                            float hh = fmaxf(1e-28f, yy2 - yy1);
                            float inter = ww * hh;
                            float ovr = inter / (rar + tar[k2] - inter);
                            if (ovr > NMS_T) bits |= (1ull << kk);
                        }
                    }
                }
                MASK[(size_t)(base + r) * WMAX + w0 + w] = bits;
            }
        }
    }
}

// ---------------- NMS stage 3: chunked bitmask scan (80 blocks) ----------------
__launch_bounds__(256)
__global__ void nms_scan(const unsigned long long* __restrict__ MASK,
                         const int* __restrict__ GIX,
                         const int* __restrict__ NCOUNT, const int* __restrict__ NBASE,
                         float* __restrict__ keep)
{
    int c = blockIdx.x, t = threadIdx.x;
    int n = NCOUNT[c];
    if (n == 0) return;
    int base = NBASE[c];
    int Wc = (n + 63) >> 6;
    __shared__ unsigned long long remv[WMAX];
    __shared__ unsigned long long sld[32][WMAX];
    __shared__ unsigned int s_alive;
    for (int w = t; w < Wc; w += 256) remv[w] = 0ull;
    __syncthreads();
    for (int i0 = 0; i0 < n; i0 += 32) {
        int rows = min(32, n - i0);
        int tot = rows * Wc;
        for (int k = t; k < tot; k += 256) {
            int rr = k / Wc, w = k - rr * Wc;
            sld[rr][w] = MASK[(size_t)(base + i0 + rr) * WMAX + w];
        }
        __syncthreads();
        if (t == 0) {
            int wq = i0 >> 6, b0 = i0 & 63;
            unsigned long long lw = remv[wq];
            unsigned am = 0;
            for (int rr = 0; rr < rows; ++rr) {
                if (!((lw >> (b0 + rr)) & 1ull)) {
                    am |= (1u << rr);
                    lw |= sld[rr][wq];
                }
            }
            s_alive = am;
        }
        __syncthreads();
        unsigned am = s_alive;
        for (int w = t; w < Wc; w += 256) {
            unsigned long long acc = remv[w];
            unsigned m = am;
            while (m) { int rr = __ffs(m) - 1; m &= m - 1; acc |= sld[rr][w]; }
            remv[w] = acc;
        }
        if (t < rows && ((am >> t) & 1u)) keep[GIX[base + i0 + t]] = 1.0f;
        __syncthreads();
    }
}

// ---------------- host orchestration ----------------
extern "C" void kernel_launch(void* const* d_in, const int* in_sizes, int n_in,
                              void* d_out, int out_size, void* d_ws, size_t ws_size,
                              hipStream_t stream)
{
    const float* c3      = (const float*)d_in[0];
    const float* c4      = (const float*)d_in[1];
    const float* c5      = (const float*)d_in[2];
    const float* lat1_w  = (const float*)d_in[3];
    const float* lat1_b  = (const float*)d_in[4];
    const float* lat2_w  = (const float*)d_in[5];
    const float* lat2_b  = (const float*)d_in[6];
    const float* lat3_w  = (const float*)d_in[7];
    const float* lat3_b  = (const float*)d_in[8];
    const float* sm1_w   = (const float*)d_in[9];
    const float* sm1_b   = (const float*)d_in[10];
    const float* sm2_w   = (const float*)d_in[11];
    const float* sm2_b   = (const float*)d_in[12];
    const float* sm3_w   = (const float*)d_in[13];
    const float* sm3_b   = (const float*)d_in[14];
    const float* clsh_w  = (const float*)d_in[15];
    const float* clsh_b  = (const float*)d_in[16];
    const float* regh_w  = (const float*)d_in[17];
    const float* regh_b  = (const float*)d_in[18];
    const float* clsd_w  = (const float*)d_in[19];
    const float* clsd_b  = (const float*)d_in[20];
    const float* regd_w  = (const float*)d_in[21];
    const float* regd_b  = (const float*)d_in[22];
    const float* ctnd_w  = (const float*)d_in[23];
    const float* ctnd_b  = (const float*)d_in[24];

    float* ws = (float*)d_ws;
    float* T3 = ws + OFF_T3;  float* T4 = ws + OFF_T4;  float* T5 = ws + OFF_T5;
    float* P3 = ws + OFF_P3;  float* P4 = ws + OFF_P4;  float* P5 = ws + OFF_P5;
    float* HA3 = ws + OFF_HA3; float* HA4 = ws + OFF_HA4; float* HA5 = ws + OFF_HA5;
    float* HB3 = ws + OFF_HB3; float* HB4 = ws + OFF_HB4; float* HB5 = ws + OFF_HB5;
    float* HD3 = ws + OFF_HD3; float* HD4 = ws + OFF_HD4; float* HD5 = ws + OFF_HD5;
    float* CLS = ws + OFF_CLS; float* REG = ws + OFF_REG; float* CTN = ws + OFF_CTN;
    _Float16* WH = (_Float16*)(ws + OFF_W2H);
    _Float16* WL = (_Float16*)(ws + OFF_W2L);
    unsigned long long* KEYS = (unsigned long long*)(ws + POFF_KEYS);
    float* SCS = ws + POFF_SCS;
    int* CLSS = (int*)(ws + POFF_CLSS);
    int* IDXS = (int*)(ws + POFF_IDXS);
    float* GX1 = ws + POFF_GX1; float* GY1 = ws + POFF_GY1;
    float* GX2 = ws + POFF_GX2; float* GY2 = ws + POFF_GY2;
    float* GAR = ws + POFF_GAR;
    int* GIX = (int*)(ws + POFF_GIX);
    int* NCOUNT = (int*)(ws + POFF_NCNT);
    int* NBASE  = (int*)(ws + POFF_NBASE);
    unsigned long long* MASK = (unsigned long long*)(ws + POFF_MASK);

    float* out = (float*)d_out;
    dim3 blk(256);

    // weight f16 hi/lo prep (11 matrices)
    w2prep<<<dim3((11 * WSTEP9 + 255) / 256), blk, 0, stream>>>(
        clsh_w, regh_w, sm1_w, sm2_w, sm3_w, WH, WL);

    // FPN laterals (dependency chain), then all smooths fused (MFMA)
    conv1x1_kernel<<<dim3(7, 4), blk, 0, stream>>>(c5, lat3_w, lat3_b, T5, nullptr,
                                                   512, 256, 400, 20, 400, 0);
    conv1x1_kernel<<<dim3(25, 4), blk, 0, stream>>>(c4, lat2_w, lat2_b, T4, T5,
                                                    256, 256, 1600, 40, 1600, 0);
    conv1x1_kernel<<<dim3(100, 4), blk, 0, stream>>>(c3, lat1_w, lat1_b, T3, T4,
                                                     128, 256, 6400, 80, 6400, 0);
    {
        MC mc{};
        float* sT[3] = {T3, T4, T5};
        float* sP[3] = {P3, P4, P5};
        const float* sB[3] = {sm1_b, sm2_b, sm3_b};
        for (int l = 0; l < 3; ++l) {
            mc.src[0][l] = sT[l]; mc.dst[0][l] = sP[l];
            mc.wh[0][l] = WH + (size_t)(8 + l) * WSTEP9;
            mc.wl[0][l] = WL + (size_t)(8 + l) * WSTEP9;
            mc.bias[0][l] = sB[l];
        }
        mc.act = 0; mc.nbr = 1;
        mconv3x3<<<dim3(140 * 4), blk, 0, stream>>>(mc);
    }
    // heads: 4 MFMA layers (slice-swizzled 1D grid)
    {
        float* clsS[3][5] = { {P3, HA3, HB3, HA3, HB3},
                              {P4, HA4, HB4, HA4, HB4},
                              {P5, HA5, HB5, HA5, HB5} };
        float* regS[3][5] = { {P3, T3,  HD3, T3,  HD3},
                              {P4, T4,  HD4, T4,  HD4},
                              {P5, T5,  HD5, T5,  HD5} };
        for (int i = 0; i < 4; ++i) {
            MC mc{};
            for (int l = 0; l < 3; ++l) {
                mc.src[0][l] = clsS[l][i]; mc.dst[0][l] = clsS[l][i + 1];
                mc.src[1][l] = regS[l][i]; mc.dst[1][l] = regS[l][i + 1];
                mc.wh[0][l] = WH + (size_t)i * WSTEP9;
                mc.wl[0][l] = WL + (size_t)i * WSTEP9;
                mc.wh[1][l] = WH + (size_t)(4 + i) * WSTEP9;
                mc.wl[1][l] = WL + (size_t)(4 + i) * WSTEP9;
                mc.bias[0][l] = clsh_b + i * 256;
                mc.bias[1][l] = regh_b + i * 256;
            }
            mc.act = 1; mc.nbr = 2;
            mconv3x3<<<dim3(140 * 8), blk, 0, stream>>>(mc);
        }
    }

    // ---- detectors: all 9 (level x {cls,reg,ctn}) in one dispatch ----
    {
        Det9 d;
        const float* feats[3][2] = { {HB3, HD3}, {HB4, HD4}, {HB5, HD5} };
        int   npx[3]   = {6400, 1600, 400};
        int   obase[3] = {0, 6400, 8000};
        int q = 0, bacc = 0;
        for (int l = 0; l < 3; ++l) {
            d.src[q] = feats[l][0]; d.w[q] = clsd_w; d.b[q] = clsd_b; d.dst[q] = CLS;
            d.cout[q] = 80; d.npx[q] = npx[l]; d.obase[q] = obase[l];
            d.bstart[q] = bacc; d.npxb[q] = (npx[l] + 63) / 64;
            bacc += d.npxb[q] * 2; ++q;
            d.src[q] = feats[l][1]; d.w[q] = regd_w; d.b[q] = regd_b; d.dst[q] = REG;
            d.cout[q] = 4; d.npx[q] = npx[l]; d.obase[q] = obase[l];
            d.bstart[q] = bacc; d.npxb[q] = (npx[l] + 63) / 64;
            bacc += d.npxb[q]; ++q;
            d.src[q] = feats[l][1]; d.w[q] = ctnd_w; d.b[q] = ctnd_b; d.dst[q] = CTN;
            d.cout[q] = 1; d.npx[q] = npx[l]; d.obase[q] = obase[l];
            d.bstart[q] = bacc; d.npxb[q] = (npx[l] + 63) / 64;
            bacc += d.npxb[q]; ++q;
        }
        det1x1_fused<<<dim3(bacc), blk, 0, stream>>>(d);
    }

    // ---- decode ----
    decode_kernel<<<dim3(64), blk, 0, stream>>>(CLS, REG, CTN, out, KEYS);

    // ---- hybrid bitonic sort ----
    bitonic_local<<<dim3(8), blk, 0, stream>>>(KEYS, 0u);
    bitonic_global<<<dim3(32), blk, 0, stream>>>(KEYS, 4096u, 2048u);
    bitonic_local<<<dim3(8), blk, 0, stream>>>(KEYS, 4096u);
    bitonic_global<<<dim3(32), blk, 0, stream>>>(KEYS, 8192u, 4096u);
    bitonic_global<<<dim3(32), blk, 0, stream>>>(KEYS, 8192u, 2048u);
    bitonic_local<<<dim3(8), blk, 0, stream>>>(KEYS, 8192u);
    bitonic_global<<<dim3(32), blk, 0, stream>>>(KEYS, 16384u, 8192u);
    bitonic_global<<<dim3(32), blk, 0, stream>>>(KEYS, 16384u, 4096u);
    bitonic_global<<<dim3(32), blk, 0, stream>>>(KEYS, 16384u, 2048u);
    bitonic_local<<<dim3(8), blk, 0, stream>>>(KEYS, 16384u);

    // ---- NMS pipeline ----
    sorted_aux<<<dim3(64), blk, 0, stream>>>(KEYS, out, SCS, CLSS, IDXS);
    compact_cls<<<dim3(80), blk, 0, stream>>>(SCS, CLSS, IDXS, out,
                                              GX1, GY1, GX2, GY2, GAR, GIX, NCOUNT, NBASE);
    nms_mask<<<dim3(33, 80), blk, 0, stream>>>(GX1, GY1, GX2, GY2, GAR, NCOUNT, NBASE, MASK);
    nms_scan<<<dim3(80), blk, 0, stream>>>(MASK, GIX, NCOUNT, NBASE, out + 50400);
}

// Round 15
// 1466.770 us; speedup vs baseline: 2.0091x; 1.0457x over previous
//
#include <hip/hip_runtime.h>
#include <stdint.h>

#define CONF_T 0.05f
#define NMS_T  0.5f
#define WMAX   132           // ceil(8400/64)
#define WSTEP9 589824        // 256*256*9

typedef _Float16 f16x8 __attribute__((ext_vector_type(8)));
typedef _Float16 f16x2 __attribute__((ext_vector_type(2)));
typedef float    f32x4 __attribute__((ext_vector_type(4)));
#define MFMA16 __builtin_amdgcn_mfma_f32_16x16x32_f16

// ---- workspace layout (float offsets) ----
#define OFF_T3   0u
#define OFF_T4   1638400u
#define OFF_T5   2048000u
#define OFF_P3   2150400u
#define OFF_P4   3788800u
#define OFF_P5   4198400u
#define OFF_HA3  4300800u
#define OFF_HA4  5939200u
#define OFF_HA5  6348800u
#define OFF_HB3  6451200u
#define OFF_HB4  8089600u
#define OFF_HB5  8499200u
#define OFF_HD3  8601600u
#define OFF_HD4  10240000u
#define OFF_HD5  10649600u
#define OFF_CLS  10752000u
#define OFF_REG  11424000u
#define OFF_CTN  11457600u
#define OFF_W2H  11466000u                 // 11 matrices x 589824 f16 (hi)
#define OFF_W2L  14710032u                 // (lo)
#define WS_NEED  17954064u
// post-processing arrays (T3 region, free after conv stack)
#define POFF_KEYS  (OFF_T3 + 0u)
#define POFF_SCS   (OFF_T3 + 32768u)
#define POFF_CLSS  (OFF_T3 + 49152u)
#define POFF_IDXS  (OFF_T3 + 65536u)
#define POFF_GX1   (OFF_T3 + 81920u)
#define POFF_GY1   (OFF_T3 + 90320u)
#define POFF_GX2   (OFF_T3 + 98720u)
#define POFF_GY2   (OFF_T3 + 107120u)
#define POFF_GAR   (OFF_T3 + 115520u)
#define POFF_GIX   (OFF_T3 + 123920u)
#define POFF_NCNT  (OFF_T3 + 132320u)
#define POFF_NBASE (OFF_T3 + 132400u)
#define POFF_MASK  OFF_HA3

// ---------------- conv 1x1 (+ optional nearest-up2 add) ----------------
__launch_bounds__(256)
__global__ void conv1x1_kernel(const float* __restrict__ in, const float* __restrict__ w,
                               const float* __restrict__ b, float* __restrict__ out,
                               const float* __restrict__ add,
                               int Cin, int Cout, int NPX, int W, int outStride, int outBase)
{
    __shared__ float s_in[16][64];
    __shared__ float s_w[16][64];
    int t = threadIdx.x;
    int pxg = t & 31, cg = t >> 5;
    int px0 = blockIdx.x * 64;
    int co0 = blockIdx.y * 64;
    float acc[8][2];
#pragma unroll
    for (int c = 0; c < 8; ++c) { acc[c][0] = 0.f; acc[c][1] = 0.f; }
    int chunks = Cin >> 4;
    int wco = t >> 2, wpart = t & 3;
    for (int ch = 0; ch < chunks; ++ch) {
        int ci0 = ch << 4;
#pragma unroll
        for (int k = 0; k < 4; ++k) {
            int id = t + k * 256;
            int ci = id >> 6, pp = id & 63;
            int gp = px0 + pp;
            s_in[ci][pp] = (gp < NPX) ? in[(size_t)(ci0 + ci) * NPX + gp] : 0.f;
        }
        {
            int gco = co0 + wco;
            if (gco < Cout) {
                const float* run = w + (size_t)gco * Cin + ci0;
#pragma unroll
                for (int k = 0; k < 4; ++k) {
                    int e = wpart + 4 * k;
                    s_w[e][wco] = run[e];
                }
            } else {
#pragma unroll
                for (int k = 0; k < 4; ++k) s_w[wpart + 4 * k][wco] = 0.f;
            }
        }
        __syncthreads();
#pragma unroll
        for (int ci = 0; ci < 16; ++ci) {
            float i0 = s_in[ci][pxg * 2], i1 = s_in[ci][pxg * 2 + 1];
#pragma unroll
            for (int c = 0; c < 8; ++c) {
                float wv = s_w[ci][cg * 8 + c];
                acc[c][0] += wv * i0;
                acc[c][1] += wv * i1;
            }
        }
        __syncthreads();
    }
    for (int c = 0; c < 8; ++c) {
        int co = co0 + cg * 8 + c;
        if (co >= Cout) break;
        float bb = b[co];
#pragma unroll
        for (int j = 0; j < 2; ++j) {
            int p = px0 + pxg * 2 + j;
            if (p < NPX) {
                float v = acc[c][j] + bb;
                if (add) {
                    int y = p / W, x = p % W;
                    int Sp = W >> 1;
                    v += add[(size_t)co * (Sp * Sp) + (y >> 1) * Sp + (x >> 1)];
                }
                out[(size_t)co * outStride + outBase + p] = v;
            }
        }
    }
}

// ---------------- fused detector 1x1 (9 combos in one dispatch) ----------------
struct Det9 {
    const float* src[9]; const float* w[9]; const float* b[9];
    float*       dst[9];
    int cout[9], npx[9], obase[9], bstart[9], npxb[9];
};

__launch_bounds__(256)
__global__ void det1x1_fused(Det9 d)
{
    int bid = blockIdx.x;
    int q = 0;
#pragma unroll
    for (int i = 1; i < 9; ++i) if (bid >= d.bstart[i]) q = i;
    int local = bid - d.bstart[q];
    int coIdx = local / d.npxb[q];
    int pxIdx = local - coIdx * d.npxb[q];
    const float* in = d.src[q];
    const float* w  = d.w[q];
    const float* b  = d.b[q];
    float* out = d.dst[q];
    int Cout = d.cout[q], NPX = d.npx[q], outBase = d.obase[q];

    __shared__ float s_in[16][64];
    __shared__ float s_w[16][64];
    int t = threadIdx.x;
    int pxg = t & 31, cg = t >> 5;
    int px0 = pxIdx * 64;
    int co0 = coIdx * 64;
    float acc[8][2];
#pragma unroll
    for (int c = 0; c < 8; ++c) { acc[c][0] = 0.f; acc[c][1] = 0.f; }
    int wco = t >> 2, wpart = t & 3;
    for (int ch = 0; ch < 16; ++ch) {
        int ci0 = ch << 4;
#pragma unroll
        for (int k = 0; k < 4; ++k) {
            int id = t + k * 256;
            int ci = id >> 6, pp = id & 63;
            int gp = px0 + pp;
            s_in[ci][pp] = (gp < NPX) ? in[(size_t)(ci0 + ci) * NPX + gp] : 0.f;
        }
        {
            int gco = co0 + wco;
            if (gco < Cout) {
                const float* run = w + (size_t)gco * 256 + ci0;
#pragma unroll
                for (int k = 0; k < 4; ++k) {
                    int e = wpart + 4 * k;
                    s_w[e][wco] = run[e];
                }
            } else {
#pragma unroll
                for (int k = 0; k < 4; ++k) s_w[wpart + 4 * k][wco] = 0.f;
            }
        }
        __syncthreads();
#pragma unroll
        for (int ci = 0; ci < 16; ++ci) {
            float i0 = s_in[ci][pxg * 2], i1 = s_in[ci][pxg * 2 + 1];
#pragma unroll
            for (int c = 0; c < 8; ++c) {
                float wv = s_w[ci][cg * 8 + c];
                acc[c][0] += wv * i0;
                acc[c][1] += wv * i1;
            }
        }
        __syncthreads();
    }
    for (int c = 0; c < 8; ++c) {
        int co = co0 + cg * 8 + c;
        if (co >= Cout) break;
        float bb = b[co];
#pragma unroll
        for (int j = 0; j < 2; ++j) {
            int p = px0 + pxg * 2 + j;
            if (p < NPX) out[(size_t)co * 8400 + outBase + p] = acc[c][j] + bb;
        }
    }
}

// ---------------- MFMA path: weight f16 hi/lo prep ----------------
__launch_bounds__(256)
__global__ void w2prep(const float* __restrict__ clsh_w, const float* __restrict__ regh_w,
                       const float* __restrict__ sm1_w, const float* __restrict__ sm2_w,
                       const float* __restrict__ sm3_w,
                       _Float16* __restrict__ WH, _Float16* __restrict__ WL)
{
    int idx = blockIdx.x * 256 + threadIdx.x;
    if (idx >= 11 * WSTEP9) return;
    int m = idx / WSTEP9, e = idx - m * WSTEP9;
    int co = e / 2304, r2 = e - co * 2304;
    int ci = r2 / 9, tap = r2 - ci * 9;
    const float* srcb;
    if (m < 4)       srcb = clsh_w + (size_t)m * WSTEP9;
    else if (m < 8)  srcb = regh_w + (size_t)(m - 4) * WSTEP9;
    else if (m == 8) srcb = sm1_w;
    else if (m == 9) srcb = sm2_w;
    else             srcb = sm3_w;
    float f = srcb[(size_t)co * 2304 + ci * 9 + tap];
    _Float16 h = (_Float16)f;
    _Float16 l = (_Float16)(f - (float)h);
    size_t d = (size_t)m * WSTEP9 + ((size_t)(tap * 256 + co)) * 256 + ci;
    WH[d] = h; WL[d] = l;
}

// ---------------- MFMA conv3x3 (fp16 3-term split) ----------------
// r14 structure (XCD-slice swizzle) + DISTANCE-2 A-prefetch: 3-slot ring,
// slot = tap%3 (compile-time after full unroll -> stays in registers).
// Loads for iteration g+2 issue at g -> ~2 iterations (~160-250 cyc incl
// MFMA issue + B-LDS reads) of cover vs ~200 cyc L2 latency; r14's 1-tap
// lookahead gave only ~60-80 cyc (MfmaUtil 11%, ~80% latency stall).
struct MC {
    const float*    src[2][3];
    float*          dst[2][3];
    const _Float16* wh[2][3];
    const _Float16* wl[2][3];
    const float*    bias[2][3];
    int act;
    int nbr;
};

__launch_bounds__(256)
__global__ void mconv3x3(MC p)
{
    __shared__ __align__(16) _Float16 SH[2][108 * 40];
    __shared__ __align__(16) _Float16 SL[2][108 * 40];
    int t = threadIdx.x;
    int NS = 4 * p.nbr;
    int bid = blockIdx.x;
    int slice = bid % NS;
    int sp = bid / NS;                        // 0..139: 100 L3, 30 L4, 10 L5
    int br = slice % p.nbr;
    int co0 = (slice / p.nbr) * 64;
    int lvl = (sp < 100) ? 0 : (sp < 130) ? 1 : 2;
    int tloc = sp - ((lvl == 0) ? 0 : (lvl == 1) ? 100 : 130);
    int W = (lvl == 0) ? 80 : (lvl == 1) ? 40 : 20;
    int nTx = (lvl == 0) ? 5 : (lvl == 1) ? 3 : 2;
    int HW = W * W;
    int bx0 = (tloc % nTx) * 16, by0 = (tloc / nTx) * 4;
    const float* src = p.src[br][lvl];
    float* dst = p.dst[br][lvl];
    const _Float16* wh = p.wh[br][lvl];
    const _Float16* wl = p.wl[br][lvl];
    const float* bias = p.bias[br][lvl];

    int lane = t & 63, wid = t >> 6;
    int cw = wid & 1, pw = wid >> 1;
    int colc = lane & 15, g = lane >> 4;

    // staging descriptors: 1728 ci-pair slots (108 cells x 16 pairs)
    int sgo[7], sla[7];
#pragma unroll
    for (int k = 0; k < 7; ++k) {
        int s2 = t + k * 256;
        sgo[k] = -1; sla[k] = 0;
        if (s2 < 1728) {
            int ci2 = s2 / 108, cell = s2 - ci2 * 108;
            int r = cell / 18, c = cell - r * 18;
            sla[k] = cell * 40 + ci2 * 2;
            int gy = by0 - 1 + r, gx = bx0 - 1 + c;
            if (gy >= 0 && gy < W && gx >= 0 && gx < W)
                sgo[k] = (ci2 * 2) * HW + gy * W + gx;
        }
    }

    f32x4 acc[2][2];
#pragma unroll
    for (int mi = 0; mi < 2; ++mi)
#pragma unroll
        for (int ny = 0; ny < 2; ++ny) acc[mi][ny] = (f32x4)0.f;

    // stage chunk 0
#pragma unroll
    for (int k = 0; k < 7; ++k) {
        if (t + k * 256 < 1728) {
            float v0 = 0.f, v1 = 0.f;
            if (sgo[k] >= 0) { v0 = src[sgo[k]]; v1 = src[sgo[k] + HW]; }
            _Float16 h0 = (_Float16)v0, h1 = (_Float16)v1;
            _Float16 l0 = (_Float16)(v0 - (float)h0), l1 = (_Float16)(v1 - (float)h1);
            f16x2 ph = {h0, h1}, pl = {l0, l1};
            *(f16x2*)&SH[0][sla[k]] = ph;
            *(f16x2*)&SL[0][sla[k]] = pl;
        }
    }
    __syncthreads();

    int coA = co0 + cw * 32 + colc;
    auto aoff = [&](int ckk, int tap) -> size_t {
        return ((size_t)(tap * 256 + coA)) * 256 + ckk * 32 + g * 8;
    };
    // 3-slot A-frag ring (indices compile-time after unroll)
    f16x8 Ah0[3], Al0[3], Ah1[3], Al1[3];
    {
        size_t a = aoff(0, 0);
        Ah0[0] = *(const f16x8*)(wh + a);        Al0[0] = *(const f16x8*)(wl + a);
        Ah1[0] = *(const f16x8*)(wh + a + 4096); Al1[0] = *(const f16x8*)(wl + a + 4096);
        a = aoff(0, 1);
        Ah0[1] = *(const f16x8*)(wh + a);        Al0[1] = *(const f16x8*)(wl + a);
        Ah1[1] = *(const f16x8*)(wh + a + 4096); Al1[1] = *(const f16x8*)(wl + a + 4096);
    }
    for (int ck = 0; ck < 8; ++ck) {
        const _Float16* sh  = SH[ck & 1];
        const _Float16* sl_ = SL[ck & 1];
        float pv[14];
        bool pf = (ck < 7);
        if (pf) {
            const float* sb = src + (size_t)(ck + 1) * 32 * HW;
#pragma unroll
            for (int k = 0; k < 7; ++k) {
                pv[2 * k] = 0.f; pv[2 * k + 1] = 0.f;
                if (t + k * 256 < 1728 && sgo[k] >= 0) {
                    pv[2 * k] = sb[sgo[k]]; pv[2 * k + 1] = sb[sgo[k] + HW];
                }
            }
        }
#pragma unroll
        for (int tap = 0; tap < 9; ++tap) {
            int ky = tap / 3, kx = tap - ky * 3;
            int slot = tap % 3;
            int nsl  = (tap + 2) % 3;
            // prefetch A-frags for global iteration g+2
            int pck = ck, ptap = tap + 2;
            if (ptap >= 9) { ptap -= 9; if (pf) pck = ck + 1; }
            size_t an = aoff(pck, ptap);
            Ah0[nsl] = *(const f16x8*)(wh + an);
            Al0[nsl] = *(const f16x8*)(wl + an);
            Ah1[nsl] = *(const f16x8*)(wh + an + 4096);
            Al1[nsl] = *(const f16x8*)(wl + an + 4096);
#pragma unroll
            for (int ny = 0; ny < 2; ++ny) {
                int cell = (pw * 2 + ny + ky) * 18 + colc + kx;
                f16x8 bh = *(const f16x8*)(sh  + cell * 40 + g * 8);
                f16x8 bl = *(const f16x8*)(sl_ + cell * 40 + g * 8);
                acc[0][ny] = MFMA16(Ah0[slot], bh, acc[0][ny], 0, 0, 0);
                acc[1][ny] = MFMA16(Ah1[slot], bh, acc[1][ny], 0, 0, 0);
                acc[0][ny] = MFMA16(Ah0[slot], bl, acc[0][ny], 0, 0, 0);
                acc[1][ny] = MFMA16(Ah1[slot], bl, acc[1][ny], 0, 0, 0);
                acc[0][ny] = MFMA16(Al0[slot], bh, acc[0][ny], 0, 0, 0);
                acc[1][ny] = MFMA16(Al1[slot], bh, acc[1][ny], 0, 0, 0);
            }
        }
        if (pf) {
            _Float16* nh = SH[(ck + 1) & 1];
            _Float16* nl = SL[(ck + 1) & 1];
#pragma unroll
            for (int k = 0; k < 7; ++k) {
                if (t + k * 256 < 1728) {
                    float v0 = pv[2 * k], v1 = pv[2 * k + 1];
                    _Float16 h0 = (_Float16)v0, h1 = (_Float16)v1;
                    _Float16 l0 = (_Float16)(v0 - (float)h0), l1 = (_Float16)(v1 - (float)h1);
                    f16x2 ph = {h0, h1}, pl = {l0, l1};
                    *(f16x2*)&nh[sla[k]] = ph;
                    *(f16x2*)&nl[sla[k]] = pl;
                }
            }
        }
        __syncthreads();
    }

    int x = bx0 + colc;
    if (x < W) {
#pragma unroll
        for (int mi = 0; mi < 2; ++mi) {
            int cob = co0 + cw * 32 + mi * 16 + g * 4;
#pragma unroll
            for (int ny = 0; ny < 2; ++ny) {
                int y = by0 + pw * 2 + ny;
#pragma unroll
                for (int i = 0; i < 4; ++i) {
                    int co = cob + i;
                    float v = acc[mi][ny][i] + bias[co];
                    if (p.act) v = (v >= 0.f) ? v : 0.1f * v;
                    dst[(size_t)co * HW + y * W + x] = v;
                }
            }
        }
    }
}

// ---------------- decode: scores, argmax, boxes, sort keys ----------------
__launch_bounds__(256)
__global__ void decode_kernel(const float* __restrict__ cls, const float* __restrict__ reg,
                              const float* __restrict__ ctn, float* __restrict__ out,
                              unsigned long long* __restrict__ keys)
{
    int p = blockIdx.x * 256 + threadIdx.x;
    if (p >= 16384) return;
    if (p >= 8400) { keys[p] = ~0ull; return; }
    int base, hs; float s;
    if (p < 6400)      { base = 0;    hs = 80; s = 8.f;  }
    else if (p < 8000) { base = 6400; hs = 40; s = 16.f; }
    else               { base = 8000; hs = 20; s = 32.f; }
    int local = p - base;
    float gx = (float)(local % hs), gy = (float)(local / hs);
    float ct = ctn[p];
    float sct = 1.f / (1.f + expf(-ct));
    float best = -1.f; int arg = 0;
    for (int c = 0; c < 80; ++c) {
        float v = cls[(size_t)c * 8400 + p];
        float sv = 1.f / (1.f + expf(-v));
        float sc = sqrtf(sv * sct);
        if (sc > best) { best = sc; arg = c; }
    }
    float r0 = reg[0 * 8400 + p], r1 = reg[1 * 8400 + p];
    float r2 = reg[2 * 8400 + p], r3 = reg[3 * 8400 + p];
    float x1 = (gx - expf(r0)) * s / 640.f;
    float y1 = (gy - expf(r1)) * s / 640.f;
    float x2 = (gx + expf(r2)) * s / 640.f;
    float y2 = (gy + expf(r3)) * s / 640.f;
    x1 = fminf(fmaxf(x1, 0.f), 1.f);
    y1 = fminf(fmaxf(y1, 0.f), 1.f);
    x2 = fminf(fmaxf(x2, 0.f), 1.f);
    y2 = fminf(fmaxf(y2, 0.f), 1.f);
    out[p * 4 + 0] = x1; out[p * 4 + 1] = y1;
    out[p * 4 + 2] = x2; out[p * 4 + 3] = y2;
    out[33600 + p] = best;
    out[42000 + p] = (float)arg;
    out[50400 + p] = 0.f;
    unsigned int ub = __float_as_uint(best);
    keys[p] = ((unsigned long long)(~ub) << 32) | (unsigned int)p;
}

// ---------------- hybrid bitonic sort of 16384 u64 keys ----------------
__launch_bounds__(256)
__global__ void bitonic_local(unsigned long long* __restrict__ keys, unsigned kmerge)
{
    __shared__ unsigned long long sk[2048];
    int t = threadIdx.x;
    unsigned base = blockIdx.x * 2048u;
#pragma unroll
    for (int m = 0; m < 8; ++m) sk[t + m * 256] = keys[base + t + m * 256];
    __syncthreads();
    if (kmerge == 0u) {
        for (unsigned k = 2; k <= 2048u; k <<= 1) {
            for (unsigned j = k >> 1; j > 0; j >>= 1) {
#pragma unroll
                for (int pp = 0; pp < 4; ++pp) {
                    unsigned p = (unsigned)t + pp * 256u;
                    unsigned li = ((p & ~(j - 1)) << 1) | (p & (j - 1));
                    unsigned gi = base + li;
                    bool up = ((gi & k) == 0);
                    unsigned long long a = sk[li], b = sk[li + j];
                    if ((a > b) == up) { sk[li] = b; sk[li + j] = a; }
                }
                __syncthreads();
            }
        }
    } else {
        unsigned k = kmerge;
        for (unsigned j = 1024; j > 0; j >>= 1) {
#pragma unroll
            for (int pp = 0; pp < 4; ++pp) {
                unsigned p = (unsigned)t + pp * 256u;
                unsigned li = ((p & ~(j - 1)) << 1) | (p & (j - 1));
                unsigned gi = base + li;
                bool up = ((gi & k) == 0);
                unsigned long long a = sk[li], b = sk[li + j];
                if ((a > b) == up) { sk[li] = b; sk[li + j] = a; }
            }
            __syncthreads();
        }
    }
#pragma unroll
    for (int m = 0; m < 8; ++m) keys[base + t + m * 256] = sk[t + m * 256];
}

__launch_bounds__(256)
__global__ void bitonic_global(unsigned long long* __restrict__ keys, unsigned k, unsigned j)
{
    unsigned p = blockIdx.x * 256u + threadIdx.x;
    unsigned i = ((p & ~(j - 1)) << 1) | (p & (j - 1));
    bool up = ((i & k) == 0);
    unsigned long long a = keys[i], b = keys[i + j];
    if ((a > b) == up) { keys[i] = b; keys[i + j] = a; }
}

// ---------------- expand sorted keys into SoA arrays ----------------
__launch_bounds__(256)
__global__ void sorted_aux(const unsigned long long* __restrict__ keys,
                           const float* __restrict__ out,
                           float* __restrict__ scs, int* __restrict__ clss,
                           int* __restrict__ idxs)
{
    int i = blockIdx.x * 256 + threadIdx.x;
    if (i >= 16384) return;
    unsigned long long key = keys[i];
    unsigned ub = ~(unsigned)(key >> 32);
    float sc = __uint_as_float(ub);
    unsigned idx = (unsigned)(key & 0xffffffffu);
    int cl = -1;
    if (idx < 8400u) cl = (int)out[42000 + idx];
    else sc = 0.f;
    scs[i] = sc; clss[i] = cl; idxs[i] = (int)idx;
}

// ---------------- NMS stage 1: per-class stable compaction ----------------
__launch_bounds__(256)
__global__ void compact_cls(const float* __restrict__ scs, const int* __restrict__ clss,
                            const int* __restrict__ idxs, const float* __restrict__ outbuf,
                            float* __restrict__ GX1, float* __restrict__ GY1,
                            float* __restrict__ GX2, float* __restrict__ GY2,
                            float* __restrict__ GAR, int* __restrict__ GIX,
                            int* __restrict__ NCOUNT, int* __restrict__ NBASE)
{
    int c = blockIdx.x, t = threadIdx.x;
    __shared__ int s_red[2];
    __shared__ int s_wtot[4];
    int cb = 0, co = 0;
    for (int i = t; i < 16384; i += 256) {
        float sc = scs[i]; int cl = clss[i];
        if (sc >= CONF_T && cl >= 0) { cb += (cl < c); co += (cl == c); }
    }
    if (t == 0) { s_red[0] = 0; s_red[1] = 0; }
    __syncthreads();
    atomicAdd(&s_red[0], cb);
    atomicAdd(&s_red[1], co);
    __syncthreads();
    int base = s_red[0], n = s_red[1];
    if (t == 0) { NCOUNT[c] = n; NBASE[c] = base; }

    int rank = 0;
    for (int st = 0; st < 16384; st += 256) {
        int i = st + t;
        float sc = scs[i]; int cl = clss[i];
        bool flag = (sc >= CONF_T && cl == c);
        unsigned long long m = __ballot(flag);
        int lane = t & 63, wv = t >> 6;
        if (lane == 0) s_wtot[wv] = __popcll(m);
        __syncthreads();
        int off = rank;
        for (int w = 0; w < wv; ++w) off += s_wtot[w];
        int tot = s_wtot[0] + s_wtot[1] + s_wtot[2] + s_wtot[3];
        if (flag) {
            int pos = off + __popcll(m & ((1ull << lane) - 1ull));
            int idx = idxs[i];
            float x1 = outbuf[idx * 4 + 0], y1 = outbuf[idx * 4 + 1];
            float x2 = outbuf[idx * 4 + 2], y2 = outbuf[idx * 4 + 3];
            GX1[base + pos] = x1; GY1[base + pos] = y1;
            GX2[base + pos] = x2; GY2[base + pos] = y2;
            GAR[base + pos] = (x2 - x1) * (y2 - y1);
            GIX[base + pos] = idx;
        }
        rank += tot;
        __syncthreads();
    }
}

// ---------------- NMS stage 2: suppression bit-matrix (parallel) ----------------
__launch_bounds__(256)
__global__ void nms_mask(const float* __restrict__ GX1, const float* __restrict__ GY1,
                         const float* __restrict__ GX2, const float* __restrict__ GY2,
                         const float* __restrict__ GAR,
                         const int* __restrict__ NCOUNT, const int* __restrict__ NBASE,
                         unsigned long long* __restrict__ MASK)
{
    int c = blockIdx.y;
    int n = NCOUNT[c];
    if ((int)(blockIdx.x * 256) >= n) return;
    int base = NBASE[c];
    int t = threadIdx.x;
    int r = blockIdx.x * 256 + t;
    bool hav = (r < n);
    float rx1 = 0.f, ry1 = 0.f, rx2 = 0.f, ry2 = 0.f, rar = 0.f;
    if (hav) {
        rx1 = GX1[base + r]; ry1 = GY1[base + r];
        rx2 = GX2[base + r]; ry2 = GY2[base + r];
        rar = GAR[base + r];
    }
    __shared__ float tx1[2048], ty1[2048], tx2[2048], ty2[2048], tar[2048];
    for (int jt = 0; jt < n; jt += 2048) {
        int cnt = min(2048, n - jt);
        __syncthreads();
        for (int k = t; k < cnt; k += 256) {
            tx1[k] = GX1[base + jt + k]; ty1[k] = GY1[base + jt + k];
            tx2[k] = GX2[base + jt + k]; ty2[k] = GY2[base + jt + k];
            tar[k] = GAR[base + jt + k];
        }
        __syncthreads();
        if (hav) {
            int w0 = jt >> 6;
            int nw = (cnt + 63) >> 6;
            for (int w = 0; w < nw; ++w) {
                int jb = jt + w * 64;
                unsigned long long bits = 0ull;
                if (jb + 63 > r) {
                    int kmax = min(64, n - jb);
                    for (int kk = 0; kk < kmax; ++kk) {
                        int j = jb + kk;
                        if (j > r) {
                            int k2 = j - jt;
                            float xx1 = fmaxf(rx1, tx1[k2]);
                            float yy1 = fmaxf(ry1, ty1[k2]);
                            float xx2 = fminf(rx2, tx2[k2]);
                            float yy2 = fminf(ry2, ty2[k2]);
                            float ww = fmaxf(1e-28f, xx2 - xx1);
                            float hh = fmaxf(1e-28f, yy2 - yy1);
                            float inter = ww * hh;
                            float ovr = inter / (rar + tar[k2] - inter);
                            if (ovr > NMS_T) bits |= (1ull << kk);
                        }
                    }
                }
                MASK[(size_t)(base + r) * WMAX + w0 + w] = bits;
            }
        }
    }
}

// ---------------- NMS stage 3: chunked bitmask scan (80 blocks) ----------------
__launch_bounds__(256)
__global__ void nms_scan(const unsigned long long* __restrict__ MASK,
                         const int* __restrict__ GIX,
                         const int* __restrict__ NCOUNT, const int* __restrict__ NBASE,
                         float* __restrict__ keep)
{
    int c = blockIdx.x, t = threadIdx.x;
    int n = NCOUNT[c];
    if (n == 0) return;
    int base = NBASE[c];
    int Wc = (n + 63) >> 6;
    __shared__ unsigned long long remv[WMAX];
    __shared__ unsigned long long sld[32][WMAX];
    __shared__ unsigned int s_alive;
    for (int w = t; w < Wc; w += 256) remv[w] = 0ull;
    __syncthreads();
    for (int i0 = 0; i0 < n; i0 += 32) {
        int rows = min(32, n - i0);
        int tot = rows * Wc;
        for (int k = t; k < tot; k += 256) {
            int rr = k / Wc, w = k - rr * Wc;
            sld[rr][w] = MASK[(size_t)(base + i0 + rr) * WMAX + w];
        }
        __syncthreads();
        if (t == 0) {
            int wq = i0 >> 6, b0 = i0 & 63;
            unsigned long long lw = remv[wq];
            unsigned am = 0;
            for (int rr = 0; rr < rows; ++rr) {
                if (!((lw >> (b0 + rr)) & 1ull)) {
                    am |= (1u << rr);
                    lw |= sld[rr][wq];
                }
            }
            s_alive = am;
        }
        __syncthreads();
        unsigned am = s_alive;
        for (int w = t; w < Wc; w += 256) {
            unsigned long long acc = remv[w];
            unsigned m = am;
            while (m) { int rr = __ffs(m) - 1; m &= m - 1; acc |= sld[rr][w]; }
            remv[w] = acc;
        }
        if (t < rows && ((am >> t) & 1u)) keep[GIX[base + i0 + t]] = 1.0f;
        __syncthreads();
    }
}

// ---------------- host orchestration ----------------
extern "C" void kernel_launch(void* const* d_in, const int* in_sizes, int n_in,
                              void* d_out, int out_size, void* d_ws, size_t ws_size,
                              hipStream_t stream)
{
    const float* c3      = (const float*)d_in[0];
    const float* c4      = (const float*)d_in[1];
    const float* c5      = (const float*)d_in[2];
    const float* lat1_w  = (const float*)d_in[3];
    const float* lat1_b  = (const float*)d_in[4];
    const float* lat2_w  = (const float*)d_in[5];
    const float* lat2_b  = (const float*)d_in[6];
    const float* lat3_w  = (const float*)d_in[7];
    const float* lat3_b  = (const float*)d_in[8];
    const float* sm1_w   = (const float*)d_in[9];
    const float* sm1_b   = (const float*)d_in[10];
    const float* sm2_w   = (const float*)d_in[11];
    const float* sm2_b   = (const float*)d_in[12];
    const float* sm3_w   = (const float*)d_in[13];
    const float* sm3_b   = (const float*)d_in[14];
    const float* clsh_w  = (const float*)d_in[15];
    const float* clsh_b  = (const float*)d_in[16];
    const float* regh_w  = (const float*)d_in[17];
    const float* regh_b  = (const float*)d_in[18];
    const float* clsd_w  = (const float*)d_in[19];
    const float* clsd_b  = (const float*)d_in[20];
    const float* regd_w  = (const float*)d_in[21];
    const float* regd_b  = (const float*)d_in[22];
    const float* ctnd_w  = (const float*)d_in[23];
    const float* ctnd_b  = (const float*)d_in[24];

    float* ws = (float*)d_ws;
    float* T3 = ws + OFF_T3;  float* T4 = ws + OFF_T4;  float* T5 = ws + OFF_T5;
    float* P3 = ws + OFF_P3;  float* P4 = ws + OFF_P4;  float* P5 = ws + OFF_P5;
    float* HA3 = ws + OFF_HA3; float* HA4 = ws + OFF_HA4; float* HA5 = ws + OFF_HA5;
    float* HB3 = ws + OFF_HB3; float* HB4 = ws + OFF_HB4; float* HB5 = ws + OFF_HB5;
    float* HD3 = ws + OFF_HD3; float* HD4 = ws + OFF_HD4; float* HD5 = ws + OFF_HD5;
    float* CLS = ws + OFF_CLS; float* REG = ws + OFF_REG; float* CTN = ws + OFF_CTN;
    _Float16* WH = (_Float16*)(ws + OFF_W2H);
    _Float16* WL = (_Float16*)(ws + OFF_W2L);
    unsigned long long* KEYS = (unsigned long long*)(ws + POFF_KEYS);
    float* SCS = ws + POFF_SCS;
    int* CLSS = (int*)(ws + POFF_CLSS);
    int* IDXS = (int*)(ws + POFF_IDXS);
    float* GX1 = ws + POFF_GX1; float* GY1 = ws + POFF_GY1;
    float* GX2 = ws + POFF_GX2; float* GY2 = ws + POFF_GY2;
    float* GAR = ws + POFF_GAR;
    int* GIX = (int*)(ws + POFF_GIX);
    int* NCOUNT = (int*)(ws + POFF_NCNT);
    int* NBASE  = (int*)(ws + POFF_NBASE);
    unsigned long long* MASK = (unsigned long long*)(ws + POFF_MASK);

    float* out = (float*)d_out;
    dim3 blk(256);

    // weight f16 hi/lo prep (11 matrices)
    w2prep<<<dim3((11 * WSTEP9 + 255) / 256), blk, 0, stream>>>(
        clsh_w, regh_w, sm1_w, sm2_w, sm3_w, WH, WL);

    // FPN laterals (dependency chain), then all smooths fused (MFMA)
    conv1x1_kernel<<<dim3(7, 4), blk, 0, stream>>>(c5, lat3_w, lat3_b, T5, nullptr,
                                                   512, 256, 400, 20, 400, 0);
    conv1x1_kernel<<<dim3(25, 4), blk, 0, stream>>>(c4, lat2_w, lat2_b, T4, T5,
                                                    256, 256, 1600, 40, 1600, 0);
    conv1x1_kernel<<<dim3(100, 4), blk, 0, stream>>>(c3, lat1_w, lat1_b, T3, T4,
                                                     128, 256, 6400, 80, 6400, 0);
    {
        MC mc{};
        float* sT[3] = {T3, T4, T5};
        float* sP[3] = {P3, P4, P5};
        const float* sB[3] = {sm1_b, sm2_b, sm3_b};
        for (int l = 0; l < 3; ++l) {
            mc.src[0][l] = sT[l]; mc.dst[0][l] = sP[l];
            mc.wh[0][l] = WH + (size_t)(8 + l) * WSTEP9;
            mc.wl[0][l] = WL + (size_t)(8 + l) * WSTEP9;
            mc.bias[0][l] = sB[l];
        }
        mc.act = 0; mc.nbr = 1;
        mconv3x3<<<dim3(140 * 4), blk, 0, stream>>>(mc);
    }
    // heads: 4 MFMA layers (slice-swizzled 1D grid)
    {
        float* clsS[3][5] = { {P3, HA3, HB3, HA3, HB3},
                              {P4, HA4, HB4, HA4, HB4},
                              {P5, HA5, HB5, HA5, HB5} };
        float* regS[3][5] = { {P3, T3,  HD3, T3,  HD3},
                              {P4, T4,  HD4, T4,  HD4},
                              {P5, T5,  HD5, T5,  HD5} };
        for (int i = 0; i < 4; ++i) {
            MC mc{};
            for (int l = 0; l < 3; ++l) {
                mc.src[0][l] = clsS[l][i]; mc.dst[0][l] = clsS[l][i + 1];
                mc.src[1][l] = regS[l][i]; mc.dst[1][l] = regS[l][i + 1];
                mc.wh[0][l] = WH + (size_t)i * WSTEP9;
                mc.wl[0][l] = WL + (size_t)i * WSTEP9;
                mc.wh[1][l] = WH + (size_t)(4 + i) * WSTEP9;
                mc.wl[1][l] = WL + (size_t)(4 + i) * WSTEP9;
                mc.bias[0][l] = clsh_b + i * 256;
                mc.bias[1][l] = regh_b + i * 256;
            }
            mc.act = 1; mc.nbr = 2;
            mconv3x3<<<dim3(140 * 8), blk, 0, stream>>>(mc);
        }
    }

    // ---- detectors: all 9 (level x {cls,reg,ctn}) in one dispatch ----
    {
        Det9 d;
        const float* feats[3][2] = { {HB3, HD3}, {HB4, HD4}, {HB5, HD5} };
        int   npx[3]   = {6400, 1600, 400};
        int   obase[3] = {0, 6400, 8000};
        int q = 0, bacc = 0;
        for (int l = 0; l < 3; ++l) {
            d.src[q] = feats[l][0]; d.w[q] = clsd_w; d.b[q] = clsd_b; d.dst[q] = CLS;
            d.cout[q] = 80; d.npx[q] = npx[l]; d.obase[q] = obase[l];
            d.bstart[q] = bacc; d.npxb[q] = (npx[l] + 63) / 64;
            bacc += d.npxb[q] * 2; ++q;
            d.src[q] = feats[l][1]; d.w[q] = regd_w; d.b[q] = regd_b; d.dst[q] = REG;
            d.cout[q] = 4; d.npx[q] = npx[l]; d.obase[q] = obase[l];
            d.bstart[q] = bacc; d.npxb[q] = (npx[l] + 63) / 64;
            bacc += d.npxb[q]; ++q;
            d.src[q] = feats[l][1]; d.w[q] = ctnd_w; d.b[q] = ctnd_b; d.dst[q] = CTN;
            d.cout[q] = 1; d.npx[q] = npx[l]; d.obase[q] = obase[l];
            d.bstart[q] = bacc; d.npxb[q] = (npx[l] + 63) / 64;
            bacc += d.npxb[q]; ++q;
        }
        det1x1_fused<<<dim3(bacc), blk, 0, stream>>>(d);
    }

    // ---- decode ----
    decode_kernel<<<dim3(64), blk, 0, stream>>>(CLS, REG, CTN, out, KEYS);

    // ---- hybrid bitonic sort ----
    bitonic_local<<<dim3(8), blk, 0, stream>>>(KEYS, 0u);
    bitonic_global<<<dim3(32), blk, 0, stream>>>(KEYS, 4096u, 2048u);
    bitonic_local<<<dim3(8), blk, 0, stream>>>(KEYS, 4096u);
    bitonic_global<<<dim3(32), blk, 0, stream>>>(KEYS, 8192u, 4096u);
    bitonic_global<<<dim3(32), blk, 0, stream>>>(KEYS, 8192u, 2048u);
    bitonic_local<<<dim3(8), blk, 0, stream>>>(KEYS, 8192u);
    bitonic_global<<<dim3(32), blk, 0, stream>>>(KEYS, 16384u, 8192u);
    bitonic_global<<<dim3(32), blk, 0, stream>>>(KEYS, 16384u, 4096u);
    bitonic_global<<<dim3(32), blk, 0, stream>>>(KEYS, 16384u, 2048u);
    bitonic_local<<<dim3(8), blk, 0, stream>>>(KEYS, 16384u);

    // ---- NMS pipeline ----
    sorted_aux<<<dim3(64), blk, 0, stream>>>(KEYS, out, SCS, CLSS, IDXS);
    compact_cls<<<dim3(80), blk, 0, stream>>>(SCS, CLSS, IDXS, out,
                                              GX1, GY1, GX2, GY2, GAR, GIX, NCOUNT, NBASE);
    nms_mask<<<dim3(33, 80), blk, 0, stream>>>(GX1, GY1, GX2, GY2, GAR, NCOUNT, NBASE, MASK);
    nms_scan<<<dim3(80), blk, 0, stream>>>(MASK, GIX, NCOUNT, NBASE, out + 50400);
}

// Round 16
// 1092.128 us; speedup vs baseline: 2.6983x; 1.3430x over previous
//
#include <hip/hip_runtime.h>
#include <stdint.h>

#define CONF_T 0.05f
#define NMS_T  0.5f
#define WMAX   132           // ceil(8400/64)
#define WSTEP9 589824        // 256*256*9

typedef _Float16 f16x8 __attribute__((ext_vector_type(8)));
typedef _Float16 f16x2 __attribute__((ext_vector_type(2)));
typedef float    f32x4 __attribute__((ext_vector_type(4)));
#define MFMA16 __builtin_amdgcn_mfma_f32_16x16x32_f16

// ---- workspace layout (float offsets) ----
#define OFF_T3   0u
#define OFF_T4   1638400u
#define OFF_T5   2048000u
#define OFF_P3   2150400u
#define OFF_P4   3788800u
#define OFF_P5   4198400u
#define OFF_HA3  4300800u
#define OFF_HA4  5939200u
#define OFF_HA5  6348800u
#define OFF_HB3  6451200u
#define OFF_HB4  8089600u
#define OFF_HB5  8499200u
#define OFF_HD3  8601600u
#define OFF_HD4  10240000u
#define OFF_HD5  10649600u
#define OFF_CLS  10752000u
#define OFF_REG  11424000u
#define OFF_CTN  11457600u
#define OFF_W2H  11466000u                 // 11 matrices x 589824 f16 (hi)
#define OFF_W2L  14710032u                 // (lo)
#define WS_NEED  17954064u
// post-processing arrays (T3 region, free after conv stack)
#define POFF_KEYS  (OFF_T3 + 0u)
#define POFF_SCS   (OFF_T3 + 32768u)
#define POFF_CLSS  (OFF_T3 + 49152u)
#define POFF_IDXS  (OFF_T3 + 65536u)
#define POFF_GX1   (OFF_T3 + 81920u)
#define POFF_GY1   (OFF_T3 + 90320u)
#define POFF_GX2   (OFF_T3 + 98720u)
#define POFF_GY2   (OFF_T3 + 107120u)
#define POFF_GAR   (OFF_T3 + 115520u)
#define POFF_GIX   (OFF_T3 + 123920u)
#define POFF_NCNT  (OFF_T3 + 132320u)
#define POFF_NBASE (OFF_T3 + 132400u)
#define POFF_MASK  OFF_HA3

// ---------------- conv 1x1 (+ optional nearest-up2 add) ----------------
__launch_bounds__(256)
__global__ void conv1x1_kernel(const float* __restrict__ in, const float* __restrict__ w,
                               const float* __restrict__ b, float* __restrict__ out,
                               const float* __restrict__ add,
                               int Cin, int Cout, int NPX, int W, int outStride, int outBase)
{
    __shared__ float s_in[16][64];
    __shared__ float s_w[16][64];
    int t = threadIdx.x;
    int pxg = t & 31, cg = t >> 5;
    int px0 = blockIdx.x * 64;
    int co0 = blockIdx.y * 64;
    float acc[8][2];
#pragma unroll
    for (int c = 0; c < 8; ++c) { acc[c][0] = 0.f; acc[c][1] = 0.f; }
    int chunks = Cin >> 4;
    int wco = t >> 2, wpart = t & 3;
    for (int ch = 0; ch < chunks; ++ch) {
        int ci0 = ch << 4;
#pragma unroll
        for (int k = 0; k < 4; ++k) {
            int id = t + k * 256;
            int ci = id >> 6, pp = id & 63;
            int gp = px0 + pp;
            s_in[ci][pp] = (gp < NPX) ? in[(size_t)(ci0 + ci) * NPX + gp] : 0.f;
        }
        {
            int gco = co0 + wco;
            if (gco < Cout) {
                const float* run = w + (size_t)gco * Cin + ci0;
#pragma unroll
                for (int k = 0; k < 4; ++k) {
                    int e = wpart + 4 * k;
                    s_w[e][wco] = run[e];
                }
            } else {
#pragma unroll
                for (int k = 0; k < 4; ++k) s_w[wpart + 4 * k][wco] = 0.f;
            }
        }
        __syncthreads();
#pragma unroll
        for (int ci = 0; ci < 16; ++ci) {
            float i0 = s_in[ci][pxg * 2], i1 = s_in[ci][pxg * 2 + 1];
#pragma unroll
            for (int c = 0; c < 8; ++c) {
                float wv = s_w[ci][cg * 8 + c];
                acc[c][0] += wv * i0;
                acc[c][1] += wv * i1;
            }
        }
        __syncthreads();
    }
    for (int c = 0; c < 8; ++c) {
        int co = co0 + cg * 8 + c;
        if (co >= Cout) break;
        float bb = b[co];
#pragma unroll
        for (int j = 0; j < 2; ++j) {
            int p = px0 + pxg * 2 + j;
            if (p < NPX) {
                float v = acc[c][j] + bb;
                if (add) {
                    int y = p / W, x = p % W;
                    int Sp = W >> 1;
                    v += add[(size_t)co * (Sp * Sp) + (y >> 1) * Sp + (x >> 1)];
                }
                out[(size_t)co * outStride + outBase + p] = v;
            }
        }
    }
}

// ---------------- fused detector 1x1 (9 combos in one dispatch) ----------------
struct Det9 {
    const float* src[9]; const float* w[9]; const float* b[9];
    float*       dst[9];
    int cout[9], npx[9], obase[9], bstart[9], npxb[9];
};

__launch_bounds__(256)
__global__ void det1x1_fused(Det9 d)
{
    int bid = blockIdx.x;
    int q = 0;
#pragma unroll
    for (int i = 1; i < 9; ++i) if (bid >= d.bstart[i]) q = i;
    int local = bid - d.bstart[q];
    int coIdx = local / d.npxb[q];
    int pxIdx = local - coIdx * d.npxb[q];
    const float* in = d.src[q];
    const float* w  = d.w[q];
    const float* b  = d.b[q];
    float* out = d.dst[q];
    int Cout = d.cout[q], NPX = d.npx[q], outBase = d.obase[q];

    __shared__ float s_in[16][64];
    __shared__ float s_w[16][64];
    int t = threadIdx.x;
    int pxg = t & 31, cg = t >> 5;
    int px0 = pxIdx * 64;
    int co0 = coIdx * 64;
    float acc[8][2];
#pragma unroll
    for (int c = 0; c < 8; ++c) { acc[c][0] = 0.f; acc[c][1] = 0.f; }
    int wco = t >> 2, wpart = t & 3;
    for (int ch = 0; ch < 16; ++ch) {
        int ci0 = ch << 4;
#pragma unroll
        for (int k = 0; k < 4; ++k) {
            int id = t + k * 256;
            int ci = id >> 6, pp = id & 63;
            int gp = px0 + pp;
            s_in[ci][pp] = (gp < NPX) ? in[(size_t)(ci0 + ci) * NPX + gp] : 0.f;
        }
        {
            int gco = co0 + wco;
            if (gco < Cout) {
                const float* run = w + (size_t)gco * 256 + ci0;
#pragma unroll
                for (int k = 0; k < 4; ++k) {
                    int e = wpart + 4 * k;
                    s_w[e][wco] = run[e];
                }
            } else {
#pragma unroll
                for (int k = 0; k < 4; ++k) s_w[wpart + 4 * k][wco] = 0.f;
            }
        }
        __syncthreads();
#pragma unroll
        for (int ci = 0; ci < 16; ++ci) {
            float i0 = s_in[ci][pxg * 2], i1 = s_in[ci][pxg * 2 + 1];
#pragma unroll
            for (int c = 0; c < 8; ++c) {
                float wv = s_w[ci][cg * 8 + c];
                acc[c][0] += wv * i0;
                acc[c][1] += wv * i1;
            }
        }
        __syncthreads();
    }
    for (int c = 0; c < 8; ++c) {
        int co = co0 + cg * 8 + c;
        if (co >= Cout) break;
        float bb = b[co];
#pragma unroll
        for (int j = 0; j < 2; ++j) {
            int p = px0 + pxg * 2 + j;
            if (p < NPX) out[(size_t)co * 8400 + outBase + p] = acc[c][j] + bb;
        }
    }
}

// ---------------- MFMA path: weight f16 hi/lo prep (FRAGMENT-ORDER layout) ----
// New layout [m][tap][cob][ck][lane][8]: the A-frag load address is
// base + lane*8 -> fully coalesced 1KB contiguous per wave instruction.
// r15's [tap][cout][ci] layout had 512B stride between adjacent lanes ->
// every A-load fanned into ~16 TA transactions (the 11% MfmaUtil wall).
__launch_bounds__(256)
__global__ void w2prep(const float* __restrict__ clsh_w, const float* __restrict__ regh_w,
                       const float* __restrict__ sm1_w, const float* __restrict__ sm2_w,
                       const float* __restrict__ sm3_w,
                       _Float16* __restrict__ WH, _Float16* __restrict__ WL)
{
    int idx = blockIdx.x * 256 + threadIdx.x;
    if (idx >= 11 * WSTEP9) return;
    int m = idx / WSTEP9, e = idx - m * WSTEP9;
    int tap = e / 65536;            // 16 cob * 8 ck * 512
    int r   = e - tap * 65536;
    int cob = r / 4096;             // 8 ck * 512
    int r2  = r - cob * 4096;
    int ck  = r2 / 512;
    int r3  = r2 - ck * 512;
    int lane = r3 / 8, el = r3 - (r3 / 8) * 8;
    int co = cob * 16 + (lane & 15);
    int ci = ck * 32 + (lane >> 4) * 8 + el;
    const float* srcb;
    if (m < 4)       srcb = clsh_w + (size_t)m * WSTEP9;
    else if (m < 8)  srcb = regh_w + (size_t)(m - 4) * WSTEP9;
    else if (m == 8) srcb = sm1_w;
    else if (m == 9) srcb = sm2_w;
    else             srcb = sm3_w;
    float f = srcb[(size_t)co * 2304 + ci * 9 + tap];
    _Float16 h = (_Float16)f;
    _Float16 l = (_Float16)(f - (float)h);
    WH[idx] = h; WL[idx] = l;
}

// ---------------- MFMA conv3x3 (fp16 3-term split) ----------------
struct MC {
    const float*    src[2][3];
    float*          dst[2][3];
    const _Float16* wh[2][3];
    const _Float16* wl[2][3];
    const float*    bias[2][3];
    int act;
    int nbr;
};

__launch_bounds__(256)
__global__ void mconv3x3(MC p)
{
    __shared__ __align__(16) _Float16 SH[2][108 * 40];
    __shared__ __align__(16) _Float16 SL[2][108 * 40];
    int t = threadIdx.x;
    int NS = 4 * p.nbr;
    int bid = blockIdx.x;
    int slice = bid % NS;
    int sp = bid / NS;                        // 0..139: 100 L3, 30 L4, 10 L5
    int br = slice % p.nbr;
    int co0 = (slice / p.nbr) * 64;
    int lvl = (sp < 100) ? 0 : (sp < 130) ? 1 : 2;
    int tloc = sp - ((lvl == 0) ? 0 : (lvl == 1) ? 100 : 130);
    int W = (lvl == 0) ? 80 : (lvl == 1) ? 40 : 20;
    int nTx = (lvl == 0) ? 5 : (lvl == 1) ? 3 : 2;
    int HW = W * W;
    int bx0 = (tloc % nTx) * 16, by0 = (tloc / nTx) * 4;
    const float* src = p.src[br][lvl];
    float* dst = p.dst[br][lvl];
    const _Float16* wh = p.wh[br][lvl];
    const _Float16* wl = p.wl[br][lvl];
    const float* bias = p.bias[br][lvl];

    int lane = t & 63, wid = t >> 6;
    int cw = wid & 1, pw = wid >> 1;
    int colc = lane & 15, g = lane >> 4;

    // staging descriptors: 1728 ci-pair slots (108 cells x 16 pairs)
    int sgo[7], sla[7];
#pragma unroll
    for (int k = 0; k < 7; ++k) {
        int s2 = t + k * 256;
        sgo[k] = -1; sla[k] = 0;
        if (s2 < 1728) {
            int ci2 = s2 / 108, cell = s2 - ci2 * 108;
            int r = cell / 18, c = cell - r * 18;
            sla[k] = cell * 40 + ci2 * 2;
            int gy = by0 - 1 + r, gx = bx0 - 1 + c;
            if (gy >= 0 && gy < W && gx >= 0 && gx < W)
                sgo[k] = (ci2 * 2) * HW + gy * W + gx;
        }
    }

    f32x4 acc[2][2];
#pragma unroll
    for (int mi = 0; mi < 2; ++mi)
#pragma unroll
        for (int ny = 0; ny < 2; ++ny) acc[mi][ny] = (f32x4)0.f;

    // stage chunk 0
#pragma unroll
    for (int k = 0; k < 7; ++k) {
        if (t + k * 256 < 1728) {
            float v0 = 0.f, v1 = 0.f;
            if (sgo[k] >= 0) { v0 = src[sgo[k]]; v1 = src[sgo[k] + HW]; }
            _Float16 h0 = (_Float16)v0, h1 = (_Float16)v1;
            _Float16 l0 = (_Float16)(v0 - (float)h0), l1 = (_Float16)(v1 - (float)h1);
            f16x2 ph = {h0, h1}, pl = {l0, l1};
            *(f16x2*)&SH[0][sla[k]] = ph;
            *(f16x2*)&SL[0][sla[k]] = pl;
        }
    }
    __syncthreads();

    int cob0 = (co0 + cw * 32) >> 4;          // mi=0 A-block; mi=1 is cob0+1
    auto aoff = [&](int ckk, int tap, int mi) -> size_t {
        return ((size_t)((tap * 16 + cob0 + mi) * 8 + ckk)) * 512 + lane * 8;
    };
    // 3-slot A-frag ring (indices compile-time after unroll)
    f16x8 Ah0[3], Al0[3], Ah1[3], Al1[3];
    {
        size_t a0 = aoff(0, 0, 0), a1 = aoff(0, 0, 1);
        Ah0[0] = *(const f16x8*)(wh + a0); Al0[0] = *(const f16x8*)(wl + a0);
        Ah1[0] = *(const f16x8*)(wh + a1); Al1[0] = *(const f16x8*)(wl + a1);
        a0 = aoff(0, 1, 0); a1 = aoff(0, 1, 1);
        Ah0[1] = *(const f16x8*)(wh + a0); Al0[1] = *(const f16x8*)(wl + a0);
        Ah1[1] = *(const f16x8*)(wh + a1); Al1[1] = *(const f16x8*)(wl + a1);
    }
    for (int ck = 0; ck < 8; ++ck) {
        const _Float16* sh  = SH[ck & 1];
        const _Float16* sl_ = SL[ck & 1];
        float pv[14];
        bool pf = (ck < 7);
        if (pf) {
            const float* sb = src + (size_t)(ck + 1) * 32 * HW;
#pragma unroll
            for (int k = 0; k < 7; ++k) {
                pv[2 * k] = 0.f; pv[2 * k + 1] = 0.f;
                if (t + k * 256 < 1728 && sgo[k] >= 0) {
                    pv[2 * k] = sb[sgo[k]]; pv[2 * k + 1] = sb[sgo[k] + HW];
                }
            }
        }
#pragma unroll
        for (int tap = 0; tap < 9; ++tap) {
            int ky = tap / 3, kx = tap - ky * 3;
            int slot = tap % 3;
            int nsl  = (tap + 2) % 3;
            // prefetch A-frags for global iteration +2 (coalesced: base+lane*8)
            int pck = ck, ptap = tap + 2;
            if (ptap >= 9) { ptap -= 9; if (pf) pck = ck + 1; }
            size_t an0 = aoff(pck, ptap, 0), an1 = aoff(pck, ptap, 1);
            Ah0[nsl] = *(const f16x8*)(wh + an0);
            Al0[nsl] = *(const f16x8*)(wl + an0);
            Ah1[nsl] = *(const f16x8*)(wh + an1);
            Al1[nsl] = *(const f16x8*)(wl + an1);
#pragma unroll
            for (int ny = 0; ny < 2; ++ny) {
                int cell = (pw * 2 + ny + ky) * 18 + colc + kx;
                f16x8 bh = *(const f16x8*)(sh  + cell * 40 + g * 8);
                f16x8 bl = *(const f16x8*)(sl_ + cell * 40 + g * 8);
                acc[0][ny] = MFMA16(Ah0[slot], bh, acc[0][ny], 0, 0, 0);
                acc[1][ny] = MFMA16(Ah1[slot], bh, acc[1][ny], 0, 0, 0);
                acc[0][ny] = MFMA16(Ah0[slot], bl, acc[0][ny], 0, 0, 0);
                acc[1][ny] = MFMA16(Ah1[slot], bl, acc[1][ny], 0, 0, 0);
                acc[0][ny] = MFMA16(Al0[slot], bh, acc[0][ny], 0, 0, 0);
                acc[1][ny] = MFMA16(Al1[slot], bh, acc[1][ny], 0, 0, 0);
            }
        }
        if (pf) {
            _Float16* nh = SH[(ck + 1) & 1];
            _Float16* nl = SL[(ck + 1) & 1];
#pragma unroll
            for (int k = 0; k < 7; ++k) {
                if (t + k * 256 < 1728) {
                    float v0 = pv[2 * k], v1 = pv[2 * k + 1];
                    _Float16 h0 = (_Float16)v0, h1 = (_Float16)v1;
                    _Float16 l0 = (_Float16)(v0 - (float)h0), l1 = (_Float16)(v1 - (float)h1);
                    f16x2 ph = {h0, h1}, pl = {l0, l1};
                    *(f16x2*)&nh[sla[k]] = ph;
                    *(f16x2*)&nl[sla[k]] = pl;
                }
            }
        }
        __syncthreads();
    }

    int x = bx0 + colc;
    if (x < W) {
#pragma unroll
        for (int mi = 0; mi < 2; ++mi) {
            int cob = co0 + cw * 32 + mi * 16 + g * 4;
#pragma unroll
            for (int ny = 0; ny < 2; ++ny) {
                int y = by0 + pw * 2 + ny;
#pragma unroll
                for (int i = 0; i < 4; ++i) {
                    int co = cob + i;
                    float v = acc[mi][ny][i] + bias[co];
                    if (p.act) v = (v >= 0.f) ? v : 0.1f * v;
                    dst[(size_t)co * HW + y * W + x] = v;
                }
            }
        }
    }
}

// ---------------- decode: scores, argmax, boxes, sort keys ----------------
__launch_bounds__(256)
__global__ void decode_kernel(const float* __restrict__ cls, const float* __restrict__ reg,
                              const float* __restrict__ ctn, float* __restrict__ out,
                              unsigned long long* __restrict__ keys)
{
    int p = blockIdx.x * 256 + threadIdx.x;
    if (p >= 16384) return;
    if (p >= 8400) { keys[p] = ~0ull; return; }
    int base, hs; float s;
    if (p < 6400)      { base = 0;    hs = 80; s = 8.f;  }
    else if (p < 8000) { base = 6400; hs = 40; s = 16.f; }
    else               { base = 8000; hs = 20; s = 32.f; }
    int local = p - base;
    float gx = (float)(local % hs), gy = (float)(local / hs);
    float ct = ctn[p];
    float sct = 1.f / (1.f + expf(-ct));
    float best = -1.f; int arg = 0;
    for (int c = 0; c < 80; ++c) {
        float v = cls[(size_t)c * 8400 + p];
        float sv = 1.f / (1.f + expf(-v));
        float sc = sqrtf(sv * sct);
        if (sc > best) { best = sc; arg = c; }
    }
    float r0 = reg[0 * 8400 + p], r1 = reg[1 * 8400 + p];
    float r2 = reg[2 * 8400 + p], r3 = reg[3 * 8400 + p];
    float x1 = (gx - expf(r0)) * s / 640.f;
    float y1 = (gy - expf(r1)) * s / 640.f;
    float x2 = (gx + expf(r2)) * s / 640.f;
    float y2 = (gy + expf(r3)) * s / 640.f;
    x1 = fminf(fmaxf(x1, 0.f), 1.f);
    y1 = fminf(fmaxf(y1, 0.f), 1.f);
    x2 = fminf(fmaxf(x2, 0.f), 1.f);
    y2 = fminf(fmaxf(y2, 0.f), 1.f);
    out[p * 4 + 0] = x1; out[p * 4 + 1] = y1;
    out[p * 4 + 2] = x2; out[p * 4 + 3] = y2;
    out[33600 + p] = best;
    out[42000 + p] = (float)arg;
    out[50400 + p] = 0.f;
    unsigned int ub = __float_as_uint(best);
    keys[p] = ((unsigned long long)(~ub) << 32) | (unsigned int)p;
}

// ---------------- hybrid bitonic sort of 16384 u64 keys ----------------
__launch_bounds__(256)
__global__ void bitonic_local(unsigned long long* __restrict__ keys, unsigned kmerge)
{
    __shared__ unsigned long long sk[2048];
    int t = threadIdx.x;
    unsigned base = blockIdx.x * 2048u;
#pragma unroll
    for (int m = 0; m < 8; ++m) sk[t + m * 256] = keys[base + t + m * 256];
    __syncthreads();
    if (kmerge == 0u) {
        for (unsigned k = 2; k <= 2048u; k <<= 1) {
            for (unsigned j = k >> 1; j > 0; j >>= 1) {
#pragma unroll
                for (int pp = 0; pp < 4; ++pp) {
                    unsigned p = (unsigned)t + pp * 256u;
                    unsigned li = ((p & ~(j - 1)) << 1) | (p & (j - 1));
                    unsigned gi = base + li;
                    bool up = ((gi & k) == 0);
                    unsigned long long a = sk[li], b = sk[li + j];
                    if ((a > b) == up) { sk[li] = b; sk[li + j] = a; }
                }
                __syncthreads();
            }
        }
    } else {
        unsigned k = kmerge;
        for (unsigned j = 1024; j > 0; j >>= 1) {
#pragma unroll
            for (int pp = 0; pp < 4; ++pp) {
                unsigned p = (unsigned)t + pp * 256u;
                unsigned li = ((p & ~(j - 1)) << 1) | (p & (j - 1));
                unsigned gi = base + li;
                bool up = ((gi & k) == 0);
                unsigned long long a = sk[li], b = sk[li + j];
                if ((a > b) == up) { sk[li] = b; sk[li + j] = a; }
            }
            __syncthreads();
        }
    }
#pragma unroll
    for (int m = 0; m < 8; ++m) keys[base + t + m * 256] = sk[t + m * 256];
}

__launch_bounds__(256)
__global__ void bitonic_global(unsigned long long* __restrict__ keys, unsigned k, unsigned j)
{
    unsigned p = blockIdx.x * 256u + threadIdx.x;
    unsigned i = ((p & ~(j - 1)) << 1) | (p & (j - 1));
    bool up = ((i & k) == 0);
    unsigned long long a = keys[i], b = keys[i + j];
    if ((a > b) == up) { keys[i] = b; keys[i + j] = a; }
}

// ---------------- expand sorted keys into SoA arrays ----------------
__launch_bounds__(256)
__global__ void sorted_aux(const unsigned long long* __restrict__ keys,
                           const float* __restrict__ out,
                           float* __restrict__ scs, int* __restrict__ clss,
                           int* __restrict__ idxs)
{
    int i = blockIdx.x * 256 + threadIdx.x;
    if (i >= 16384) return;
    unsigned long long key = keys[i];
    unsigned ub = ~(unsigned)(key >> 32);
    float sc = __uint_as_float(ub);
    unsigned idx = (unsigned)(key & 0xffffffffu);
    int cl = -1;
    if (idx < 8400u) cl = (int)out[42000 + idx];
    else sc = 0.f;
    scs[i] = sc; clss[i] = cl; idxs[i] = (int)idx;
}

// ---------------- NMS stage 1: per-class stable compaction ----------------
__launch_bounds__(256)
__global__ void compact_cls(const float* __restrict__ scs, const int* __restrict__ clss,
                            const int* __restrict__ idxs, const float* __restrict__ outbuf,
                            float* __restrict__ GX1, float* __restrict__ GY1,
                            float* __restrict__ GX2, float* __restrict__ GY2,
                            float* __restrict__ GAR, int* __restrict__ GIX,
                            int* __restrict__ NCOUNT, int* __restrict__ NBASE)
{
    int c = blockIdx.x, t = threadIdx.x;
    __shared__ int s_red[2];
    __shared__ int s_wtot[4];
    int cb = 0, co = 0;
    for (int i = t; i < 16384; i += 256) {
        float sc = scs[i]; int cl = clss[i];
        if (sc >= CONF_T && cl >= 0) { cb += (cl < c); co += (cl == c); }
    }
    if (t == 0) { s_red[0] = 0; s_red[1] = 0; }
    __syncthreads();
    atomicAdd(&s_red[0], cb);
    atomicAdd(&s_red[1], co);
    __syncthreads();
    int base = s_red[0], n = s_red[1];
    if (t == 0) { NCOUNT[c] = n; NBASE[c] = base; }

    int rank = 0;
    for (int st = 0; st < 16384; st += 256) {
        int i = st + t;
        float sc = scs[i]; int cl = clss[i];
        bool flag = (sc >= CONF_T && cl == c);
        unsigned long long m = __ballot(flag);
        int lane = t & 63, wv = t >> 6;
        if (lane == 0) s_wtot[wv] = __popcll(m);
        __syncthreads();
        int off = rank;
        for (int w = 0; w < wv; ++w) off += s_wtot[w];
        int tot = s_wtot[0] + s_wtot[1] + s_wtot[2] + s_wtot[3];
        if (flag) {
            int pos = off + __popcll(m & ((1ull << lane) - 1ull));
            int idx = idxs[i];
            float x1 = outbuf[idx * 4 + 0], y1 = outbuf[idx * 4 + 1];
            float x2 = outbuf[idx * 4 + 2], y2 = outbuf[idx * 4 + 3];
            GX1[base + pos] = x1; GY1[base + pos] = y1;
            GX2[base + pos] = x2; GY2[base + pos] = y2;
            GAR[base + pos] = (x2 - x1) * (y2 - y1);
            GIX[base + pos] = idx;
        }
        rank += tot;
        __syncthreads();
    }
}

// ---------------- NMS stage 2: suppression bit-matrix (parallel) ----------------
__launch_bounds__(256)
__global__ void nms_mask(const float* __restrict__ GX1, const float* __restrict__ GY1,
                         const float* __restrict__ GX2, const float* __restrict__ GY2,
                         const float* __restrict__ GAR,
                         const int* __restrict__ NCOUNT, const int* __restrict__ NBASE,
                         unsigned long long* __restrict__ MASK)
{
    int c = blockIdx.y;
    int n = NCOUNT[c];
    if ((int)(blockIdx.x * 256) >= n) return;
    int base = NBASE[c];
    int t = threadIdx.x;
    int r = blockIdx.x * 256 + t;
    bool hav = (r < n);
    float rx1 = 0.f, ry1 = 0.f, rx2 = 0.f, ry2 = 0.f, rar = 0.f;
    if (hav) {
        rx1 = GX1[base + r]; ry1 = GY1[base + r];
        rx2 = GX2[base + r]; ry2 = GY2[base + r];
        rar = GAR[base + r];
    }
    __shared__ float tx1[2048], ty1[2048], tx2[2048], ty2[2048], tar[2048];
    for (int jt = 0; jt < n; jt += 2048) {
        int cnt = min(2048, n - jt);
        __syncthreads();
        for (int k = t; k < cnt; k += 256) {
            tx1[k] = GX1[base + jt + k]; ty1[k] = GY1[base + jt + k];
            tx2[k] = GX2[base + jt + k]; ty2[k] = GY2[base + jt + k];
            tar[k] = GAR[base + jt + k];
        }
        __syncthreads();
        if (hav) {
            int w0 = jt >> 6;
            int nw = (cnt + 63) >> 6;
            for (int w = 0; w < nw; ++w) {
                int jb = jt + w * 64;
                unsigned long long bits = 0ull;
                if (jb + 63 > r) {
                    int kmax = min(64, n - jb);
                    for (int kk = 0; kk < kmax; ++kk) {
                        int j = jb + kk;
                        if (j > r) {
                            int k2 = j - jt;
                            float xx1 = fmaxf(rx1, tx1[k2]);
                            float yy1 = fmaxf(ry1, ty1[k2]);
                            float xx2 = fminf(rx2, tx2[k2]);
                            float yy2 = fminf(ry2, ty2[k2]);
                            float ww = fmaxf(1e-28f, xx2 - xx1);
                            float hh = fmaxf(1e-28f, yy2 - yy1);
                            float inter = ww * hh;
                            float ovr = inter / (rar + tar[k2] - inter);
                            if (ovr > NMS_T) bits |= (1ull << kk);
                        }
                    }
                }
                MASK[(size_t)(base + r) * WMAX + w0 + w] = bits;
            }
        }
    }
}

// ---------------- NMS stage 3: chunked bitmask scan (80 blocks) ----------------
__launch_bounds__(256)
__global__ void nms_scan(const unsigned long long* __restrict__ MASK,
                         const int* __restrict__ GIX,
                         const int* __restrict__ NCOUNT, const int* __restrict__ NBASE,
                         float* __restrict__ keep)
{
    int c = blockIdx.x, t = threadIdx.x;
    int n = NCOUNT[c];
    if (n == 0) return;
    int base = NBASE[c];
    int Wc = (n + 63) >> 6;
    __shared__ unsigned long long remv[WMAX];
    __shared__ unsigned long long sld[32][WMAX];
    __shared__ unsigned int s_alive;
    for (int w = t; w < Wc; w += 256) remv[w] = 0ull;
    __syncthreads();
    for (int i0 = 0; i0 < n; i0 += 32) {
        int rows = min(32, n - i0);
        int tot = rows * Wc;
        for (int k = t; k < tot; k += 256) {
            int rr = k / Wc, w = k - rr * Wc;
            sld[rr][w] = MASK[(size_t)(base + i0 + rr) * WMAX + w];
        }
        __syncthreads();
        if (t == 0) {
            int wq = i0 >> 6, b0 = i0 & 63;
            unsigned long long lw = remv[wq];
            unsigned am = 0;
            for (int rr = 0; rr < rows; ++rr) {
                if (!((lw >> (b0 + rr)) & 1ull)) {
                    am |= (1u << rr);
                    lw |= sld[rr][wq];
                }
            }
            s_alive = am;
        }
        __syncthreads();
        unsigned am = s_alive;
        for (int w = t; w < Wc; w += 256) {
            unsigned long long acc = remv[w];
            unsigned m = am;
            while (m) { int rr = __ffs(m) - 1; m &= m - 1; acc |= sld[rr][w]; }
            remv[w] = acc;
        }
        if (t < rows && ((am >> t) & 1u)) keep[GIX[base + i0 + t]] = 1.0f;
        __syncthreads();
    }
}

// ---------------- host orchestration ----------------
extern "C" void kernel_launch(void* const* d_in, const int* in_sizes, int n_in,
                              void* d_out, int out_size, void* d_ws, size_t ws_size,
                              hipStream_t stream)
{
    const float* c3      = (const float*)d_in[0];
    const float* c4      = (const float*)d_in[1];
    const float* c5      = (const float*)d_in[2];
    const float* lat1_w  = (const float*)d_in[3];
    const float* lat1_b  = (const float*)d_in[4];
    const float* lat2_w  = (const float*)d_in[5];
    const float* lat2_b  = (const float*)d_in[6];
    const float* lat3_w  = (const float*)d_in[7];
    const float* lat3_b  = (const float*)d_in[8];
    const float* sm1_w   = (const float*)d_in[9];
    const float* sm1_b   = (const float*)d_in[10];
    const float* sm2_w   = (const float*)d_in[11];
    const float* sm2_b   = (const float*)d_in[12];
    const float* sm3_w   = (const float*)d_in[13];
    const float* sm3_b   = (const float*)d_in[14];
    const float* clsh_w  = (const float*)d_in[15];
    const float* clsh_b  = (const float*)d_in[16];
    const float* regh_w  = (const float*)d_in[17];
    const float* regh_b  = (const float*)d_in[18];
    const float* clsd_w  = (const float*)d_in[19];
    const float* clsd_b  = (const float*)d_in[20];
    const float* regd_w  = (const float*)d_in[21];
    const float* regd_b  = (const float*)d_in[22];
    const float* ctnd_w  = (const float*)d_in[23];
    const float* ctnd_b  = (const float*)d_in[24];

    float* ws = (float*)d_ws;
    float* T3 = ws + OFF_T3;  float* T4 = ws + OFF_T4;  float* T5 = ws + OFF_T5;
    float* P3 = ws + OFF_P3;  float* P4 = ws + OFF_P4;  float* P5 = ws + OFF_P5;
    float* HA3 = ws + OFF_HA3; float* HA4 = ws + OFF_HA4; float* HA5 = ws + OFF_HA5;
    float* HB3 = ws + OFF_HB3; float* HB4 = ws + OFF_HB4; float* HB5 = ws + OFF_HB5;
    float* HD3 = ws + OFF_HD3; float* HD4 = ws + OFF_HD4; float* HD5 = ws + OFF_HD5;
    float* CLS = ws + OFF_CLS; float* REG = ws + OFF_REG; float* CTN = ws + OFF_CTN;
    _Float16* WH = (_Float16*)(ws + OFF_W2H);
    _Float16* WL = (_Float16*)(ws + OFF_W2L);
    unsigned long long* KEYS = (unsigned long long*)(ws + POFF_KEYS);
    float* SCS = ws + POFF_SCS;
    int* CLSS = (int*)(ws + POFF_CLSS);
    int* IDXS = (int*)(ws + POFF_IDXS);
    float* GX1 = ws + POFF_GX1; float* GY1 = ws + POFF_GY1;
    float* GX2 = ws + POFF_GX2; float* GY2 = ws + POFF_GY2;
    float* GAR = ws + POFF_GAR;
    int* GIX = (int*)(ws + POFF_GIX);
    int* NCOUNT = (int*)(ws + POFF_NCNT);
    int* NBASE  = (int*)(ws + POFF_NBASE);
    unsigned long long* MASK = (unsigned long long*)(ws + POFF_MASK);

    float* out = (float*)d_out;
    dim3 blk(256);

    // weight f16 hi/lo prep (11 matrices, fragment-order layout)
    w2prep<<<dim3((11 * WSTEP9 + 255) / 256), blk, 0, stream>>>(
        clsh_w, regh_w, sm1_w, sm2_w, sm3_w, WH, WL);

    // FPN laterals (dependency chain), then all smooths fused (MFMA)
    conv1x1_kernel<<<dim3(7, 4), blk, 0, stream>>>(c5, lat3_w, lat3_b, T5, nullptr,
                                                   512, 256, 400, 20, 400, 0);
    conv1x1_kernel<<<dim3(25, 4), blk, 0, stream>>>(c4, lat2_w, lat2_b, T4, T5,
                                                    256, 256, 1600, 40, 1600, 0);
    conv1x1_kernel<<<dim3(100, 4), blk, 0, stream>>>(c3, lat1_w, lat1_b, T3, T4,
                                                     128, 256, 6400, 80, 6400, 0);
    {
        MC mc{};
        float* sT[3] = {T3, T4, T5};
        float* sP[3] = {P3, P4, P5};
        const float* sB[3] = {sm1_b, sm2_b, sm3_b};
        for (int l = 0; l < 3; ++l) {
            mc.src[0][l] = sT[l]; mc.dst[0][l] = sP[l];
            mc.wh[0][l] = WH + (size_t)(8 + l) * WSTEP9;
            mc.wl[0][l] = WL + (size_t)(8 + l) * WSTEP9;
            mc.bias[0][l] = sB[l];
        }
        mc.act = 0; mc.nbr = 1;
        mconv3x3<<<dim3(140 * 4), blk, 0, stream>>>(mc);
    }
    // heads: 4 MFMA layers (slice-swizzled 1D grid)
    {
        float* clsS[3][5] = { {P3, HA3, HB3, HA3, HB3},
                              {P4, HA4, HB4, HA4, HB4},
                              {P5, HA5, HB5, HA5, HB5} };
        float* regS[3][5] = { {P3, T3,  HD3, T3,  HD3},
                              {P4, T4,  HD4, T4,  HD4},
                              {P5, T5,  HD5, T5,  HD5} };
        for (int i = 0; i < 4; ++i) {
            MC mc{};
            for (int l = 0; l < 3; ++l) {
                mc.src[0][l] = clsS[l][i]; mc.dst[0][l] = clsS[l][i + 1];
                mc.src[1][l] = regS[l][i]; mc.dst[1][l] = regS[l][i + 1];
                mc.wh[0][l] = WH + (size_t)i * WSTEP9;
                mc.wl[0][l] = WL + (size_t)i * WSTEP9;
                mc.wh[1][l] = WH + (size_t)(4 + i) * WSTEP9;
                mc.wl[1][l] = WL + (size_t)(4 + i) * WSTEP9;
                mc.bias[0][l] = clsh_b + i * 256;
                mc.bias[1][l] = regh_b + i * 256;
            }
            mc.act = 1; mc.nbr = 2;
            mconv3x3<<<dim3(140 * 8), blk, 0, stream>>>(mc);
        }
    }

    // ---- detectors: all 9 (level x {cls,reg,ctn}) in one dispatch ----
    {
        Det9 d;
        const float* feats[3][2] = { {HB3, HD3}, {HB4, HD4}, {HB5, HD5} };
        int   npx[3]   = {6400, 1600, 400};
        int   obase[3] = {0, 6400, 8000};
        int q = 0, bacc = 0;
        for (int l = 0; l < 3; ++l) {
            d.src[q] = feats[l][0]; d.w[q] = clsd_w; d.b[q] = clsd_b; d.dst[q] = CLS;
            d.cout[q] = 80; d.npx[q] = npx[l]; d.obase[q] = obase[l];
            d.bstart[q] = bacc; d.npxb[q] = (npx[l] + 63) / 64;
            bacc += d.npxb[q] * 2; ++q;
            d.src[q] = feats[l][1]; d.w[q] = regd_w; d.b[q] = regd_b; d.dst[q] = REG;
            d.cout[q] = 4; d.npx[q] = npx[l]; d.obase[q] = obase[l];
            d.bstart[q] = bacc; d.npxb[q] = (npx[l] + 63) / 64;
            bacc += d.npxb[q]; ++q;
            d.src[q] = feats[l][1]; d.w[q] = ctnd_w; d.b[q] = ctnd_b; d.dst[q] = CTN;
            d.cout[q] = 1; d.npx[q] = npx[l]; d.obase[q] = obase[l];
            d.bstart[q] = bacc; d.npxb[q] = (npx[l] + 63) / 64;
            bacc += d.npxb[q]; ++q;
        }
        det1x1_fused<<<dim3(bacc), blk, 0, stream>>>(d);
    }

    // ---- decode ----
    decode_kernel<<<dim3(64), blk, 0, stream>>>(CLS, REG, CTN, out, KEYS);

    // ---- hybrid bitonic sort ----
    bitonic_local<<<dim3(8), blk, 0, stream>>>(KEYS, 0u);
    bitonic_global<<<dim3(32), blk, 0, stream>>>(KEYS, 4096u, 2048u);
    bitonic_local<<<dim3(8), blk, 0, stream>>>(KEYS, 4096u);
    bitonic_global<<<dim3(32), blk, 0, stream>>>(KEYS, 8192u, 4096u);
    bitonic_global<<<dim3(32), blk, 0, stream>>>(KEYS, 8192u, 2048u);
    bitonic_local<<<dim3(8), blk, 0, stream>>>(KEYS, 8192u);
    bitonic_global<<<dim3(32), blk, 0, stream>>>(KEYS, 16384u, 8192u);
    bitonic_global<<<dim3(32), blk, 0, stream>>>(KEYS, 16384u, 4096u);
    bitonic_global<<<dim3(32), blk, 0, stream>>>(KEYS, 16384u, 2048u);
    bitonic_local<<<dim3(8), blk, 0, stream>>>(KEYS, 16384u);

    // ---- NMS pipeline ----
    sorted_aux<<<dim3(64), blk, 0, stream>>>(KEYS, out, SCS, CLSS, IDXS);
    compact_cls<<<dim3(80), blk, 0, stream>>>(SCS, CLSS, IDXS, out,
                                              GX1, GY1, GX2, GY2, GAR, GIX, NCOUNT, NBASE);
    nms_mask<<<dim3(33, 80), blk, 0, stream>>>(GX1, GY1, GX2, GY2, GAR, NCOUNT, NBASE, MASK);
    nms_scan<<<dim3(80), blk, 0, stream>>>(MASK, GIX, NCOUNT, NBASE, out + 50400);
}